// Round 10
// baseline (544.550 us; speedup 1.0000x reference)
//
#include <hip/hip_runtime.h>
#include <math.h>

#define BB   128
#define NN   1024
#define BN   (BB*NN)          // 131072
#define EDG  (BB*8192)        // 1048576
#define K1C  820
#define K2C  656
#define TSEQ 19
#define HID  120
#define D1K  4816
#define D1CH 38               // ceil(4816/128)

// ---------------- reduction helper (128-thread block) ----------------
__device__ __forceinline__ float blockReduceSum128(float v, float* tmp2) {
#pragma unroll
  for (int o = 32; o > 0; o >>= 1) v += __shfl_down(v, o);
  int lane = threadIdx.x & 63, w = threadIdx.x >> 6;
  if (lane == 0) tmp2[w] = v;
  __syncthreads();
  float r = tmp2[0] + tmp2[1];
  __syncthreads();
  return r;
}

// ---------------- p-norm precompute ----------------
__global__ void k_pnorm(const float* __restrict__ p1, const float* __restrict__ p2,
                        float* __restrict__ invp) {
  __shared__ float tmp2[2];
  float a = p1[threadIdx.x], b = p2[threadIdx.x];
  float s1 = blockReduceSum128(a * a, tmp2);
  float s2 = blockReduceSum128(b * b, tmp2);
  if (threadIdx.x == 0) { invp[0] = 1.f / sqrtf(s1); invp[1] = 1.f / sqrtf(s2); }
}

// ---------------- layer-1 CSR build (per-graph, LDS, no global atomics) ----------------
// elist1 stores LOCAL src id (0..1023)
__global__ __launch_bounds__(1024) void k_csr1(const int* __restrict__ src,
                                               const int* __restrict__ dst,
                                               int* __restrict__ starts,
                                               int* __restrict__ cnt,
                                               int* __restrict__ elist) {
  __shared__ int h[1024];
  __shared__ int s[1024];
  int b = blockIdx.x, tid = threadIdx.x;
  h[tid] = 0;
  __syncthreads();
  int base = b * 8192, nb = b * 1024;
#pragma unroll
  for (int it = 0; it < 8; ++it) {
    int d = dst[base + it * 1024 + tid] - nb;
    atomicAdd(&h[d], 1);
  }
  __syncthreads();
  int v = h[tid];
  cnt[nb + tid] = v;
  s[tid] = v;
  __syncthreads();
  for (int o = 1; o < 1024; o <<= 1) {
    int t = (tid >= o) ? s[tid - o] : 0;
    __syncthreads();
    s[tid] += t;
    __syncthreads();
  }
  int st = s[tid] - v;                 // exclusive, local to graph
  starts[nb + tid] = base + st;
  h[tid] = st;                         // reuse as local cursor
  __syncthreads();
#pragma unroll
  for (int it = 0; it < 8; ++it) {
    int e = base + it * 1024 + tid;
    int d = dst[e] - nb;
    int pos = atomicAdd(&h[d], 1);
    elist[base + pos] = src[e] - nb;   // LOCAL src id
  }
}

// ---------------- layer-1 aggregate: LDS-staged x slice (16KB/graph) ----------------
__global__ __launch_bounds__(1024) void k_agg1(const int* __restrict__ starts,
                                               const int* __restrict__ cnt,
                                               const int* __restrict__ elist,
                                               const float* __restrict__ x,
                                               float* __restrict__ agg1) {
  __shared__ float4 xls4[1024];
  int b = blockIdx.x, tid = threadIdx.x;
  int nb = b * 1024;
  xls4[tid] = ((const float4*)x)[nb + tid];
  __syncthreads();
  const float* xls = (const float*)xls4;
  int rg = tid >> 2, lane = tid & 3;
#pragma unroll
  for (int it = 0; it < 4; ++it) {
    int r = rg + it * 256;
    int s0 = starts[nb + r], n = cnt[nb + r];
    float a0 = 0.f, a1 = 0.f;
    int j = 0;
    for (; j + 1 < n; j += 2) {
      int m0 = elist[s0 + j], m1 = elist[s0 + j + 1];
      a0 += xls[m0 * 4 + lane];
      a1 += xls[m1 * 4 + lane];
    }
    if (j < n) a0 += xls[elist[s0 + j] * 4 + lane];
    agg1[(size_t)(nb + r) * 4 + lane] = a0 + a1;
  }
}

// ---------------- h1 = relu(agg1@W1rel + x@W1root + b1); score1 fused ----------------
__global__ void k_h1(const float* __restrict__ x, const float* __restrict__ agg1,
                     const float* __restrict__ W1rel, const float* __restrict__ W1root,
                     const float* __restrict__ b1, const float* __restrict__ p1,
                     const float* __restrict__ invp,
                     float* __restrict__ h1, float* __restrict__ score1) {
  int tid = blockIdx.x * 256 + threadIdx.x;
  int r = tid >> 5, lane = tid & 31, f4 = lane * 4;
  float4 a = ((const float4*)agg1)[r];
  float4 xv = ((const float4*)x)[r];
  float o[4], dot = 0.f;
#pragma unroll
  for (int j = 0; j < 4; ++j) {
    int f = f4 + j;
    float acc = b1[f]
      + a.x * W1rel[f] + a.y * W1rel[128 + f] + a.z * W1rel[256 + f] + a.w * W1rel[384 + f]
      + xv.x * W1root[f] + xv.y * W1root[128 + f] + xv.z * W1root[256 + f] + xv.w * W1root[384 + f];
    o[j] = fmaxf(acc, 0.f);
    dot += o[j] * p1[f];
  }
  *(float4*)&h1[(size_t)r * 128 + f4] = make_float4(o[0], o[1], o[2], o[3]);
#pragma unroll
  for (int off = 16; off > 0; off >>= 1) dot += __shfl_down(dot, off, 32);
  if (lane == 0) score1[r] = tanhf(dot * invp[0]);
}

// ---------------- per-graph top-k via LDS bitonic sort (1024 slots) ----------------
__global__ void k_sort(const float* __restrict__ score, int n_per, int K,
                       int* __restrict__ perm, int* __restrict__ mapping) {
  __shared__ float s[1024];
  __shared__ int   id[1024];
  int b = blockIdx.x;
  const float* sc = score + (size_t)b * n_per;
  for (int i = threadIdx.x; i < 1024; i += blockDim.x) {
    if (i < n_per) { s[i] = sc[i]; id[i] = i; }
    else           { s[i] = -INFINITY; id[i] = 0x7fffffff; }
  }
  __syncthreads();
  for (int k = 2; k <= 1024; k <<= 1) {
    for (int j = k >> 1; j > 0; j >>= 1) {
      for (int i = threadIdx.x; i < 1024; i += blockDim.x) {
        int l = i ^ j;
        if (l > i) {
          float si = s[i], sl = s[l];
          int ii = id[i], il = id[l];
          bool iBeforeL = (si > sl) || (si == sl && ii < il);
          bool up = ((i & k) == 0);
          if (up ? (!iBeforeL) : iBeforeL) {
            s[i] = sl; s[l] = si; id[i] = il; id[l] = ii;
          }
        }
      }
      __syncthreads();
    }
  }
  for (int r = threadIdx.x; r < K; r += blockDim.x)
    perm[(size_t)b * K + r] = b * n_per + id[r];
  if (mapping) {
    for (int i = threadIdx.x; i < n_per; i += blockDim.x)
      mapping[(size_t)b * n_per + i] = -1;
    __syncthreads();
    for (int r = threadIdx.x; r < K; r += blockDim.x)
      mapping[(size_t)b * n_per + id[r]] = b * K + r;
  }
}

// ---------------- fused gather(+scale) + partial readout over 64-row chunks ----------------
// xp may be null (layer 2: no materialization needed)
#define RCH 64
__global__ void k_gatherread(const float* __restrict__ h, const float* __restrict__ score,
                             const int* __restrict__ perm, float* __restrict__ xp,
                             float* __restrict__ pmax, float* __restrict__ psum,
                             int K, int nch) {
  int b = blockIdx.x / nch, c = blockIdx.x % nch, f = threadIdx.x;  // 128 threads
  int r0 = c * RCH, r1 = min(r0 + RCH, K);
  float mx = -INFINITY, sm = 0.f;
  if (xp) {
    for (int r = r0; r < r1; ++r) {
      int g = perm[(size_t)b * K + r];
      float v = h[(size_t)g * 128 + f] * score[g];
      xp[((size_t)b * K + r) * 128 + f] = v;
      mx = fmaxf(mx, v); sm += v;
    }
  } else {
    for (int r = r0; r < r1; ++r) {
      int g = perm[(size_t)b * K + r];
      float v = h[(size_t)g * 128 + f] * score[g];
      mx = fmaxf(mx, v); sm += v;
    }
  }
  pmax[((size_t)b * nch + c) * 128 + f] = mx;
  psum[((size_t)b * nch + c) * 128 + f] = sm;
}

// ---------------- readout stage 2 ----------------
__global__ void k_readout2(const float* __restrict__ pmax, const float* __restrict__ psum,
                           float* __restrict__ xout, int K, int nch) {
  int b = blockIdx.x, f = threadIdx.x;
  float mx = -INFINITY, sm = 0.f;
  for (int c = 0; c < nch; ++c) {
    mx = fmaxf(mx, pmax[((size_t)b * nch + c) * 128 + f]);
    sm += psum[((size_t)b * nch + c) * 128 + f];
  }
  xout[b * 256 + f] = mx;
  xout[b * 256 + 128 + f] = sm / (float)K;
}

// ---------------- layer-2 aggregate: walk layer-1 CSR of kept rows, filter via LDS map ----------------
// LDS: xp1 f-chunk (105KB) + local map (4KB) + starts/cnt (8KB) = 117KB
__global__ __launch_bounds__(1024) void k_agg2s(const int* __restrict__ perm1,
                                                const int* __restrict__ starts1,
                                                const int* __restrict__ cnt1,
                                                const int* __restrict__ elist1,
                                                const int* __restrict__ map1,
                                                const float* __restrict__ xp1,
                                                float* __restrict__ agg2) {
  __shared__ float xls[K1C * 32];     // [kept row][32 feats] = 104,960 B
  __shared__ int mapl[1024];          // local node -> local kept idx or -1
  __shared__ int sts[1024];           // local edge-list start
  __shared__ int ctn[1024];           // count
  int g = blockIdx.x >> 2, q = blockIdx.x & 3;
  int tid = threadIdx.x;
  int nb = g * 1024, nb2 = g * K1C, eb0 = g * 8192;
  for (int i = tid; i < K1C * 8; i += 1024) {
    int row = i >> 3, f4 = i & 7;
    ((float4*)xls)[i] = ((const float4*)xp1)[(size_t)(nb2 + row) * 32 + q * 8 + f4];
  }
  {
    int v = map1[nb + tid];
    mapl[tid] = (v >= 0) ? (v - nb2) : -1;
    sts[tid] = starts1[nb + tid] - eb0;
    ctn[tid] = cnt1[nb + tid];
  }
  __syncthreads();
  const int* eb = elist1 + eb0;
  int rg = tid >> 5, lane = tid & 31;  // 32 row-groups x 32 feats
  for (int r = rg; r < K1C; r += 32) {
    int lorig = perm1[(size_t)nb2 + r] & (NN - 1);
    int s0 = sts[lorig], n = ctn[lorig];
    float a = 0.f;
    for (int j = 0; j < n; ++j) {
      int ms = mapl[eb[s0 + j]];
      if (ms >= 0) a += xls[ms * 32 + lane];
    }
    agg2[(size_t)(nb2 + r) * 128 + q * 32 + lane] = a;
  }
}

// ---------------- h2 GEMM: 64x128 tile, 128 thr, 8x8/thread, BK=32, grid 1640 ----------------
// A transposed in LDS stride 65 (65%32==1 -> banks (kq+j+row)%32, 2-way max = free);
// W stride 132; reads broadcast/2-way. 6 blocks/CU LDS-resident, 6.4 blocks/CU grid.
#define ALDA 65
#define WLDA 132
__global__ __launch_bounds__(128, 3) void k_h2(
    const float* __restrict__ agg2, const float* __restrict__ xp1,
    const float* __restrict__ W2rel, const float* __restrict__ W2root,
    const float* __restrict__ b2, const float* __restrict__ p2,
    const float* __restrict__ invp, float* __restrict__ h2,
    float* __restrict__ score2) {
  __shared__ float As[32][ALDA];     // [k][row], 8.3 KB
  __shared__ float Ws[32][WLDA];     // [k][col], 16.9 KB
  int tid = threadIdx.x;
  int r0 = blockIdx.x * 64;
  int tx = tid & 15, ty = tid >> 4;  // ty 0..7: rows ty*8..+7; cols {tx*4, 64+tx*4}
  float acc[8][8] = {};
  for (int ks = 0; ks < 8; ++ks) {
    const float* Asrc = (ks < 4) ? agg2 : xp1;
    const float* Wsrc = (ks < 4) ? W2rel : W2root;
    int kof = (ks & 3) * 32;
    // stage A transposed: 64 rows x 32 k = 512 float4, 4/thread
#pragma unroll
    for (int l = 0; l < 4; ++l) {
      int idx = l * 128 + tid;
      int row = idx >> 3, kq = (idx & 7) * 4;
      float4 v = *(const float4*)&Asrc[(size_t)(r0 + row) * 128 + kof + kq];
      As[kq + 0][row] = v.x; As[kq + 1][row] = v.y;
      As[kq + 2][row] = v.z; As[kq + 3][row] = v.w;
    }
    // stage W: 32 k x 128 cols = 1024 float4, 8/thread
#pragma unroll
    for (int l = 0; l < 8; ++l) {
      int idx = l * 128 + tid;
      int kr = idx >> 5, c4 = (idx & 31) * 4;
      *(float4*)&Ws[kr][c4] = *(const float4*)&Wsrc[(size_t)(kof + kr) * 128 + c4];
    }
    __syncthreads();
#pragma unroll 4
    for (int kk = 0; kk < 32; ++kk) {
      float4 a0 = *(const float4*)&As[kk][ty * 8];
      float4 a1 = *(const float4*)&As[kk][ty * 8 + 4];
      float4 w0 = *(const float4*)&Ws[kk][tx * 4];
      float4 w1 = *(const float4*)&Ws[kk][64 + tx * 4];
      float av[8] = {a0.x, a0.y, a0.z, a0.w, a1.x, a1.y, a1.z, a1.w};
      float wv[8] = {w0.x, w0.y, w0.z, w0.w, w1.x, w1.y, w1.z, w1.w};
#pragma unroll
      for (int i = 0; i < 8; ++i)
#pragma unroll
        for (int j = 0; j < 8; ++j) acc[i][j] += av[i] * wv[j];
    }
    __syncthreads();
  }
  float4 bb0 = *(const float4*)&b2[tx * 4];
  float4 bb1 = *(const float4*)&b2[64 + tx * 4];
  float4 pp0 = *(const float4*)&p2[tx * 4];
  float4 pp1 = *(const float4*)&p2[64 + tx * 4];
  float bbv[8] = {bb0.x, bb0.y, bb0.z, bb0.w, bb1.x, bb1.y, bb1.z, bb1.w};
  float pbv[8] = {pp0.x, pp0.y, pp0.z, pp0.w, pp1.x, pp1.y, pp1.z, pp1.w};
  float inv = invp[1];
#pragma unroll
  for (int i = 0; i < 8; ++i) {
    int row = r0 + ty * 8 + i;
    float o[8], dot = 0.f;
#pragma unroll
    for (int j = 0; j < 8; ++j) {
      o[j] = fmaxf(acc[i][j] + bbv[j], 0.f);
      dot += o[j] * pbv[j];
    }
    *(float4*)&h2[(size_t)row * 128 + tx * 4] = make_float4(o[0], o[1], o[2], o[3]);
    *(float4*)&h2[(size_t)row * 128 + 64 + tx * 4] = make_float4(o[4], o[5], o[6], o[7]);
#pragma unroll
    for (int off = 8; off > 0; off >>= 1) dot += __shfl_down(dot, off, 16);
    if (tx == 0) score2[row] = tanhf(dot * inv);
  }
}

// ---------------- target conv + relu + avgpool -> xs[t][b][o] ----------------
__global__ void k_conv(const float* __restrict__ target, const float* __restrict__ Wc,
                       const float* __restrict__ bc, float* __restrict__ xs) {
  int gb = blockIdx.x;               // B*19
  int b = gb / TSEQ, tt = gb % TSEQ;
  int o = threadIdx.x;               // 128
  __shared__ float tg[30][8];
  for (int i = threadIdx.x; i < 210; i += 128) {
    int ch = i / 7, u = i % 7;
    tg[ch][u] = target[((size_t)b * 30 + ch) * 101 + tt * 5 + u];
  }
  __syncthreads();
  const float* w = Wc + (size_t)o * 90;
  float acc5[5] = {0, 0, 0, 0, 0};
  for (int ch = 0; ch < 30; ++ch) {
    float w0 = w[ch * 3], w1 = w[ch * 3 + 1], w2 = w[ch * 3 + 2];
#pragma unroll
    for (int u = 0; u < 5; ++u)
      acc5[u] += tg[ch][u] * w0 + tg[ch][u + 1] * w1 + tg[ch][u + 2] * w2;
  }
  float bo = bc[o], s = 0.f;
#pragma unroll
  for (int u = 0; u < 5; ++u) s += fmaxf(acc5[u] + bo, 0.f);
  xs[((size_t)tt * BB + b) * 128 + o] = s * 0.2f;
}

// ---------------- gi = xs @ Wih^T + bih; 16 batches per block ----------------
#define GIB 16
__global__ __launch_bounds__(384) void k_gi(const float* __restrict__ xs,
                     const float* __restrict__ Wihf, const float* __restrict__ bihf,
                     const float* __restrict__ Wihb, const float* __restrict__ bihb,
                     float* __restrict__ gi) {
  int bg = blockIdx.x & 7;
  int t = (blockIdx.x >> 3) % TSEQ;
  int dir = blockIdx.x / (8 * TSEQ);
  int b0 = bg * GIB;
  __shared__ float xst[GIB][128];
  int tid = threadIdx.x;
  for (int i = tid; i < GIB * 128; i += 384) {
    int bb = i >> 7, k = i & 127;
    xst[bb][k] = xs[((size_t)t * BB + b0 + bb) * 128 + k];
  }
  __syncthreads();
  int j = tid;
  if (j < 360) {
    const float* W = (dir ? Wihb : Wihf) + (size_t)j * 128;
    float bias = (dir ? bihb : bihf)[j];
    float acc[GIB];
#pragma unroll
    for (int bb = 0; bb < GIB; ++bb) acc[bb] = bias;
#pragma unroll 4
    for (int k = 0; k < 128; ++k) {
      float w = W[k];
#pragma unroll
      for (int bb = 0; bb < GIB; ++bb) acc[bb] += xst[bb][k] * w;
    }
    size_t base = ((size_t)dir * TSEQ + t) * BB + b0;
#pragma unroll
    for (int bb = 0; bb < GIB; ++bb) gi[(base + bb) * 360 + j] = acc[bb];
  }
}

// ---------------- GRU recurrence: Whh rows held in REGISTERS, h via LDS broadcast ----------------
__global__ __launch_bounds__(384) void k_gru(const float* __restrict__ gi,
                      const float* __restrict__ Whhf, const float* __restrict__ bhhf,
                      const float* __restrict__ Whhb, const float* __restrict__ bhhb,
                      float* __restrict__ xc) {
  int pair = blockIdx.x & 63, dir = blockIdx.x >> 6;
  int b0 = pair * 2;
  const float* Whh = dir ? Whhb : Whhf;
  const float* bhh = dir ? bhhb : bhhf;
  __shared__ float h_sh[2][HID];
  __shared__ float g0[360], g1[360];
  int j = threadIdx.x;               // 384
  float wrow[HID];
  float bias = 0.f;
  if (j < 360) {
    const float4* W4 = (const float4*)(Whh + (size_t)j * HID);
#pragma unroll
    for (int k4 = 0; k4 < HID / 4; ++k4) {
      float4 w = W4[k4];
      wrow[k4 * 4 + 0] = w.x; wrow[k4 * 4 + 1] = w.y;
      wrow[k4 * 4 + 2] = w.z; wrow[k4 * 4 + 3] = w.w;
    }
    bias = bhh[j];
  }
  if (j < 2 * HID) h_sh[j / HID][j % HID] = 0.f;
  __syncthreads();
  for (int st = 0; st < TSEQ; ++st) {
    int tt = dir ? (TSEQ - 1 - st) : st;
    if (j < 360) {
      float a0 = bias, a1 = bias;
      const float4* h40 = (const float4*)h_sh[0];
      const float4* h41 = (const float4*)h_sh[1];
#pragma unroll
      for (int k4 = 0; k4 < HID / 4; ++k4) {
        float4 v0 = h40[k4];
        float4 v1 = h41[k4];
        a0 += wrow[k4*4+0]*v0.x + wrow[k4*4+1]*v0.y + wrow[k4*4+2]*v0.z + wrow[k4*4+3]*v0.w;
        a1 += wrow[k4*4+0]*v1.x + wrow[k4*4+1]*v1.y + wrow[k4*4+2]*v1.z + wrow[k4*4+3]*v1.w;
      }
      g0[j] = a0; g1[j] = a1;
    }
    __syncthreads();
    if (j < 2 * HID) {
      int bb = j / HID, th = j - bb * HID;
      const float* g = gi + (((size_t)dir * TSEQ + tt) * BB + (b0 + bb)) * 360;
      const float* gh = bb ? g1 : g0;
      float r  = 1.f / (1.f + expf(-(g[th]       + gh[th])));
      float z  = 1.f / (1.f + expf(-(g[120 + th] + gh[120 + th])));
      float ng = tanhf(g[240 + th] + r * gh[240 + th]);
      float hn = (1.f - z) * ng + z * h_sh[bb][th];
      h_sh[bb][th] = hn;
      xc[(size_t)(b0 + bb) * 4816 + 256 + (size_t)tt * 240 + dir * 120 + th] = hn;
    }
    __syncthreads();
  }
}

// ---------------- xg = x1 + x2 into xc[:, :256] ----------------
__global__ void k_xg(const float* __restrict__ x1, const float* __restrict__ x2,
                     float* __restrict__ xc) {
  int b = blockIdx.x, f = threadIdx.x;
  xc[(size_t)b * 4816 + f] = x1[b * 256 + f] + x2[b * 256 + f];
}

// ---------------- d1 partial GEMM ----------------
__global__ __launch_bounds__(128) void k_d1(const float* __restrict__ xc,
                                            const float* __restrict__ Wd1,
                                            float* __restrict__ part) {
  int c = blockIdx.x % D1CH;
  int rg = blockIdx.x / D1CH;
  int k0 = c * 128, kn = min(128, D1K - k0);
  __shared__ float xcs[8][128];
  int tid = threadIdx.x;
#pragma unroll
  for (int l = 0; l < 8; ++l) {
    int i = tid + l * 128;
    int r = i >> 7, k = i & 127;
    xcs[r][k] = (k < kn) ? xc[(size_t)(rg * 8 + r) * D1K + k0 + k] : 0.f;
  }
  __syncthreads();
  int j = tid;
  if (j < 102) {
    float acc[8] = {};
    for (int k = 0; k < kn; ++k) {
      float w = Wd1[(size_t)(k0 + k) * 102 + j];
#pragma unroll
      for (int r = 0; r < 8; ++r) acc[r] += xcs[r][k] * w;
    }
#pragma unroll
    for (int r = 0; r < 8; ++r)
      part[((size_t)(rg * 8 + r) * D1CH + c) * 102 + j] = acc[r];
  }
}

// ---------------- reduce partials + relu + d3 + log_softmax ----------------
__global__ void k_final2(const float* __restrict__ part, const float* __restrict__ bd1,
                         const float* __restrict__ Wd3, const float* __restrict__ bd3,
                         float* __restrict__ out) {
  __shared__ float tmp2[2];
  int b = blockIdx.x, j = threadIdx.x;
  float v = 0.f;
  if (j < 102) {
    float acc = bd1[j];
    for (int c = 0; c < D1CH; ++c) acc += part[((size_t)b * D1CH + c) * 102 + j];
    v = fmaxf(acc, 0.f);
  }
  float c0 = (j < 102) ? v * Wd3[j * 2] : 0.f;
  float c1 = (j < 102) ? v * Wd3[j * 2 + 1] : 0.f;
  float z0 = blockReduceSum128(c0, tmp2) + bd3[0];
  float z1 = blockReduceSum128(c1, tmp2) + bd3[1];
  if (j < 2) {
    float m = fmaxf(z0, z1);
    float lse = m + logf(expf(z0 - m) + expf(z1 - m));
    out[b * 2 + j] = (j == 0 ? z0 : z1) - lse;
  }
}

// ---------------- launch ----------------
extern "C" void kernel_launch(void* const* d_in, const int* in_sizes, int n_in,
                              void* d_out, int out_size, void* d_ws, size_t ws_size,
                              hipStream_t stream) {
  const float* x      = (const float*)d_in[0];
  const float* target = (const float*)d_in[1];
  const int*   esrc   = (const int*)d_in[2];
  const int*   edst   = (const int*)d_in[3];
  const float* W1rel  = (const float*)d_in[4];
  const float* W1root = (const float*)d_in[5];
  const float* b1     = (const float*)d_in[6];
  const float* p1     = (const float*)d_in[7];
  const float* W2rel  = (const float*)d_in[8];
  const float* W2root = (const float*)d_in[9];
  const float* b2     = (const float*)d_in[10];
  const float* p2     = (const float*)d_in[11];
  const float* Wc     = (const float*)d_in[12];
  const float* bc     = (const float*)d_in[13];
  const float* Wihf   = (const float*)d_in[14];
  const float* Whhf   = (const float*)d_in[15];
  const float* bihf   = (const float*)d_in[16];
  const float* bhhf   = (const float*)d_in[17];
  const float* Wihb   = (const float*)d_in[18];
  const float* Whhb   = (const float*)d_in[19];
  const float* bihb   = (const float*)d_in[20];
  const float* bhhb   = (const float*)d_in[21];
  const float* Wd1    = (const float*)d_in[22];
  const float* bd1    = (const float*)d_in[23];
  const float* Wd3    = (const float*)d_in[24];
  const float* bd3    = (const float*)d_in[25];
  float* out = (float*)d_out;

  char* wsb = (char*)d_ws;
  size_t off = 0;
  auto alloc = [&](size_t bytes) -> void* {
    void* p = wsb + off;
    off = (off + bytes + 255) & ~(size_t)255;
    return p;
  };
  float* regH    = (float*)alloc((size_t)BN * 128 * 4);   // h1 / agg2 (64MB)
  float* agg1    = (float*)alloc((size_t)BN * 4 * 4);
  float* score1  = (float*)alloc((size_t)BN * 4);
  int*   perm1   = (int*)  alloc((size_t)BB * K1C * 4);
  int*   map1    = (int*)  alloc((size_t)BN * 4);
  float* xp1     = (float*)alloc((size_t)BB * K1C * 128 * 4);
  float* h2      = (float*)alloc((size_t)BB * K1C * 128 * 4);
  float* score2  = (float*)alloc((size_t)BB * K1C * 4);
  int*   perm2   = (int*)  alloc((size_t)BB * K2C * 4);
  float* x1      = (float*)alloc((size_t)BB * 256 * 4);
  float* x2      = (float*)alloc((size_t)BB * 256 * 4);
  float* invp    = (float*)alloc(256);
  float* xs      = (float*)alloc((size_t)TSEQ * BB * 128 * 4);
  float* gi      = (float*)alloc((size_t)2 * TSEQ * BB * 360 * 4);
  float* xc      = (float*)alloc((size_t)BB * 4816 * 4);
  int*   starts1 = (int*)  alloc((size_t)BN * 4);
  int*   cnt1    = (int*)  alloc((size_t)BN * 4);
  int*   elist1  = (int*)  alloc((size_t)EDG * 4);
  float* pmax    = (float*)alloc((size_t)BB * 13 * 128 * 4);
  float* psum    = (float*)alloc((size_t)BB * 13 * 128 * 4);
  float* part    = (float*)alloc((size_t)BB * D1CH * 102 * 4);
  float* h1   = regH;
  float* agg2 = regH;

  k_pnorm<<<1, 128, 0, stream>>>(p1, p2, invp);
  k_csr1<<<BB, 1024, 0, stream>>>(esrc, edst, starts1, cnt1, elist1);

  // --- layer 1 ---
  k_agg1<<<BB, 1024, 0, stream>>>(starts1, cnt1, elist1, x, agg1);
  k_h1<<<BN * 32 / 256, 256, 0, stream>>>(x, agg1, W1rel, W1root, b1, p1, invp, h1, score1);
  k_sort<<<BB, 512, 0, stream>>>(score1, NN, K1C, perm1, map1);
  {
    int nch = (K1C + RCH - 1) / RCH;  // 13
    k_gatherread<<<BB * nch, 128, 0, stream>>>(h1, score1, perm1, xp1, pmax, psum, K1C, nch);
    k_readout2<<<BB, 128, 0, stream>>>(pmax, psum, x1, K1C, nch);
  }

  // --- layer 2: aggregate straight from layer-1 CSR (no csr2 kernel) ---
  k_agg2s<<<BB * 4, 1024, 0, stream>>>(perm1, starts1, cnt1, elist1, map1, xp1, agg2);
  k_h2<<<(BB * K1C) / 64, 128, 0, stream>>>(agg2, xp1, W2rel, W2root, b2, p2, invp, h2, score2);
  k_sort<<<BB, 512, 0, stream>>>(score2, K1C, K2C, perm2, nullptr);
  {
    int nch = (K2C + RCH - 1) / RCH;  // 11
    k_gatherread<<<BB * nch, 128, 0, stream>>>(h2, score2, perm2, nullptr, pmax, psum, K2C, nch);
    k_readout2<<<BB, 128, 0, stream>>>(pmax, psum, x2, K2C, nch);
  }

  // --- target branch ---
  k_conv<<<BB * TSEQ, 128, 0, stream>>>(target, Wc, bc, xs);
  k_gi<<<2 * TSEQ * 8, 384, 0, stream>>>(xs, Wihf, bihf, Wihb, bihb, gi);
  k_gru<<<2 * 64, 384, 0, stream>>>(gi, Whhf, bhhf, Whhb, bhhb, xc);

  // --- head ---
  k_xg<<<BB, 256, 0, stream>>>(x1, x2, xc);
  k_d1<<<(BB / 8) * D1CH, 128, 0, stream>>>(xc, Wd1, part);
  k_final2<<<BB, 128, 0, stream>>>(part, bd1, Wd3, bd3, out);
}

// Round 11
// 485.679 us; speedup vs baseline: 1.1212x; 1.1212x over previous
//
#include <hip/hip_runtime.h>
#include <math.h>

#define BB   128
#define NN   1024
#define BN   (BB*NN)          // 131072
#define EDG  (BB*8192)        // 1048576
#define K1C  820
#define K2C  656
#define TSEQ 19
#define HID  120
#define D1K  4816
#define D1CH 38               // ceil(4816/128)
#define NCH1 13               // ceil(820/64)
#define NCH2 11               // ceil(656/64)

// ---------------- reduction helper (128-thread block) ----------------
__device__ __forceinline__ float blockReduceSum128(float v, float* tmp2) {
#pragma unroll
  for (int o = 32; o > 0; o >>= 1) v += __shfl_down(v, o);
  int lane = threadIdx.x & 63, w = threadIdx.x >> 6;
  if (lane == 0) tmp2[w] = v;
  __syncthreads();
  float r = tmp2[0] + tmp2[1];
  __syncthreads();
  return r;
}

// ---------------- p-norm precompute ----------------
__global__ void k_pnorm(const float* __restrict__ p1, const float* __restrict__ p2,
                        float* __restrict__ invp) {
  __shared__ float tmp2[2];
  float a = p1[threadIdx.x], b = p2[threadIdx.x];
  float s1 = blockReduceSum128(a * a, tmp2);
  float s2 = blockReduceSum128(b * b, tmp2);
  if (threadIdx.x == 0) { invp[0] = 1.f / sqrtf(s1); invp[1] = 1.f / sqrtf(s2); }
}

// ---------------- fused layer-1 CSR build + aggregate (all in LDS) ----------------
// Per-graph block: histogram -> scan -> fill elist in LDS -> gather-aggregate.
// CSR never touches global memory.
__global__ __launch_bounds__(1024) void k_l1(const int* __restrict__ src,
                                             const int* __restrict__ dst,
                                             const float* __restrict__ x,
                                             float* __restrict__ agg1) {
  __shared__ int hcur[1024];
  __shared__ int sscan[1024];
  __shared__ int ccnt[1024];
  __shared__ int el[8192];
  __shared__ float4 xls4[1024];
  int b = blockIdx.x, tid = threadIdx.x;
  int base = b * 8192, nb = b * 1024;
  hcur[tid] = 0;
  __syncthreads();
#pragma unroll
  for (int it = 0; it < 8; ++it)
    atomicAdd(&hcur[dst[base + it * 1024 + tid] - nb], 1);
  __syncthreads();
  int v = hcur[tid];
  ccnt[tid] = v;
  sscan[tid] = v;
  __syncthreads();
  for (int o = 1; o < 1024; o <<= 1) {
    int t = (tid >= o) ? sscan[tid - o] : 0;
    __syncthreads();
    sscan[tid] += t;
    __syncthreads();
  }
  hcur[tid] = sscan[tid] - v;          // exclusive start (local cursor)
  __syncthreads();
#pragma unroll
  for (int it = 0; it < 8; ++it) {
    int e = base + it * 1024 + tid;
    int d = dst[e] - nb;
    int pos = atomicAdd(&hcur[d], 1);
    el[pos] = src[e] - nb;             // LOCAL src id
  }
  xls4[tid] = ((const float4*)x)[nb + tid];
  __syncthreads();
  const float* xls = (const float*)xls4;
  int rg = tid >> 2, lane = tid & 3;
#pragma unroll
  for (int it = 0; it < 4; ++it) {
    int r = rg + it * 256;
    int n = ccnt[r], s0 = sscan[r] - n;
    float a0 = 0.f, a1 = 0.f;
    int j = 0;
    for (; j + 1 < n; j += 2) {
      a0 += xls[el[s0 + j] * 4 + lane];
      a1 += xls[el[s0 + j + 1] * 4 + lane];
    }
    if (j < n) a0 += xls[el[s0 + j] * 4 + lane];
    agg1[(size_t)(nb + r) * 4 + lane] = a0 + a1;
  }
}

// ---------------- h1 = relu(agg1@W1rel + x@W1root + b1); score1 fused ----------------
__global__ void k_h1(const float* __restrict__ x, const float* __restrict__ agg1,
                     const float* __restrict__ W1rel, const float* __restrict__ W1root,
                     const float* __restrict__ b1, const float* __restrict__ p1,
                     const float* __restrict__ invp,
                     float* __restrict__ h1, float* __restrict__ score1) {
  int tid = blockIdx.x * 256 + threadIdx.x;
  int r = tid >> 5, lane = tid & 31, f4 = lane * 4;
  float4 a = ((const float4*)agg1)[r];
  float4 xv = ((const float4*)x)[r];
  float o[4], dot = 0.f;
#pragma unroll
  for (int j = 0; j < 4; ++j) {
    int f = f4 + j;
    float acc = b1[f]
      + a.x * W1rel[f] + a.y * W1rel[128 + f] + a.z * W1rel[256 + f] + a.w * W1rel[384 + f]
      + xv.x * W1root[f] + xv.y * W1root[128 + f] + xv.z * W1root[256 + f] + xv.w * W1root[384 + f];
    o[j] = fmaxf(acc, 0.f);
    dot += o[j] * p1[f];
  }
  *(float4*)&h1[(size_t)r * 128 + f4] = make_float4(o[0], o[1], o[2], o[3]);
#pragma unroll
  for (int off = 16; off > 0; off >>= 1) dot += __shfl_down(dot, off, 32);
  if (lane == 0) score1[r] = tanhf(dot * invp[0]);
}

// ---------------- per-graph top-k via LDS bitonic sort (1024 slots) ----------------
__global__ void k_sort(const float* __restrict__ score, int n_per, int K,
                       int* __restrict__ perm, int* __restrict__ mapping) {
  __shared__ float s[1024];
  __shared__ int   id[1024];
  int b = blockIdx.x;
  const float* sc = score + (size_t)b * n_per;
  for (int i = threadIdx.x; i < 1024; i += blockDim.x) {
    if (i < n_per) { s[i] = sc[i]; id[i] = i; }
    else           { s[i] = -INFINITY; id[i] = 0x7fffffff; }
  }
  __syncthreads();
  for (int k = 2; k <= 1024; k <<= 1) {
    for (int j = k >> 1; j > 0; j >>= 1) {
      for (int i = threadIdx.x; i < 1024; i += blockDim.x) {
        int l = i ^ j;
        if (l > i) {
          float si = s[i], sl = s[l];
          int ii = id[i], il = id[l];
          bool iBeforeL = (si > sl) || (si == sl && ii < il);
          bool up = ((i & k) == 0);
          if (up ? (!iBeforeL) : iBeforeL) {
            s[i] = sl; s[l] = si; id[i] = il; id[l] = ii;
          }
        }
      }
      __syncthreads();
    }
  }
  for (int r = threadIdx.x; r < K; r += blockDim.x)
    perm[(size_t)b * K + r] = b * n_per + id[r];
  if (mapping) {
    for (int i = threadIdx.x; i < n_per; i += blockDim.x)
      mapping[(size_t)b * n_per + i] = -1;
    __syncthreads();
    for (int r = threadIdx.x; r < K; r += blockDim.x)
      mapping[(size_t)b * n_per + id[r]] = b * K + r;
  }
}

// ---------------- fused gather(+scale) + partial readout over 64-row chunks ----------------
// xp may be null (layer 2: no materialization needed)
#define RCH 64
__global__ void k_gatherread(const float* __restrict__ h, const float* __restrict__ score,
                             const int* __restrict__ perm, float* __restrict__ xp,
                             float* __restrict__ pmax, float* __restrict__ psum,
                             int K, int nch) {
  int b = blockIdx.x / nch, c = blockIdx.x % nch, f = threadIdx.x;  // 128 threads
  int r0 = c * RCH, r1 = min(r0 + RCH, K);
  float mx = -INFINITY, sm = 0.f;
  if (xp) {
    for (int r = r0; r < r1; ++r) {
      int g = perm[(size_t)b * K + r];
      float v = h[(size_t)g * 128 + f] * score[g];
      xp[((size_t)b * K + r) * 128 + f] = v;
      mx = fmaxf(mx, v); sm += v;
    }
  } else {
    for (int r = r0; r < r1; ++r) {
      int g = perm[(size_t)b * K + r];
      float v = h[(size_t)g * 128 + f] * score[g];
      mx = fmaxf(mx, v); sm += v;
    }
  }
  pmax[((size_t)b * nch + c) * 128 + f] = mx;
  psum[((size_t)b * nch + c) * 128 + f] = sm;
}

// ---------------- layer-2 filtered CSR (per-graph, LDS, no global atomics) ----------------
__global__ __launch_bounds__(1024) void k_csr2(const int* __restrict__ src,
                                               const int* __restrict__ dst,
                                               const int* __restrict__ map,
                                               int* __restrict__ starts2,
                                               int* __restrict__ cnt2,
                                               int* __restrict__ elist2) {
  __shared__ int mloc[8192];   // local kept dst per edge, -1 invalid
  __shared__ int msl[8192];    // local kept src per edge
  __shared__ int h[1024];
  __shared__ int s[1024];
  int g = blockIdx.x, tid = threadIdx.x;
  int base = g * 8192, nb2 = g * K1C;
  h[tid] = 0;
  __syncthreads();
#pragma unroll
  for (int it = 0; it < 8; ++it) {
    int e = base + it * 1024 + tid;
    int ms = map[src[e]], md = map[dst[e]];
    bool valid = (ms >= 0) && (md >= 0);
    int idx = it * 1024 + tid;
    int ml = valid ? (md - nb2) : -1;
    mloc[idx] = ml;
    msl[idx] = ms - nb2;
    if (valid) atomicAdd(&h[ml], 1);
  }
  __syncthreads();
  int v = (tid < K1C) ? h[tid] : 0;
  if (tid < K1C) cnt2[nb2 + tid] = v;
  s[tid] = v;
  __syncthreads();
  for (int o = 1; o < 1024; o <<= 1) {
    int t = (tid >= o) ? s[tid - o] : 0;
    __syncthreads();
    s[tid] += t;
    __syncthreads();
  }
  int st = s[tid] - v;
  if (tid < K1C) starts2[nb2 + tid] = base + st;
  h[tid] = st;                        // local cursor
  __syncthreads();
#pragma unroll
  for (int it = 0; it < 8; ++it) {
    int idx = it * 1024 + tid;
    int ml = mloc[idx];
    if (ml >= 0) {
      int pos = atomicAdd(&h[ml], 1);
      elist2[base + pos] = msl[idx];
    }
  }
}

// ---------------- layer-2 aggregate: LDS-staged xp1 16-feat chunk (52.5KB, 3 blocks/CU) ----------------
__global__ __launch_bounds__(512) void k_agg2s(const int* __restrict__ starts2,
                                               const int* __restrict__ cnt2,
                                               const int* __restrict__ elist2,
                                               const float* __restrict__ xp1,
                                               float* __restrict__ agg2) {
  __shared__ float xls[K1C * 16];     // [kept row][16 feats] = 52,480 B
  int g = blockIdx.x >> 3, q = blockIdx.x & 7;
  int tid = threadIdx.x;
  int nb2 = g * K1C;
  for (int i = tid; i < K1C * 4; i += 512) {
    int row = i >> 2, f4 = i & 3;
    ((float4*)xls)[i] = ((const float4*)xp1)[(size_t)(nb2 + row) * 32 + q * 4 + f4];
  }
  __syncthreads();
  int rg = tid >> 4, lane = tid & 15;  // 32 row-groups x 16 feats
  for (int r = rg; r < K1C; r += 32) {
    int s0 = starts2[nb2 + r], n = cnt2[nb2 + r];
    float a0 = 0.f, a1 = 0.f;
    int j = 0;
    for (; j + 1 < n; j += 2) {
      int m0 = elist2[s0 + j], m1 = elist2[s0 + j + 1];
      a0 += xls[m0 * 16 + lane];
      a1 += xls[m1 * 16 + lane];
    }
    if (j < n) a0 += xls[elist2[s0 + j] * 16 + lane];
    agg2[(size_t)(nb2 + r) * 128 + q * 16 + lane] = a0 + a1;
  }
}

// ---------------- h2 GEMM: 128x128 tile, 8x8/thread, BK=16, 4 blocks/CU ----------------
#define ALDA 130
#define WLDA 132
__global__ __launch_bounds__(256, 4) void k_h2(
    const float* __restrict__ agg2, const float* __restrict__ xp1,
    const float* __restrict__ W2rel, const float* __restrict__ W2root,
    const float* __restrict__ b2, const float* __restrict__ p2,
    const float* __restrict__ invp, float* __restrict__ h2,
    float* __restrict__ score2) {
  __shared__ float As[16][ALDA];     // [k][row], 8.3 KB
  __shared__ float Ws[16][WLDA];     // [k][col], 8.4 KB
  int tid = threadIdx.x;
  int r0 = blockIdx.x * 128;
  int tx = tid & 15, ty = tid >> 4;  // cols {tx*4, 64+tx*4}, rows ty*8..ty*8+7
  float acc[8][8] = {};
  for (int ks = 0; ks < 16; ++ks) {
    const float* Asrc = (ks < 8) ? agg2 : xp1;
    const float* Wsrc = (ks < 8) ? W2rel : W2root;
    int kof = (ks & 7) * 16;
#pragma unroll
    for (int l = 0; l < 2; ++l) {
      int idx = l * 256 + tid;
      int row = idx >> 2, kq = (idx & 3) * 4;
      float4 v = *(const float4*)&Asrc[(size_t)(r0 + row) * 128 + kof + kq];
      As[kq + 0][row] = v.x; As[kq + 1][row] = v.y;
      As[kq + 2][row] = v.z; As[kq + 3][row] = v.w;
    }
#pragma unroll
    for (int l = 0; l < 2; ++l) {
      int idx = l * 256 + tid;
      int kr = idx >> 5, c4 = (idx & 31) * 4;
      *(float4*)&Ws[kr][c4] = *(const float4*)&Wsrc[(size_t)(kof + kr) * 128 + c4];
    }
    __syncthreads();
#pragma unroll 8
    for (int kk = 0; kk < 16; ++kk) {
      float4 a0 = *(const float4*)&As[kk][ty * 8];
      float4 a1 = *(const float4*)&As[kk][ty * 8 + 4];
      float4 w0 = *(const float4*)&Ws[kk][tx * 4];
      float4 w1 = *(const float4*)&Ws[kk][64 + tx * 4];
      float av[8] = {a0.x, a0.y, a0.z, a0.w, a1.x, a1.y, a1.z, a1.w};
      float wv[8] = {w0.x, w0.y, w0.z, w0.w, w1.x, w1.y, w1.z, w1.w};
#pragma unroll
      for (int i = 0; i < 8; ++i)
#pragma unroll
        for (int j = 0; j < 8; ++j) acc[i][j] += av[i] * wv[j];
    }
    __syncthreads();
  }
  float4 bb0 = *(const float4*)&b2[tx * 4];
  float4 bb1 = *(const float4*)&b2[64 + tx * 4];
  float4 pp0 = *(const float4*)&p2[tx * 4];
  float4 pp1 = *(const float4*)&p2[64 + tx * 4];
  float bbv[8] = {bb0.x, bb0.y, bb0.z, bb0.w, bb1.x, bb1.y, bb1.z, bb1.w};
  float pbv[8] = {pp0.x, pp0.y, pp0.z, pp0.w, pp1.x, pp1.y, pp1.z, pp1.w};
  float inv = invp[1];
#pragma unroll
  for (int i = 0; i < 8; ++i) {
    int row = r0 + ty * 8 + i;
    float o[8], dot = 0.f;
#pragma unroll
    for (int j = 0; j < 8; ++j) {
      o[j] = fmaxf(acc[i][j] + bbv[j], 0.f);
      dot += o[j] * pbv[j];
    }
    *(float4*)&h2[(size_t)row * 128 + tx * 4] = make_float4(o[0], o[1], o[2], o[3]);
    *(float4*)&h2[(size_t)row * 128 + 64 + tx * 4] = make_float4(o[4], o[5], o[6], o[7]);
#pragma unroll
    for (int off = 8; off > 0; off >>= 1) dot += __shfl_down(dot, off, 16);
    if (tx == 0) score2[row] = tanhf(dot * inv);
  }
}

// ---------------- target conv + relu + avgpool -> xs[t][b][o] ----------------
__global__ void k_conv(const float* __restrict__ target, const float* __restrict__ Wc,
                       const float* __restrict__ bc, float* __restrict__ xs) {
  int gb = blockIdx.x;               // B*19
  int b = gb / TSEQ, tt = gb % TSEQ;
  int o = threadIdx.x;               // 128
  __shared__ float tg[30][8];
  for (int i = threadIdx.x; i < 210; i += 128) {
    int ch = i / 7, u = i % 7;
    tg[ch][u] = target[((size_t)b * 30 + ch) * 101 + tt * 5 + u];
  }
  __syncthreads();
  const float* w = Wc + (size_t)o * 90;
  float acc5[5] = {0, 0, 0, 0, 0};
  for (int ch = 0; ch < 30; ++ch) {
    float w0 = w[ch * 3], w1 = w[ch * 3 + 1], w2 = w[ch * 3 + 2];
#pragma unroll
    for (int u = 0; u < 5; ++u)
      acc5[u] += tg[ch][u] * w0 + tg[ch][u + 1] * w1 + tg[ch][u + 2] * w2;
  }
  float bo = bc[o], s = 0.f;
#pragma unroll
  for (int u = 0; u < 5; ++u) s += fmaxf(acc5[u] + bo, 0.f);
  xs[((size_t)tt * BB + b) * 128 + o] = s * 0.2f;
}

// ---------------- gi = xs @ Wih^T + bih; 16 batches per block ----------------
#define GIB 16
__global__ __launch_bounds__(384) void k_gi(const float* __restrict__ xs,
                     const float* __restrict__ Wihf, const float* __restrict__ bihf,
                     const float* __restrict__ Wihb, const float* __restrict__ bihb,
                     float* __restrict__ gi) {
  int bg = blockIdx.x & 7;
  int t = (blockIdx.x >> 3) % TSEQ;
  int dir = blockIdx.x / (8 * TSEQ);
  int b0 = bg * GIB;
  __shared__ float xst[GIB][128];
  int tid = threadIdx.x;
  for (int i = tid; i < GIB * 128; i += 384) {
    int bb = i >> 7, k = i & 127;
    xst[bb][k] = xs[((size_t)t * BB + b0 + bb) * 128 + k];
  }
  __syncthreads();
  int j = tid;
  if (j < 360) {
    const float* W = (dir ? Wihb : Wihf) + (size_t)j * 128;
    float bias = (dir ? bihb : bihf)[j];
    float acc[GIB];
#pragma unroll
    for (int bb = 0; bb < GIB; ++bb) acc[bb] = bias;
#pragma unroll 4
    for (int k = 0; k < 128; ++k) {
      float w = W[k];
#pragma unroll
      for (int bb = 0; bb < GIB; ++bb) acc[bb] += xst[bb][k] * w;
    }
    size_t base = ((size_t)dir * TSEQ + t) * BB + b0;
#pragma unroll
    for (int bb = 0; bb < GIB; ++bb) gi[(base + bb) * 360 + j] = acc[bb];
  }
}

// ---------------- GRU recurrence: Whh rows held in REGISTERS, h via LDS broadcast ----------------
__global__ __launch_bounds__(384) void k_gru(const float* __restrict__ gi,
                      const float* __restrict__ Whhf, const float* __restrict__ bhhf,
                      const float* __restrict__ Whhb, const float* __restrict__ bhhb,
                      float* __restrict__ xc) {
  int pair = blockIdx.x & 63, dir = blockIdx.x >> 6;
  int b0 = pair * 2;
  const float* Whh = dir ? Whhb : Whhf;
  const float* bhh = dir ? bhhb : bhhf;
  __shared__ float h_sh[2][HID];
  __shared__ float g0[360], g1[360];
  int j = threadIdx.x;               // 384
  float wrow[HID];
  float bias = 0.f;
  if (j < 360) {
    const float4* W4 = (const float4*)(Whh + (size_t)j * HID);
#pragma unroll
    for (int k4 = 0; k4 < HID / 4; ++k4) {
      float4 w = W4[k4];
      wrow[k4 * 4 + 0] = w.x; wrow[k4 * 4 + 1] = w.y;
      wrow[k4 * 4 + 2] = w.z; wrow[k4 * 4 + 3] = w.w;
    }
    bias = bhh[j];
  }
  if (j < 2 * HID) h_sh[j / HID][j % HID] = 0.f;
  __syncthreads();
  for (int st = 0; st < TSEQ; ++st) {
    int tt = dir ? (TSEQ - 1 - st) : st;
    if (j < 360) {
      float a0 = bias, a1 = bias;
      const float4* h40 = (const float4*)h_sh[0];
      const float4* h41 = (const float4*)h_sh[1];
#pragma unroll
      for (int k4 = 0; k4 < HID / 4; ++k4) {
        float4 v0 = h40[k4];
        float4 v1 = h41[k4];
        a0 += wrow[k4*4+0]*v0.x + wrow[k4*4+1]*v0.y + wrow[k4*4+2]*v0.z + wrow[k4*4+3]*v0.w;
        a1 += wrow[k4*4+0]*v1.x + wrow[k4*4+1]*v1.y + wrow[k4*4+2]*v1.z + wrow[k4*4+3]*v1.w;
      }
      g0[j] = a0; g1[j] = a1;
    }
    __syncthreads();
    if (j < 2 * HID) {
      int bb = j / HID, th = j - bb * HID;
      const float* g = gi + (((size_t)dir * TSEQ + tt) * BB + (b0 + bb)) * 360;
      const float* gh = bb ? g1 : g0;
      float r  = 1.f / (1.f + expf(-(g[th]       + gh[th])));
      float z  = 1.f / (1.f + expf(-(g[120 + th] + gh[120 + th])));
      float ng = tanhf(g[240 + th] + r * gh[240 + th]);
      float hn = (1.f - z) * ng + z * h_sh[bb][th];
      h_sh[bb][th] = hn;
      xc[(size_t)(b0 + bb) * 4816 + 256 + (size_t)tt * 240 + dir * 120 + th] = hn;
    }
    __syncthreads();
  }
}

// ---------------- fused final readout: xc[:, :256] = x1 + x2 from partials ----------------
__global__ void k_xg(const float* __restrict__ pmax1, const float* __restrict__ psum1,
                     const float* __restrict__ pmax2, const float* __restrict__ psum2,
                     float* __restrict__ xc) {
  int b = blockIdx.x, f = threadIdx.x;  // 128 threads
  float mx1 = -INFINITY, sm1 = 0.f;
  for (int c = 0; c < NCH1; ++c) {
    mx1 = fmaxf(mx1, pmax1[((size_t)b * NCH1 + c) * 128 + f]);
    sm1 += psum1[((size_t)b * NCH1 + c) * 128 + f];
  }
  float mx2 = -INFINITY, sm2 = 0.f;
  for (int c = 0; c < NCH2; ++c) {
    mx2 = fmaxf(mx2, pmax2[((size_t)b * NCH2 + c) * 128 + f]);
    sm2 += psum2[((size_t)b * NCH2 + c) * 128 + f];
  }
  xc[(size_t)b * 4816 + f] = mx1 + mx2;
  xc[(size_t)b * 4816 + 128 + f] = sm1 / (float)K1C + sm2 / (float)K2C;
}

// ---------------- d1 partial GEMM ----------------
__global__ __launch_bounds__(128) void k_d1(const float* __restrict__ xc,
                                            const float* __restrict__ Wd1,
                                            float* __restrict__ part) {
  int c = blockIdx.x % D1CH;
  int rg = blockIdx.x / D1CH;
  int k0 = c * 128, kn = min(128, D1K - k0);
  __shared__ float xcs[8][128];
  int tid = threadIdx.x;
#pragma unroll
  for (int l = 0; l < 8; ++l) {
    int i = tid + l * 128;
    int r = i >> 7, k = i & 127;
    xcs[r][k] = (k < kn) ? xc[(size_t)(rg * 8 + r) * D1K + k0 + k] : 0.f;
  }
  __syncthreads();
  int j = tid;
  if (j < 102) {
    float acc[8] = {};
    for (int k = 0; k < kn; ++k) {
      float w = Wd1[(size_t)(k0 + k) * 102 + j];
#pragma unroll
      for (int r = 0; r < 8; ++r) acc[r] += xcs[r][k] * w;
    }
#pragma unroll
    for (int r = 0; r < 8; ++r)
      part[((size_t)(rg * 8 + r) * D1CH + c) * 102 + j] = acc[r];
  }
}

// ---------------- reduce partials + relu + d3 + log_softmax ----------------
__global__ void k_final2(const float* __restrict__ part, const float* __restrict__ bd1,
                         const float* __restrict__ Wd3, const float* __restrict__ bd3,
                         float* __restrict__ out) {
  __shared__ float tmp2[2];
  int b = blockIdx.x, j = threadIdx.x;
  float v = 0.f;
  if (j < 102) {
    float acc = bd1[j];
    for (int c = 0; c < D1CH; ++c) acc += part[((size_t)b * D1CH + c) * 102 + j];
    v = fmaxf(acc, 0.f);
  }
  float c0 = (j < 102) ? v * Wd3[j * 2] : 0.f;
  float c1 = (j < 102) ? v * Wd3[j * 2 + 1] : 0.f;
  float z0 = blockReduceSum128(c0, tmp2) + bd3[0];
  float z1 = blockReduceSum128(c1, tmp2) + bd3[1];
  if (j < 2) {
    float m = fmaxf(z0, z1);
    float lse = m + logf(expf(z0 - m) + expf(z1 - m));
    out[b * 2 + j] = (j == 0 ? z0 : z1) - lse;
  }
}

// ---------------- launch ----------------
extern "C" void kernel_launch(void* const* d_in, const int* in_sizes, int n_in,
                              void* d_out, int out_size, void* d_ws, size_t ws_size,
                              hipStream_t stream) {
  const float* x      = (const float*)d_in[0];
  const float* target = (const float*)d_in[1];
  const int*   esrc   = (const int*)d_in[2];
  const int*   edst   = (const int*)d_in[3];
  const float* W1rel  = (const float*)d_in[4];
  const float* W1root = (const float*)d_in[5];
  const float* b1     = (const float*)d_in[6];
  const float* p1     = (const float*)d_in[7];
  const float* W2rel  = (const float*)d_in[8];
  const float* W2root = (const float*)d_in[9];
  const float* b2     = (const float*)d_in[10];
  const float* p2     = (const float*)d_in[11];
  const float* Wc     = (const float*)d_in[12];
  const float* bc     = (const float*)d_in[13];
  const float* Wihf   = (const float*)d_in[14];
  const float* Whhf   = (const float*)d_in[15];
  const float* bihf   = (const float*)d_in[16];
  const float* bhhf   = (const float*)d_in[17];
  const float* Wihb   = (const float*)d_in[18];
  const float* Whhb   = (const float*)d_in[19];
  const float* bihb   = (const float*)d_in[20];
  const float* bhhb   = (const float*)d_in[21];
  const float* Wd1    = (const float*)d_in[22];
  const float* bd1    = (const float*)d_in[23];
  const float* Wd3    = (const float*)d_in[24];
  const float* bd3    = (const float*)d_in[25];
  float* out = (float*)d_out;

  char* wsb = (char*)d_ws;
  size_t off = 0;
  auto alloc = [&](size_t bytes) -> void* {
    void* p = wsb + off;
    off = (off + bytes + 255) & ~(size_t)255;
    return p;
  };
  float* regH    = (float*)alloc((size_t)BN * 128 * 4);   // h1 / agg2 (64MB)
  float* agg1    = (float*)alloc((size_t)BN * 4 * 4);
  float* score1  = (float*)alloc((size_t)BN * 4);
  int*   perm1   = (int*)  alloc((size_t)BB * K1C * 4);
  int*   map1    = (int*)  alloc((size_t)BN * 4);
  float* xp1     = (float*)alloc((size_t)BB * K1C * 128 * 4);
  float* h2      = (float*)alloc((size_t)BB * K1C * 128 * 4);
  float* score2  = (float*)alloc((size_t)BB * K1C * 4);
  int*   perm2   = (int*)  alloc((size_t)BB * K2C * 4);
  float* invp    = (float*)alloc(256);
  float* xs      = (float*)alloc((size_t)TSEQ * BB * 128 * 4);
  float* gi      = (float*)alloc((size_t)2 * TSEQ * BB * 360 * 4);
  float* xc      = (float*)alloc((size_t)BB * 4816 * 4);
  int*   starts2 = (int*)  alloc((size_t)BB * K1C * 4);
  int*   cnt2    = (int*)  alloc((size_t)BB * K1C * 4);
  int*   elist2  = (int*)  alloc((size_t)EDG * 4);
  float* pmax1   = (float*)alloc((size_t)BB * NCH1 * 128 * 4);
  float* psum1   = (float*)alloc((size_t)BB * NCH1 * 128 * 4);
  float* pmax2   = (float*)alloc((size_t)BB * NCH2 * 128 * 4);
  float* psum2   = (float*)alloc((size_t)BB * NCH2 * 128 * 4);
  float* part    = (float*)alloc((size_t)BB * D1CH * 102 * 4);
  float* h1   = regH;
  float* agg2 = regH;

  k_pnorm<<<1, 128, 0, stream>>>(p1, p2, invp);

  // --- layer 1 (CSR build + aggregate fused, CSR lives in LDS only) ---
  k_l1<<<BB, 1024, 0, stream>>>(esrc, edst, x, agg1);
  k_h1<<<BN * 32 / 256, 256, 0, stream>>>(x, agg1, W1rel, W1root, b1, p1, invp, h1, score1);
  k_sort<<<BB, 512, 0, stream>>>(score1, NN, K1C, perm1, map1);
  k_gatherread<<<BB * NCH1, 128, 0, stream>>>(h1, score1, perm1, xp1, pmax1, psum1, K1C, NCH1);

  // --- layer 2: filtered CSR + LDS-staged aggregate ---
  k_csr2<<<BB, 1024, 0, stream>>>(esrc, edst, map1, starts2, cnt2, elist2);
  k_agg2s<<<BB * 8, 512, 0, stream>>>(starts2, cnt2, elist2, xp1, agg2);
  k_h2<<<(BB * K1C) / 128, 256, 0, stream>>>(agg2, xp1, W2rel, W2root, b2, p2, invp, h2, score2);
  k_sort<<<BB, 512, 0, stream>>>(score2, K1C, K2C, perm2, nullptr);
  k_gatherread<<<BB * NCH2, 128, 0, stream>>>(h2, score2, perm2, nullptr, pmax2, psum2, K2C, NCH2);

  // --- target branch ---
  k_conv<<<BB * TSEQ, 128, 0, stream>>>(target, Wc, bc, xs);
  k_gi<<<2 * TSEQ * 8, 384, 0, stream>>>(xs, Wihf, bihf, Wihb, bihb, gi);
  k_gru<<<2 * 64, 384, 0, stream>>>(gi, Whhf, bhhf, Whhb, bhhb, xc);

  // --- head ---
  k_xg<<<BB, 128, 0, stream>>>(pmax1, psum1, pmax2, psum2, xc);
  k_d1<<<(BB / 8) * D1CH, 128, 0, stream>>>(xc, Wd1, part);
  k_final2<<<BB, 128, 0, stream>>>(part, bd1, Wd3, bd3, out);
}

// Round 12
// 473.697 us; speedup vs baseline: 1.1496x; 1.0253x over previous
//
#include <hip/hip_runtime.h>
#include <math.h>

#define BB   128
#define NN   1024
#define BN   (BB*NN)          // 131072
#define EDG  (BB*8192)        // 1048576
#define K1C  820
#define K2C  656
#define TSEQ 19
#define HID  120
#define D1K  4816
#define D1CH 38               // ceil(4816/128)
#define NCH1 13               // ceil(820/64)
#define NCH2 11               // ceil(656/64)

// ---------------- reduction helper (128-thread block) ----------------
__device__ __forceinline__ float blockReduceSum128(float v, float* tmp2) {
#pragma unroll
  for (int o = 32; o > 0; o >>= 1) v += __shfl_down(v, o);
  int lane = threadIdx.x & 63, w = threadIdx.x >> 6;
  if (lane == 0) tmp2[w] = v;
  __syncthreads();
  float r = tmp2[0] + tmp2[1];
  __syncthreads();
  return r;
}

// ---------------- p-norm precompute ----------------
__global__ void k_pnorm(const float* __restrict__ p1, const float* __restrict__ p2,
                        float* __restrict__ invp) {
  __shared__ float tmp2[2];
  float a = p1[threadIdx.x], b = p2[threadIdx.x];
  float s1 = blockReduceSum128(a * a, tmp2);
  float s2 = blockReduceSum128(b * b, tmp2);
  if (threadIdx.x == 0) { invp[0] = 1.f / sqrtf(s1); invp[1] = 1.f / sqrtf(s2); }
}

// ---------------- fused layer-1 CSR build + aggregate (all in LDS) ----------------
__global__ __launch_bounds__(1024) void k_l1(const int* __restrict__ src,
                                             const int* __restrict__ dst,
                                             const float* __restrict__ x,
                                             float* __restrict__ agg1) {
  __shared__ int hcur[1024];
  __shared__ int sscan[1024];
  __shared__ int ccnt[1024];
  __shared__ int el[8192];
  __shared__ float4 xls4[1024];
  int b = blockIdx.x, tid = threadIdx.x;
  int base = b * 8192, nb = b * 1024;
  hcur[tid] = 0;
  __syncthreads();
#pragma unroll
  for (int it = 0; it < 8; ++it)
    atomicAdd(&hcur[dst[base + it * 1024 + tid] - nb], 1);
  __syncthreads();
  int v = hcur[tid];
  ccnt[tid] = v;
  sscan[tid] = v;
  __syncthreads();
  for (int o = 1; o < 1024; o <<= 1) {
    int t = (tid >= o) ? sscan[tid - o] : 0;
    __syncthreads();
    sscan[tid] += t;
    __syncthreads();
  }
  hcur[tid] = sscan[tid] - v;          // exclusive start (local cursor)
  __syncthreads();
#pragma unroll
  for (int it = 0; it < 8; ++it) {
    int e = base + it * 1024 + tid;
    int d = dst[e] - nb;
    int pos = atomicAdd(&hcur[d], 1);
    el[pos] = src[e] - nb;             // LOCAL src id
  }
  xls4[tid] = ((const float4*)x)[nb + tid];
  __syncthreads();
  const float* xls = (const float*)xls4;
  int rg = tid >> 2, lane = tid & 3;
#pragma unroll
  for (int it = 0; it < 4; ++it) {
    int r = rg + it * 256;
    int n = ccnt[r], s0 = sscan[r] - n;
    float a0 = 0.f, a1 = 0.f;
    int j = 0;
    for (; j + 1 < n; j += 2) {
      a0 += xls[el[s0 + j] * 4 + lane];
      a1 += xls[el[s0 + j + 1] * 4 + lane];
    }
    if (j < n) a0 += xls[el[s0 + j] * 4 + lane];
    agg1[(size_t)(nb + r) * 4 + lane] = a0 + a1;
  }
}

// ---------------- h1 = relu(agg1@W1rel + x@W1root + b1); score1 fused ----------------
__global__ void k_h1(const float* __restrict__ x, const float* __restrict__ agg1,
                     const float* __restrict__ W1rel, const float* __restrict__ W1root,
                     const float* __restrict__ b1, const float* __restrict__ p1,
                     const float* __restrict__ invp,
                     float* __restrict__ h1, float* __restrict__ score1) {
  int tid = blockIdx.x * 256 + threadIdx.x;
  int r = tid >> 5, lane = tid & 31, f4 = lane * 4;
  float4 a = ((const float4*)agg1)[r];
  float4 xv = ((const float4*)x)[r];
  float o[4], dot = 0.f;
#pragma unroll
  for (int j = 0; j < 4; ++j) {
    int f = f4 + j;
    float acc = b1[f]
      + a.x * W1rel[f] + a.y * W1rel[128 + f] + a.z * W1rel[256 + f] + a.w * W1rel[384 + f]
      + xv.x * W1root[f] + xv.y * W1root[128 + f] + xv.z * W1root[256 + f] + xv.w * W1root[384 + f];
    o[j] = fmaxf(acc, 0.f);
    dot += o[j] * p1[f];
  }
  *(float4*)&h1[(size_t)r * 128 + f4] = make_float4(o[0], o[1], o[2], o[3]);
#pragma unroll
  for (int off = 16; off > 0; off >>= 1) dot += __shfl_down(dot, off, 32);
  if (lane == 0) score1[r] = tanhf(dot * invp[0]);
}

// ---------------- per-graph top-k via LDS bitonic sort (1024 slots) ----------------
__global__ void k_sort(const float* __restrict__ score, int n_per, int K,
                       int* __restrict__ perm, int* __restrict__ mapping) {
  __shared__ float s[1024];
  __shared__ int   id[1024];
  int b = blockIdx.x;
  const float* sc = score + (size_t)b * n_per;
  for (int i = threadIdx.x; i < 1024; i += blockDim.x) {
    if (i < n_per) { s[i] = sc[i]; id[i] = i; }
    else           { s[i] = -INFINITY; id[i] = 0x7fffffff; }
  }
  __syncthreads();
  for (int k = 2; k <= 1024; k <<= 1) {
    for (int j = k >> 1; j > 0; j >>= 1) {
      for (int i = threadIdx.x; i < 1024; i += blockDim.x) {
        int l = i ^ j;
        if (l > i) {
          float si = s[i], sl = s[l];
          int ii = id[i], il = id[l];
          bool iBeforeL = (si > sl) || (si == sl && ii < il);
          bool up = ((i & k) == 0);
          if (up ? (!iBeforeL) : iBeforeL) {
            s[i] = sl; s[l] = si; id[i] = il; id[l] = ii;
          }
        }
      }
      __syncthreads();
    }
  }
  for (int r = threadIdx.x; r < K; r += blockDim.x)
    perm[(size_t)b * K + r] = b * n_per + id[r];
  if (mapping) {
    for (int i = threadIdx.x; i < n_per; i += blockDim.x)
      mapping[(size_t)b * n_per + i] = -1;
    __syncthreads();
    for (int r = threadIdx.x; r < K; r += blockDim.x)
      mapping[(size_t)b * n_per + id[r]] = b * K + r;
  }
}

// ---------------- fused gather(+scale) + partial readout over 64-row chunks ----------------
#define RCH 64
__global__ void k_gatherread(const float* __restrict__ h, const float* __restrict__ score,
                             const int* __restrict__ perm, float* __restrict__ xp,
                             float* __restrict__ pmax, float* __restrict__ psum,
                             int K, int nch) {
  int b = blockIdx.x / nch, c = blockIdx.x % nch, f = threadIdx.x;  // 128 threads
  int r0 = c * RCH, r1 = min(r0 + RCH, K);
  float mx = -INFINITY, sm = 0.f;
  if (xp) {
    for (int r = r0; r < r1; ++r) {
      int g = perm[(size_t)b * K + r];
      float v = h[(size_t)g * 128 + f] * score[g];
      xp[((size_t)b * K + r) * 128 + f] = v;
      mx = fmaxf(mx, v); sm += v;
    }
  } else {
    for (int r = r0; r < r1; ++r) {
      int g = perm[(size_t)b * K + r];
      float v = h[(size_t)g * 128 + f] * score[g];
      mx = fmaxf(mx, v); sm += v;
    }
  }
  pmax[((size_t)b * nch + c) * 128 + f] = mx;
  psum[((size_t)b * nch + c) * 128 + f] = sm;
}

// ---------------- layer-2 filtered CSR (per-graph, LDS, no global atomics) ----------------
__global__ __launch_bounds__(1024) void k_csr2(const int* __restrict__ src,
                                               const int* __restrict__ dst,
                                               const int* __restrict__ map,
                                               int* __restrict__ starts2,
                                               int* __restrict__ cnt2,
                                               int* __restrict__ elist2) {
  __shared__ int mloc[8192];   // local kept dst per edge, -1 invalid
  __shared__ int msl[8192];    // local kept src per edge
  __shared__ int h[1024];
  __shared__ int s[1024];
  int g = blockIdx.x, tid = threadIdx.x;
  int base = g * 8192, nb2 = g * K1C;
  h[tid] = 0;
  __syncthreads();
#pragma unroll
  for (int it = 0; it < 8; ++it) {
    int e = base + it * 1024 + tid;
    int ms = map[src[e]], md = map[dst[e]];
    bool valid = (ms >= 0) && (md >= 0);
    int idx = it * 1024 + tid;
    int ml = valid ? (md - nb2) : -1;
    mloc[idx] = ml;
    msl[idx] = ms - nb2;
    if (valid) atomicAdd(&h[ml], 1);
  }
  __syncthreads();
  int v = (tid < K1C) ? h[tid] : 0;
  if (tid < K1C) cnt2[nb2 + tid] = v;
  s[tid] = v;
  __syncthreads();
  for (int o = 1; o < 1024; o <<= 1) {
    int t = (tid >= o) ? s[tid - o] : 0;
    __syncthreads();
    s[tid] += t;
    __syncthreads();
  }
  int st = s[tid] - v;
  if (tid < K1C) starts2[nb2 + tid] = base + st;
  h[tid] = st;                        // local cursor
  __syncthreads();
#pragma unroll
  for (int it = 0; it < 8; ++it) {
    int idx = it * 1024 + tid;
    int ml = mloc[idx];
    if (ml >= 0) {
      int pos = atomicAdd(&h[ml], 1);
      elist2[base + pos] = msl[idx];
    }
  }
}

// ---------------- layer-2 aggregate: LDS-staged xp1 32-feat chunk (105KB), Q=4 ----------------
__global__ __launch_bounds__(1024) void k_agg2s(const int* __restrict__ starts2,
                                                const int* __restrict__ cnt2,
                                                const int* __restrict__ elist2,
                                                const float* __restrict__ xp1,
                                                float* __restrict__ agg2) {
  __shared__ float xls[K1C * 32];     // [row][32 feats] = 104,960 B
  int g = blockIdx.x >> 2, q = blockIdx.x & 3;
  int tid = threadIdx.x;
  int nb2 = g * K1C;
  for (int i = tid; i < K1C * 8; i += 1024) {
    int row = i >> 3, f4 = i & 7;
    ((float4*)xls)[i] = ((const float4*)xp1)[(size_t)(nb2 + row) * 32 + q * 8 + f4];
  }
  __syncthreads();
  int rg = tid >> 5, lane = tid & 31;  // 32 row-groups x 32 feats
  for (int r = rg; r < K1C; r += 32) {
    int s0 = starts2[nb2 + r], n = cnt2[nb2 + r];
    float a0 = 0.f, a1 = 0.f;
    int j = 0;
    for (; j + 1 < n; j += 2) {
      int m0 = elist2[s0 + j], m1 = elist2[s0 + j + 1];
      a0 += xls[m0 * 32 + lane];
      a1 += xls[m1 * 32 + lane];
    }
    if (j < n) a0 += xls[elist2[s0 + j] * 32 + lane];
    agg2[(size_t)(nb2 + r) * 128 + q * 32 + lane] = a0 + a1;
  }
}

// ---------------- h2 GEMM: 128x128 tile, 8x8/thread, BK=16, DOUBLE-BUFFERED LDS ----------------
// One barrier per K-chunk; next chunk's global loads issue before compute (latency hidden).
#define ALDA 130
#define WLDA 132
__global__ __launch_bounds__(256, 4) void k_h2(
    const float* __restrict__ agg2, const float* __restrict__ xp1,
    const float* __restrict__ W2rel, const float* __restrict__ W2root,
    const float* __restrict__ b2, const float* __restrict__ p2,
    const float* __restrict__ invp, float* __restrict__ h2,
    float* __restrict__ score2) {
  __shared__ float As[2][16][ALDA];  // 2 x 8.3 KB
  __shared__ float Ws[2][16][WLDA];  // 2 x 8.4 KB  (total 33.5 KB)
  int tid = threadIdx.x;
  int r0 = blockIdx.x * 128;
  int tx = tid & 15, ty = tid >> 4;   // cols {tx*4, 64+tx*4}, rows ty*8..ty*8+7
  int row0 = tid >> 2, kq = (tid & 3) * 4;
  int kr = tid >> 5, c4 = (tid & 31) * 4;
  float acc[8][8] = {};
  float4 ra0, ra1, rw0, rw1;
  // prologue: stage chunk 0 into buffer 0
  ra0 = *(const float4*)&agg2[(size_t)(r0 + row0) * 128 + kq];
  ra1 = *(const float4*)&agg2[(size_t)(r0 + row0 + 64) * 128 + kq];
  rw0 = *(const float4*)&W2rel[(size_t)kr * 128 + c4];
  rw1 = *(const float4*)&W2rel[(size_t)(kr + 8) * 128 + c4];
  As[0][kq + 0][row0] = ra0.x; As[0][kq + 1][row0] = ra0.y;
  As[0][kq + 2][row0] = ra0.z; As[0][kq + 3][row0] = ra0.w;
  As[0][kq + 0][row0 + 64] = ra1.x; As[0][kq + 1][row0 + 64] = ra1.y;
  As[0][kq + 2][row0 + 64] = ra1.z; As[0][kq + 3][row0 + 64] = ra1.w;
  *(float4*)&Ws[0][kr][c4] = rw0;
  *(float4*)&Ws[0][kr + 8][c4] = rw1;
  __syncthreads();
  for (int ks = 0; ks < 16; ++ks) {
    int cur = ks & 1;
    if (ks + 1 < 16) {                 // issue next chunk's loads (hidden under compute)
      int k2 = ks + 1;
      const float* Asrc = (k2 < 8) ? agg2 : xp1;
      const float* Wsrc = (k2 < 8) ? W2rel : W2root;
      int kof = (k2 & 7) * 16;
      ra0 = *(const float4*)&Asrc[(size_t)(r0 + row0) * 128 + kof + kq];
      ra1 = *(const float4*)&Asrc[(size_t)(r0 + row0 + 64) * 128 + kof + kq];
      rw0 = *(const float4*)&Wsrc[(size_t)(kof + kr) * 128 + c4];
      rw1 = *(const float4*)&Wsrc[(size_t)(kof + kr + 8) * 128 + c4];
    }
#pragma unroll 8
    for (int kk = 0; kk < 16; ++kk) {
      float4 a0 = *(const float4*)&As[cur][kk][ty * 8];
      float4 a1 = *(const float4*)&As[cur][kk][ty * 8 + 4];
      float4 w0 = *(const float4*)&Ws[cur][kk][tx * 4];
      float4 w1 = *(const float4*)&Ws[cur][kk][64 + tx * 4];
      float av[8] = {a0.x, a0.y, a0.z, a0.w, a1.x, a1.y, a1.z, a1.w};
      float wv[8] = {w0.x, w0.y, w0.z, w0.w, w1.x, w1.y, w1.z, w1.w};
#pragma unroll
      for (int i = 0; i < 8; ++i)
#pragma unroll
        for (int j = 0; j < 8; ++j) acc[i][j] += av[i] * wv[j];
    }
    if (ks + 1 < 16) {                 // write next chunk into the other buffer
      int nxt = cur ^ 1;
      As[nxt][kq + 0][row0] = ra0.x; As[nxt][kq + 1][row0] = ra0.y;
      As[nxt][kq + 2][row0] = ra0.z; As[nxt][kq + 3][row0] = ra0.w;
      As[nxt][kq + 0][row0 + 64] = ra1.x; As[nxt][kq + 1][row0 + 64] = ra1.y;
      As[nxt][kq + 2][row0 + 64] = ra1.z; As[nxt][kq + 3][row0 + 64] = ra1.w;
      *(float4*)&Ws[nxt][kr][c4] = rw0;
      *(float4*)&Ws[nxt][kr + 8][c4] = rw1;
    }
    __syncthreads();                   // single barrier per chunk
  }
  float4 bb0 = *(const float4*)&b2[tx * 4];
  float4 bb1 = *(const float4*)&b2[64 + tx * 4];
  float4 pp0 = *(const float4*)&p2[tx * 4];
  float4 pp1 = *(const float4*)&p2[64 + tx * 4];
  float bbv[8] = {bb0.x, bb0.y, bb0.z, bb0.w, bb1.x, bb1.y, bb1.z, bb1.w};
  float pbv[8] = {pp0.x, pp0.y, pp0.z, pp0.w, pp1.x, pp1.y, pp1.z, pp1.w};
  float inv = invp[1];
#pragma unroll
  for (int i = 0; i < 8; ++i) {
    int row = r0 + ty * 8 + i;
    float o[8], dot = 0.f;
#pragma unroll
    for (int j = 0; j < 8; ++j) {
      o[j] = fmaxf(acc[i][j] + bbv[j], 0.f);
      dot += o[j] * pbv[j];
    }
    *(float4*)&h2[(size_t)row * 128 + tx * 4] = make_float4(o[0], o[1], o[2], o[3]);
    *(float4*)&h2[(size_t)row * 128 + 64 + tx * 4] = make_float4(o[4], o[5], o[6], o[7]);
#pragma unroll
    for (int off = 8; off > 0; off >>= 1) dot += __shfl_down(dot, off, 16);
    if (tx == 0) score2[row] = tanhf(dot * inv);
  }
}

// ---------------- target conv + relu + avgpool -> xs[t][b][o] ----------------
__global__ void k_conv(const float* __restrict__ target, const float* __restrict__ Wc,
                       const float* __restrict__ bc, float* __restrict__ xs) {
  int gb = blockIdx.x;               // B*19
  int b = gb / TSEQ, tt = gb % TSEQ;
  int o = threadIdx.x;               // 128
  __shared__ float tg[30][8];
  for (int i = threadIdx.x; i < 210; i += 128) {
    int ch = i / 7, u = i % 7;
    tg[ch][u] = target[((size_t)b * 30 + ch) * 101 + tt * 5 + u];
  }
  __syncthreads();
  const float* w = Wc + (size_t)o * 90;
  float acc5[5] = {0, 0, 0, 0, 0};
  for (int ch = 0; ch < 30; ++ch) {
    float w0 = w[ch * 3], w1 = w[ch * 3 + 1], w2 = w[ch * 3 + 2];
#pragma unroll
    for (int u = 0; u < 5; ++u)
      acc5[u] += tg[ch][u] * w0 + tg[ch][u + 1] * w1 + tg[ch][u + 2] * w2;
  }
  float bo = bc[o], s = 0.f;
#pragma unroll
  for (int u = 0; u < 5; ++u) s += fmaxf(acc5[u] + bo, 0.f);
  xs[((size_t)tt * BB + b) * 128 + o] = s * 0.2f;
}

// ---------------- gi = xs @ Wih^T + bih; 16 batches per block ----------------
#define GIB 16
__global__ __launch_bounds__(384) void k_gi(const float* __restrict__ xs,
                     const float* __restrict__ Wihf, const float* __restrict__ bihf,
                     const float* __restrict__ Wihb, const float* __restrict__ bihb,
                     float* __restrict__ gi) {
  int bg = blockIdx.x & 7;
  int t = (blockIdx.x >> 3) % TSEQ;
  int dir = blockIdx.x / (8 * TSEQ);
  int b0 = bg * GIB;
  __shared__ float xst[GIB][128];
  int tid = threadIdx.x;
  for (int i = tid; i < GIB * 128; i += 384) {
    int bb = i >> 7, k = i & 127;
    xst[bb][k] = xs[((size_t)t * BB + b0 + bb) * 128 + k];
  }
  __syncthreads();
  int j = tid;
  if (j < 360) {
    const float* W = (dir ? Wihb : Wihf) + (size_t)j * 128;
    float bias = (dir ? bihb : bihf)[j];
    float acc[GIB];
#pragma unroll
    for (int bb = 0; bb < GIB; ++bb) acc[bb] = bias;
#pragma unroll 4
    for (int k = 0; k < 128; ++k) {
      float w = W[k];
#pragma unroll
      for (int bb = 0; bb < GIB; ++bb) acc[bb] += xst[bb][k] * w;
    }
    size_t base = ((size_t)dir * TSEQ + t) * BB + b0;
#pragma unroll
    for (int bb = 0; bb < GIB; ++bb) gi[(base + bb) * 360 + j] = acc[bb];
  }
}

// ---------------- GRU recurrence: Whh rows held in REGISTERS, h via LDS broadcast ----------------
__global__ __launch_bounds__(384) void k_gru(const float* __restrict__ gi,
                      const float* __restrict__ Whhf, const float* __restrict__ bhhf,
                      const float* __restrict__ Whhb, const float* __restrict__ bhhb,
                      float* __restrict__ xc) {
  int pair = blockIdx.x & 63, dir = blockIdx.x >> 6;
  int b0 = pair * 2;
  const float* Whh = dir ? Whhb : Whhf;
  const float* bhh = dir ? bhhb : bhhf;
  __shared__ float h_sh[2][HID];
  __shared__ float g0[360], g1[360];
  int j = threadIdx.x;               // 384
  float wrow[HID];
  float bias = 0.f;
  if (j < 360) {
    const float4* W4 = (const float4*)(Whh + (size_t)j * HID);
#pragma unroll
    for (int k4 = 0; k4 < HID / 4; ++k4) {
      float4 w = W4[k4];
      wrow[k4 * 4 + 0] = w.x; wrow[k4 * 4 + 1] = w.y;
      wrow[k4 * 4 + 2] = w.z; wrow[k4 * 4 + 3] = w.w;
    }
    bias = bhh[j];
  }
  if (j < 2 * HID) h_sh[j / HID][j % HID] = 0.f;
  __syncthreads();
  for (int st = 0; st < TSEQ; ++st) {
    int tt = dir ? (TSEQ - 1 - st) : st;
    if (j < 360) {
      float a0 = bias, a1 = bias;
      const float4* h40 = (const float4*)h_sh[0];
      const float4* h41 = (const float4*)h_sh[1];
#pragma unroll
      for (int k4 = 0; k4 < HID / 4; ++k4) {
        float4 v0 = h40[k4];
        float4 v1 = h41[k4];
        a0 += wrow[k4*4+0]*v0.x + wrow[k4*4+1]*v0.y + wrow[k4*4+2]*v0.z + wrow[k4*4+3]*v0.w;
        a1 += wrow[k4*4+0]*v1.x + wrow[k4*4+1]*v1.y + wrow[k4*4+2]*v1.z + wrow[k4*4+3]*v1.w;
      }
      g0[j] = a0; g1[j] = a1;
    }
    __syncthreads();
    if (j < 2 * HID) {
      int bb = j / HID, th = j - bb * HID;
      const float* g = gi + (((size_t)dir * TSEQ + tt) * BB + (b0 + bb)) * 360;
      const float* gh = bb ? g1 : g0;
      float r  = 1.f / (1.f + expf(-(g[th]       + gh[th])));
      float z  = 1.f / (1.f + expf(-(g[120 + th] + gh[120 + th])));
      float ng = tanhf(g[240 + th] + r * gh[240 + th]);
      float hn = (1.f - z) * ng + z * h_sh[bb][th];
      h_sh[bb][th] = hn;
      xc[(size_t)(b0 + bb) * 4816 + 256 + (size_t)tt * 240 + dir * 120 + th] = hn;
    }
    __syncthreads();
  }
}

// ---------------- fused final readout: xc[:, :256] = x1 + x2 from partials ----------------
__global__ void k_xg(const float* __restrict__ pmax1, const float* __restrict__ psum1,
                     const float* __restrict__ pmax2, const float* __restrict__ psum2,
                     float* __restrict__ xc) {
  int b = blockIdx.x, f = threadIdx.x;  // 128 threads
  float mx1 = -INFINITY, sm1 = 0.f;
  for (int c = 0; c < NCH1; ++c) {
    mx1 = fmaxf(mx1, pmax1[((size_t)b * NCH1 + c) * 128 + f]);
    sm1 += psum1[((size_t)b * NCH1 + c) * 128 + f];
  }
  float mx2 = -INFINITY, sm2 = 0.f;
  for (int c = 0; c < NCH2; ++c) {
    mx2 = fmaxf(mx2, pmax2[((size_t)b * NCH2 + c) * 128 + f]);
    sm2 += psum2[((size_t)b * NCH2 + c) * 128 + f];
  }
  xc[(size_t)b * 4816 + f] = mx1 + mx2;
  xc[(size_t)b * 4816 + 128 + f] = sm1 / (float)K1C + sm2 / (float)K2C;
}

// ---------------- d1 partial GEMM ----------------
__global__ __launch_bounds__(128) void k_d1(const float* __restrict__ xc,
                                            const float* __restrict__ Wd1,
                                            float* __restrict__ part) {
  int c = blockIdx.x % D1CH;
  int rg = blockIdx.x / D1CH;
  int k0 = c * 128, kn = min(128, D1K - k0);
  __shared__ float xcs[8][128];
  int tid = threadIdx.x;
#pragma unroll
  for (int l = 0; l < 8; ++l) {
    int i = tid + l * 128;
    int r = i >> 7, k = i & 127;
    xcs[r][k] = (k < kn) ? xc[(size_t)(rg * 8 + r) * D1K + k0 + k] : 0.f;
  }
  __syncthreads();
  int j = tid;
  if (j < 102) {
    float acc[8] = {};
    for (int k = 0; k < kn; ++k) {
      float w = Wd1[(size_t)(k0 + k) * 102 + j];
#pragma unroll
      for (int r = 0; r < 8; ++r) acc[r] += xcs[r][k] * w;
    }
#pragma unroll
    for (int r = 0; r < 8; ++r)
      part[((size_t)(rg * 8 + r) * D1CH + c) * 102 + j] = acc[r];
  }
}

// ---------------- reduce partials + relu + d3 + log_softmax ----------------
__global__ void k_final2(const float* __restrict__ part, const float* __restrict__ bd1,
                         const float* __restrict__ Wd3, const float* __restrict__ bd3,
                         float* __restrict__ out) {
  __shared__ float tmp2[2];
  int b = blockIdx.x, j = threadIdx.x;
  float v = 0.f;
  if (j < 102) {
    float acc = bd1[j];
    for (int c = 0; c < D1CH; ++c) acc += part[((size_t)b * D1CH + c) * 102 + j];
    v = fmaxf(acc, 0.f);
  }
  float c0 = (j < 102) ? v * Wd3[j * 2] : 0.f;
  float c1 = (j < 102) ? v * Wd3[j * 2 + 1] : 0.f;
  float z0 = blockReduceSum128(c0, tmp2) + bd3[0];
  float z1 = blockReduceSum128(c1, tmp2) + bd3[1];
  if (j < 2) {
    float m = fmaxf(z0, z1);
    float lse = m + logf(expf(z0 - m) + expf(z1 - m));
    out[b * 2 + j] = (j == 0 ? z0 : z1) - lse;
  }
}

// ---------------- launch ----------------
extern "C" void kernel_launch(void* const* d_in, const int* in_sizes, int n_in,
                              void* d_out, int out_size, void* d_ws, size_t ws_size,
                              hipStream_t stream) {
  const float* x      = (const float*)d_in[0];
  const float* target = (const float*)d_in[1];
  const int*   esrc   = (const int*)d_in[2];
  const int*   edst   = (const int*)d_in[3];
  const float* W1rel  = (const float*)d_in[4];
  const float* W1root = (const float*)d_in[5];
  const float* b1     = (const float*)d_in[6];
  const float* p1     = (const float*)d_in[7];
  const float* W2rel  = (const float*)d_in[8];
  const float* W2root = (const float*)d_in[9];
  const float* b2     = (const float*)d_in[10];
  const float* p2     = (const float*)d_in[11];
  const float* Wc     = (const float*)d_in[12];
  const float* bc     = (const float*)d_in[13];
  const float* Wihf   = (const float*)d_in[14];
  const float* Whhf   = (const float*)d_in[15];
  const float* bihf   = (const float*)d_in[16];
  const float* bhhf   = (const float*)d_in[17];
  const float* Wihb   = (const float*)d_in[18];
  const float* Whhb   = (const float*)d_in[19];
  const float* bihb   = (const float*)d_in[20];
  const float* bhhb   = (const float*)d_in[21];
  const float* Wd1    = (const float*)d_in[22];
  const float* bd1    = (const float*)d_in[23];
  const float* Wd3    = (const float*)d_in[24];
  const float* bd3    = (const float*)d_in[25];
  float* out = (float*)d_out;

  char* wsb = (char*)d_ws;
  size_t off = 0;
  auto alloc = [&](size_t bytes) -> void* {
    void* p = wsb + off;
    off = (off + bytes + 255) & ~(size_t)255;
    return p;
  };
  float* regH    = (float*)alloc((size_t)BN * 128 * 4);   // h1 / agg2 (64MB)
  float* agg1    = (float*)alloc((size_t)BN * 4 * 4);
  float* score1  = (float*)alloc((size_t)BN * 4);
  int*   perm1   = (int*)  alloc((size_t)BB * K1C * 4);
  int*   map1    = (int*)  alloc((size_t)BN * 4);
  float* xp1     = (float*)alloc((size_t)BB * K1C * 128 * 4);
  float* h2      = (float*)alloc((size_t)BB * K1C * 128 * 4);
  float* score2  = (float*)alloc((size_t)BB * K1C * 4);
  int*   perm2   = (int*)  alloc((size_t)BB * K2C * 4);
  float* invp    = (float*)alloc(256);
  float* xs      = (float*)alloc((size_t)TSEQ * BB * 128 * 4);
  float* gi      = (float*)alloc((size_t)2 * TSEQ * BB * 360 * 4);
  float* xc      = (float*)alloc((size_t)BB * 4816 * 4);
  int*   starts2 = (int*)  alloc((size_t)BB * K1C * 4);
  int*   cnt2    = (int*)  alloc((size_t)BB * K1C * 4);
  int*   elist2  = (int*)  alloc((size_t)EDG * 4);
  float* pmax1   = (float*)alloc((size_t)BB * NCH1 * 128 * 4);
  float* psum1   = (float*)alloc((size_t)BB * NCH1 * 128 * 4);
  float* pmax2   = (float*)alloc((size_t)BB * NCH2 * 128 * 4);
  float* psum2   = (float*)alloc((size_t)BB * NCH2 * 128 * 4);
  float* part    = (float*)alloc((size_t)BB * D1CH * 102 * 4);
  float* h1   = regH;
  float* agg2 = regH;

  k_pnorm<<<1, 128, 0, stream>>>(p1, p2, invp);

  // --- layer 1 (CSR build + aggregate fused, CSR lives in LDS only) ---
  k_l1<<<BB, 1024, 0, stream>>>(esrc, edst, x, agg1);
  k_h1<<<BN * 32 / 256, 256, 0, stream>>>(x, agg1, W1rel, W1root, b1, p1, invp, h1, score1);
  k_sort<<<BB, 512, 0, stream>>>(score1, NN, K1C, perm1, map1);
  k_gatherread<<<BB * NCH1, 128, 0, stream>>>(h1, score1, perm1, xp1, pmax1, psum1, K1C, NCH1);

  // --- layer 2: filtered CSR + LDS-staged aggregate ---
  k_csr2<<<BB, 1024, 0, stream>>>(esrc, edst, map1, starts2, cnt2, elist2);
  k_agg2s<<<BB * 4, 1024, 0, stream>>>(starts2, cnt2, elist2, xp1, agg2);
  k_h2<<<(BB * K1C) / 128, 256, 0, stream>>>(agg2, xp1, W2rel, W2root, b2, p2, invp, h2, score2);
  k_sort<<<BB, 512, 0, stream>>>(score2, K1C, K2C, perm2, nullptr);
  k_gatherread<<<BB * NCH2, 128, 0, stream>>>(h2, score2, perm2, nullptr, pmax2, psum2, K2C, NCH2);

  // --- target branch ---
  k_conv<<<BB * TSEQ, 128, 0, stream>>>(target, Wc, bc, xs);
  k_gi<<<2 * TSEQ * 8, 384, 0, stream>>>(xs, Wihf, bihf, Wihb, bihb, gi);
  k_gru<<<2 * 64, 384, 0, stream>>>(gi, Whhf, bhhf, Whhb, bhhb, xc);

  // --- head ---
  k_xg<<<BB, 128, 0, stream>>>(pmax1, psum1, pmax2, psum2, xc);
  k_d1<<<(BB / 8) * D1CH, 128, 0, stream>>>(xc, Wd1, part);
  k_final2<<<BB, 128, 0, stream>>>(part, bd1, Wd3, bd3, out);
}

// Round 13
// 427.287 us; speedup vs baseline: 1.2744x; 1.1086x over previous
//
#include <hip/hip_runtime.h>
#include <math.h>

#define BB   128
#define NN   1024
#define BN   (BB*NN)          // 131072
#define EDG  (BB*8192)        // 1048576
#define K1C  820
#define K2C  656
#define TSEQ 19
#define HID  120
#define D1K  4816
#define D1CH 38               // ceil(4816/128)
#define NCH1 13               // ceil(820/64)
#define NCH2 11               // ceil(656/64)

// ---------------- reduction helper (128-thread block) ----------------
__device__ __forceinline__ float blockReduceSum128(float v, float* tmp2) {
#pragma unroll
  for (int o = 32; o > 0; o >>= 1) v += __shfl_down(v, o);
  int lane = threadIdx.x & 63, w = threadIdx.x >> 6;
  if (lane == 0) tmp2[w] = v;
  __syncthreads();
  float r = tmp2[0] + tmp2[1];
  __syncthreads();
  return r;
}

// ---------------- p-norm precompute ----------------
__global__ void k_pnorm(const float* __restrict__ p1, const float* __restrict__ p2,
                        float* __restrict__ invp) {
  __shared__ float tmp2[2];
  float a = p1[threadIdx.x], b = p2[threadIdx.x];
  float s1 = blockReduceSum128(a * a, tmp2);
  float s2 = blockReduceSum128(b * b, tmp2);
  if (threadIdx.x == 0) { invp[0] = 1.f / sqrtf(s1); invp[1] = 1.f / sqrtf(s2); }
}

// ---------------- fused layer-1 CSR build + aggregate (all in LDS) ----------------
__global__ __launch_bounds__(1024) void k_l1(const int* __restrict__ src,
                                             const int* __restrict__ dst,
                                             const float* __restrict__ x,
                                             float* __restrict__ agg1) {
  __shared__ int hcur[1024];
  __shared__ int sscan[1024];
  __shared__ int ccnt[1024];
  __shared__ int el[8192];
  __shared__ float4 xls4[1024];
  int b = blockIdx.x, tid = threadIdx.x;
  int base = b * 8192, nb = b * 1024;
  hcur[tid] = 0;
  __syncthreads();
#pragma unroll
  for (int it = 0; it < 8; ++it)
    atomicAdd(&hcur[dst[base + it * 1024 + tid] - nb], 1);
  __syncthreads();
  int v = hcur[tid];
  ccnt[tid] = v;
  sscan[tid] = v;
  __syncthreads();
  for (int o = 1; o < 1024; o <<= 1) {
    int t = (tid >= o) ? sscan[tid - o] : 0;
    __syncthreads();
    sscan[tid] += t;
    __syncthreads();
  }
  hcur[tid] = sscan[tid] - v;          // exclusive start (local cursor)
  __syncthreads();
#pragma unroll
  for (int it = 0; it < 8; ++it) {
    int e = base + it * 1024 + tid;
    int d = dst[e] - nb;
    int pos = atomicAdd(&hcur[d], 1);
    el[pos] = src[e] - nb;             // LOCAL src id
  }
  xls4[tid] = ((const float4*)x)[nb + tid];
  __syncthreads();
  const float* xls = (const float*)xls4;
  int rg = tid >> 2, lane = tid & 3;
#pragma unroll
  for (int it = 0; it < 4; ++it) {
    int r = rg + it * 256;
    int n = ccnt[r], s0 = sscan[r] - n;
    float a0 = 0.f, a1 = 0.f;
    int j = 0;
    for (; j + 1 < n; j += 2) {
      a0 += xls[el[s0 + j] * 4 + lane];
      a1 += xls[el[s0 + j + 1] * 4 + lane];
    }
    if (j < n) a0 += xls[el[s0 + j] * 4 + lane];
    agg1[(size_t)(nb + r) * 4 + lane] = a0 + a1;
  }
}

// ---------------- h1 = relu(agg1@W1rel + x@W1root + b1); score1 fused ----------------
__global__ void k_h1(const float* __restrict__ x, const float* __restrict__ agg1,
                     const float* __restrict__ W1rel, const float* __restrict__ W1root,
                     const float* __restrict__ b1, const float* __restrict__ p1,
                     const float* __restrict__ invp,
                     float* __restrict__ h1, float* __restrict__ score1) {
  int tid = blockIdx.x * 256 + threadIdx.x;
  int r = tid >> 5, lane = tid & 31, f4 = lane * 4;
  float4 a = ((const float4*)agg1)[r];
  float4 xv = ((const float4*)x)[r];
  float o[4], dot = 0.f;
#pragma unroll
  for (int j = 0; j < 4; ++j) {
    int f = f4 + j;
    float acc = b1[f]
      + a.x * W1rel[f] + a.y * W1rel[128 + f] + a.z * W1rel[256 + f] + a.w * W1rel[384 + f]
      + xv.x * W1root[f] + xv.y * W1root[128 + f] + xv.z * W1root[256 + f] + xv.w * W1root[384 + f];
    o[j] = fmaxf(acc, 0.f);
    dot += o[j] * p1[f];
  }
  *(float4*)&h1[(size_t)r * 128 + f4] = make_float4(o[0], o[1], o[2], o[3]);
#pragma unroll
  for (int off = 16; off > 0; off >>= 1) dot += __shfl_down(dot, off, 32);
  if (lane == 0) score1[r] = tanhf(dot * invp[0]);
}

// ---------------- per-graph top-k via LDS bitonic sort (1024 slots) ----------------
__global__ void k_sort(const float* __restrict__ score, int n_per, int K,
                       int* __restrict__ perm, int* __restrict__ mapping) {
  __shared__ float s[1024];
  __shared__ int   id[1024];
  int b = blockIdx.x;
  const float* sc = score + (size_t)b * n_per;
  for (int i = threadIdx.x; i < 1024; i += blockDim.x) {
    if (i < n_per) { s[i] = sc[i]; id[i] = i; }
    else           { s[i] = -INFINITY; id[i] = 0x7fffffff; }
  }
  __syncthreads();
  for (int k = 2; k <= 1024; k <<= 1) {
    for (int j = k >> 1; j > 0; j >>= 1) {
      for (int i = threadIdx.x; i < 1024; i += blockDim.x) {
        int l = i ^ j;
        if (l > i) {
          float si = s[i], sl = s[l];
          int ii = id[i], il = id[l];
          bool iBeforeL = (si > sl) || (si == sl && ii < il);
          bool up = ((i & k) == 0);
          if (up ? (!iBeforeL) : iBeforeL) {
            s[i] = sl; s[l] = si; id[i] = il; id[l] = ii;
          }
        }
      }
      __syncthreads();
    }
  }
  for (int r = threadIdx.x; r < K; r += blockDim.x)
    perm[(size_t)b * K + r] = b * n_per + id[r];
  if (mapping) {
    for (int i = threadIdx.x; i < n_per; i += blockDim.x)
      mapping[(size_t)b * n_per + i] = -1;
    __syncthreads();
    for (int r = threadIdx.x; r < K; r += blockDim.x)
      mapping[(size_t)b * n_per + id[r]] = b * K + r;
  }
}

// ---------------- fused gather(+scale) + partial readout over 64-row chunks ----------------
#define RCH 64
__global__ void k_gatherread(const float* __restrict__ h, const float* __restrict__ score,
                             const int* __restrict__ perm, float* __restrict__ xp,
                             float* __restrict__ pmax, float* __restrict__ psum,
                             int K, int nch) {
  int b = blockIdx.x / nch, c = blockIdx.x % nch, f = threadIdx.x;  // 128 threads
  int r0 = c * RCH, r1 = min(r0 + RCH, K);
  float mx = -INFINITY, sm = 0.f;
  if (xp) {
    for (int r = r0; r < r1; ++r) {
      int g = perm[(size_t)b * K + r];
      float v = h[(size_t)g * 128 + f] * score[g];
      xp[((size_t)b * K + r) * 128 + f] = v;
      mx = fmaxf(mx, v); sm += v;
    }
  } else {
    for (int r = r0; r < r1; ++r) {
      int g = perm[(size_t)b * K + r];
      float v = h[(size_t)g * 128 + f] * score[g];
      mx = fmaxf(mx, v); sm += v;
    }
  }
  pmax[((size_t)b * nch + c) * 128 + f] = mx;
  psum[((size_t)b * nch + c) * 128 + f] = sm;
}

// ---------------- layer-2 filtered CSR (per-graph, LDS, no global atomics) ----------------
__global__ __launch_bounds__(1024) void k_csr2(const int* __restrict__ src,
                                               const int* __restrict__ dst,
                                               const int* __restrict__ map,
                                               int* __restrict__ starts2,
                                               int* __restrict__ cnt2,
                                               int* __restrict__ elist2) {
  __shared__ int mloc[8192];   // local kept dst per edge, -1 invalid
  __shared__ int msl[8192];    // local kept src per edge
  __shared__ int h[1024];
  __shared__ int s[1024];
  int g = blockIdx.x, tid = threadIdx.x;
  int base = g * 8192, nb2 = g * K1C;
  h[tid] = 0;
  __syncthreads();
#pragma unroll
  for (int it = 0; it < 8; ++it) {
    int e = base + it * 1024 + tid;
    int ms = map[src[e]], md = map[dst[e]];
    bool valid = (ms >= 0) && (md >= 0);
    int idx = it * 1024 + tid;
    int ml = valid ? (md - nb2) : -1;
    mloc[idx] = ml;
    msl[idx] = ms - nb2;
    if (valid) atomicAdd(&h[ml], 1);
  }
  __syncthreads();
  int v = (tid < K1C) ? h[tid] : 0;
  if (tid < K1C) cnt2[nb2 + tid] = v;
  s[tid] = v;
  __syncthreads();
  for (int o = 1; o < 1024; o <<= 1) {
    int t = (tid >= o) ? s[tid - o] : 0;
    __syncthreads();
    s[tid] += t;
    __syncthreads();
  }
  int st = s[tid] - v;
  if (tid < K1C) starts2[nb2 + tid] = base + st;
  h[tid] = st;                        // local cursor
  __syncthreads();
#pragma unroll
  for (int it = 0; it < 8; ++it) {
    int idx = it * 1024 + tid;
    int ml = mloc[idx];
    if (ml >= 0) {
      int pos = atomicAdd(&h[ml], 1);
      elist2[base + pos] = msl[idx];
    }
  }
}

// ---------------- layer-2 aggregate: xp1 chunk + FULL edge list staged in LDS (144KB) ----------------
__global__ __launch_bounds__(1024) void k_agg2s(const int* __restrict__ starts2,
                                                const int* __restrict__ cnt2,
                                                const int* __restrict__ elist2,
                                                const float* __restrict__ xp1,
                                                float* __restrict__ agg2) {
  __shared__ float xls[K1C * 32];     // 104,960 B
  __shared__ int   el[8192];          // 32,768 B
  __shared__ int   sts[K1C];          // 3,280 B
  __shared__ int   ctn[K1C];          // 3,280 B
  int g = blockIdx.x >> 2, q = blockIdx.x & 3;
  int tid = threadIdx.x;
  int nb2 = g * K1C, base = g * 8192;
  for (int i = tid; i < K1C * 8; i += 1024) {
    int row = i >> 3, f4 = i & 7;
    ((float4*)xls)[i] = ((const float4*)xp1)[(size_t)(nb2 + row) * 32 + q * 8 + f4];
  }
  {
    const int4* esrc4 = (const int4*)(elist2 + base);
    for (int i = tid; i < 2048; i += 1024) ((int4*)el)[i] = esrc4[i];
  }
  for (int i = tid; i < K1C; i += 1024) {
    sts[i] = starts2[nb2 + i] - base;
    ctn[i] = cnt2[nb2 + i];
  }
  __syncthreads();
  int rg = tid >> 5, lane = tid & 31;  // 32 row-groups x 32 feats
  for (int r = rg; r < K1C; r += 32) {
    int s0 = sts[r], n = ctn[r];
    float a0 = 0.f, a1 = 0.f, a2 = 0.f, a3 = 0.f;
    int j = 0;
    for (; j + 3 < n; j += 4) {
      a0 += xls[el[s0 + j] * 32 + lane];
      a1 += xls[el[s0 + j + 1] * 32 + lane];
      a2 += xls[el[s0 + j + 2] * 32 + lane];
      a3 += xls[el[s0 + j + 3] * 32 + lane];
    }
    for (; j < n; ++j) a0 += xls[el[s0 + j] * 32 + lane];
    agg2[(size_t)(nb2 + r) * 128 + q * 32 + lane] = (a0 + a1) + (a2 + a3);
  }
}

// ---------------- h2 GEMM: 128x128 tile, 8x8/thread, BK=16, 4 blocks/CU (round-9 proven) ----------------
#define ALDA 130
#define WLDA 132
__global__ __launch_bounds__(256, 4) void k_h2(
    const float* __restrict__ agg2, const float* __restrict__ xp1,
    const float* __restrict__ W2rel, const float* __restrict__ W2root,
    const float* __restrict__ b2, const float* __restrict__ p2,
    const float* __restrict__ invp, float* __restrict__ h2,
    float* __restrict__ score2) {
  __shared__ float As[16][ALDA];     // [k][row], 8.3 KB
  __shared__ float Ws[16][WLDA];     // [k][col], 8.4 KB
  int tid = threadIdx.x;
  int r0 = blockIdx.x * 128;
  int tx = tid & 15, ty = tid >> 4;  // cols {tx*4, 64+tx*4}, rows ty*8..ty*8+7
  float acc[8][8] = {};
  for (int ks = 0; ks < 16; ++ks) {
    const float* Asrc = (ks < 8) ? agg2 : xp1;
    const float* Wsrc = (ks < 8) ? W2rel : W2root;
    int kof = (ks & 7) * 16;
#pragma unroll
    for (int l = 0; l < 2; ++l) {
      int idx = l * 256 + tid;
      int row = idx >> 2, kq = (idx & 3) * 4;
      float4 v = *(const float4*)&Asrc[(size_t)(r0 + row) * 128 + kof + kq];
      As[kq + 0][row] = v.x; As[kq + 1][row] = v.y;
      As[kq + 2][row] = v.z; As[kq + 3][row] = v.w;
    }
#pragma unroll
    for (int l = 0; l < 2; ++l) {
      int idx = l * 256 + tid;
      int kr = idx >> 5, c4 = (idx & 31) * 4;
      *(float4*)&Ws[kr][c4] = *(const float4*)&Wsrc[(size_t)(kof + kr) * 128 + c4];
    }
    __syncthreads();
#pragma unroll 8
    for (int kk = 0; kk < 16; ++kk) {
      float4 a0 = *(const float4*)&As[kk][ty * 8];
      float4 a1 = *(const float4*)&As[kk][ty * 8 + 4];
      float4 w0 = *(const float4*)&Ws[kk][tx * 4];
      float4 w1 = *(const float4*)&Ws[kk][64 + tx * 4];
      float av[8] = {a0.x, a0.y, a0.z, a0.w, a1.x, a1.y, a1.z, a1.w};
      float wv[8] = {w0.x, w0.y, w0.z, w0.w, w1.x, w1.y, w1.z, w1.w};
#pragma unroll
      for (int i = 0; i < 8; ++i)
#pragma unroll
        for (int j = 0; j < 8; ++j) acc[i][j] += av[i] * wv[j];
    }
    __syncthreads();
  }
  float4 bb0 = *(const float4*)&b2[tx * 4];
  float4 bb1 = *(const float4*)&b2[64 + tx * 4];
  float4 pp0 = *(const float4*)&p2[tx * 4];
  float4 pp1 = *(const float4*)&p2[64 + tx * 4];
  float bbv[8] = {bb0.x, bb0.y, bb0.z, bb0.w, bb1.x, bb1.y, bb1.z, bb1.w};
  float pbv[8] = {pp0.x, pp0.y, pp0.z, pp0.w, pp1.x, pp1.y, pp1.z, pp1.w};
  float inv = invp[1];
#pragma unroll
  for (int i = 0; i < 8; ++i) {
    int row = r0 + ty * 8 + i;
    float o[8], dot = 0.f;
#pragma unroll
    for (int j = 0; j < 8; ++j) {
      o[j] = fmaxf(acc[i][j] + bbv[j], 0.f);
      dot += o[j] * pbv[j];
    }
    *(float4*)&h2[(size_t)row * 128 + tx * 4] = make_float4(o[0], o[1], o[2], o[3]);
    *(float4*)&h2[(size_t)row * 128 + 64 + tx * 4] = make_float4(o[4], o[5], o[6], o[7]);
#pragma unroll
    for (int off = 8; off > 0; off >>= 1) dot += __shfl_down(dot, off, 16);
    if (tx == 0) score2[row] = tanhf(dot * inv);
  }
}

// ---------------- target conv + relu + avgpool -> xs[t][b][o] ----------------
__global__ void k_conv(const float* __restrict__ target, const float* __restrict__ Wc,
                       const float* __restrict__ bc, float* __restrict__ xs) {
  int gb = blockIdx.x;               // B*19
  int b = gb / TSEQ, tt = gb % TSEQ;
  int o = threadIdx.x;               // 128
  __shared__ float tg[30][8];
  for (int i = threadIdx.x; i < 210; i += 128) {
    int ch = i / 7, u = i % 7;
    tg[ch][u] = target[((size_t)b * 30 + ch) * 101 + tt * 5 + u];
  }
  __syncthreads();
  const float* w = Wc + (size_t)o * 90;
  float acc5[5] = {0, 0, 0, 0, 0};
  for (int ch = 0; ch < 30; ++ch) {
    float w0 = w[ch * 3], w1 = w[ch * 3 + 1], w2 = w[ch * 3 + 2];
#pragma unroll
    for (int u = 0; u < 5; ++u)
      acc5[u] += tg[ch][u] * w0 + tg[ch][u + 1] * w1 + tg[ch][u + 2] * w2;
  }
  float bo = bc[o], s = 0.f;
#pragma unroll
  for (int u = 0; u < 5; ++u) s += fmaxf(acc5[u] + bo, 0.f);
  xs[((size_t)tt * BB + b) * 128 + o] = s * 0.2f;
}

// ---------------- gi = xs @ Wih^T + bih; 16 batches per block ----------------
#define GIB 16
__global__ __launch_bounds__(384) void k_gi(const float* __restrict__ xs,
                     const float* __restrict__ Wihf, const float* __restrict__ bihf,
                     const float* __restrict__ Wihb, const float* __restrict__ bihb,
                     float* __restrict__ gi) {
  int bg = blockIdx.x & 7;
  int t = (blockIdx.x >> 3) % TSEQ;
  int dir = blockIdx.x / (8 * TSEQ);
  int b0 = bg * GIB;
  __shared__ float xst[GIB][128];
  int tid = threadIdx.x;
  for (int i = tid; i < GIB * 128; i += 384) {
    int bb = i >> 7, k = i & 127;
    xst[bb][k] = xs[((size_t)t * BB + b0 + bb) * 128 + k];
  }
  __syncthreads();
  int j = tid;
  if (j < 360) {
    const float* W = (dir ? Wihb : Wihf) + (size_t)j * 128;
    float bias = (dir ? bihb : bihf)[j];
    float acc[GIB];
#pragma unroll
    for (int bb = 0; bb < GIB; ++bb) acc[bb] = bias;
#pragma unroll 4
    for (int k = 0; k < 128; ++k) {
      float w = W[k];
#pragma unroll
      for (int bb = 0; bb < GIB; ++bb) acc[bb] += xst[bb][k] * w;
    }
    size_t base = ((size_t)dir * TSEQ + t) * BB + b0;
#pragma unroll
    for (int bb = 0; bb < GIB; ++bb) gi[(base + bb) * 360 + j] = acc[bb];
  }
}

// ---------------- GRU recurrence: Whh rows held in REGISTERS, h via LDS broadcast ----------------
__global__ __launch_bounds__(384) void k_gru(const float* __restrict__ gi,
                      const float* __restrict__ Whhf, const float* __restrict__ bhhf,
                      const float* __restrict__ Whhb, const float* __restrict__ bhhb,
                      float* __restrict__ xc) {
  int pair = blockIdx.x & 63, dir = blockIdx.x >> 6;
  int b0 = pair * 2;
  const float* Whh = dir ? Whhb : Whhf;
  const float* bhh = dir ? bhhb : bhhf;
  __shared__ float h_sh[2][HID];
  __shared__ float g0[360], g1[360];
  int j = threadIdx.x;               // 384
  float wrow[HID];
  float bias = 0.f;
  if (j < 360) {
    const float4* W4 = (const float4*)(Whh + (size_t)j * HID);
#pragma unroll
    for (int k4 = 0; k4 < HID / 4; ++k4) {
      float4 w = W4[k4];
      wrow[k4 * 4 + 0] = w.x; wrow[k4 * 4 + 1] = w.y;
      wrow[k4 * 4 + 2] = w.z; wrow[k4 * 4 + 3] = w.w;
    }
    bias = bhh[j];
  }
  if (j < 2 * HID) h_sh[j / HID][j % HID] = 0.f;
  __syncthreads();
  for (int st = 0; st < TSEQ; ++st) {
    int tt = dir ? (TSEQ - 1 - st) : st;
    if (j < 360) {
      float a0 = bias, a1 = bias;
      const float4* h40 = (const float4*)h_sh[0];
      const float4* h41 = (const float4*)h_sh[1];
#pragma unroll
      for (int k4 = 0; k4 < HID / 4; ++k4) {
        float4 v0 = h40[k4];
        float4 v1 = h41[k4];
        a0 += wrow[k4*4+0]*v0.x + wrow[k4*4+1]*v0.y + wrow[k4*4+2]*v0.z + wrow[k4*4+3]*v0.w;
        a1 += wrow[k4*4+0]*v1.x + wrow[k4*4+1]*v1.y + wrow[k4*4+2]*v1.z + wrow[k4*4+3]*v1.w;
      }
      g0[j] = a0; g1[j] = a1;
    }
    __syncthreads();
    if (j < 2 * HID) {
      int bb = j / HID, th = j - bb * HID;
      const float* g = gi + (((size_t)dir * TSEQ + tt) * BB + (b0 + bb)) * 360;
      const float* gh = bb ? g1 : g0;
      float r  = 1.f / (1.f + expf(-(g[th]       + gh[th])));
      float z  = 1.f / (1.f + expf(-(g[120 + th] + gh[120 + th])));
      float ng = tanhf(g[240 + th] + r * gh[240 + th]);
      float hn = (1.f - z) * ng + z * h_sh[bb][th];
      h_sh[bb][th] = hn;
      xc[(size_t)(b0 + bb) * 4816 + 256 + (size_t)tt * 240 + dir * 120 + th] = hn;
    }
    __syncthreads();
  }
}

// ---------------- fused final readout: xc[:, :256] = x1 + x2 from partials ----------------
__global__ void k_xg(const float* __restrict__ pmax1, const float* __restrict__ psum1,
                     const float* __restrict__ pmax2, const float* __restrict__ psum2,
                     float* __restrict__ xc) {
  int b = blockIdx.x, f = threadIdx.x;  // 128 threads
  float mx1 = -INFINITY, sm1 = 0.f;
  for (int c = 0; c < NCH1; ++c) {
    mx1 = fmaxf(mx1, pmax1[((size_t)b * NCH1 + c) * 128 + f]);
    sm1 += psum1[((size_t)b * NCH1 + c) * 128 + f];
  }
  float mx2 = -INFINITY, sm2 = 0.f;
  for (int c = 0; c < NCH2; ++c) {
    mx2 = fmaxf(mx2, pmax2[((size_t)b * NCH2 + c) * 128 + f]);
    sm2 += psum2[((size_t)b * NCH2 + c) * 128 + f];
  }
  xc[(size_t)b * 4816 + f] = mx1 + mx2;
  xc[(size_t)b * 4816 + 128 + f] = sm1 / (float)K1C + sm2 / (float)K2C;
}

// ---------------- d1 partial GEMM ----------------
__global__ __launch_bounds__(128) void k_d1(const float* __restrict__ xc,
                                            const float* __restrict__ Wd1,
                                            float* __restrict__ part) {
  int c = blockIdx.x % D1CH;
  int rg = blockIdx.x / D1CH;
  int k0 = c * 128, kn = min(128, D1K - k0);
  __shared__ float xcs[8][128];
  int tid = threadIdx.x;
#pragma unroll
  for (int l = 0; l < 8; ++l) {
    int i = tid + l * 128;
    int r = i >> 7, k = i & 127;
    xcs[r][k] = (k < kn) ? xc[(size_t)(rg * 8 + r) * D1K + k0 + k] : 0.f;
  }
  __syncthreads();
  int j = tid;
  if (j < 102) {
    float acc[8] = {};
    for (int k = 0; k < kn; ++k) {
      float w = Wd1[(size_t)(k0 + k) * 102 + j];
#pragma unroll
      for (int r = 0; r < 8; ++r) acc[r] += xcs[r][k] * w;
    }
#pragma unroll
    for (int r = 0; r < 8; ++r)
      part[((size_t)(rg * 8 + r) * D1CH + c) * 102 + j] = acc[r];
  }
}

// ---------------- reduce partials + relu + d3 + log_softmax ----------------
__global__ void k_final2(const float* __restrict__ part, const float* __restrict__ bd1,
                         const float* __restrict__ Wd3, const float* __restrict__ bd3,
                         float* __restrict__ out) {
  __shared__ float tmp2[2];
  int b = blockIdx.x, j = threadIdx.x;
  float v = 0.f;
  if (j < 102) {
    float acc = bd1[j];
    for (int c = 0; c < D1CH; ++c) acc += part[((size_t)b * D1CH + c) * 102 + j];
    v = fmaxf(acc, 0.f);
  }
  float c0 = (j < 102) ? v * Wd3[j * 2] : 0.f;
  float c1 = (j < 102) ? v * Wd3[j * 2 + 1] : 0.f;
  float z0 = blockReduceSum128(c0, tmp2) + bd3[0];
  float z1 = blockReduceSum128(c1, tmp2) + bd3[1];
  if (j < 2) {
    float m = fmaxf(z0, z1);
    float lse = m + logf(expf(z0 - m) + expf(z1 - m));
    out[b * 2 + j] = (j == 0 ? z0 : z1) - lse;
  }
}

// ---------------- launch ----------------
extern "C" void kernel_launch(void* const* d_in, const int* in_sizes, int n_in,
                              void* d_out, int out_size, void* d_ws, size_t ws_size,
                              hipStream_t stream) {
  const float* x      = (const float*)d_in[0];
  const float* target = (const float*)d_in[1];
  const int*   esrc   = (const int*)d_in[2];
  const int*   edst   = (const int*)d_in[3];
  const float* W1rel  = (const float*)d_in[4];
  const float* W1root = (const float*)d_in[5];
  const float* b1     = (const float*)d_in[6];
  const float* p1     = (const float*)d_in[7];
  const float* W2rel  = (const float*)d_in[8];
  const float* W2root = (const float*)d_in[9];
  const float* b2     = (const float*)d_in[10];
  const float* p2     = (const float*)d_in[11];
  const float* Wc     = (const float*)d_in[12];
  const float* bc     = (const float*)d_in[13];
  const float* Wihf   = (const float*)d_in[14];
  const float* Whhf   = (const float*)d_in[15];
  const float* bihf   = (const float*)d_in[16];
  const float* bhhf   = (const float*)d_in[17];
  const float* Wihb   = (const float*)d_in[18];
  const float* Whhb   = (const float*)d_in[19];
  const float* bihb   = (const float*)d_in[20];
  const float* bhhb   = (const float*)d_in[21];
  const float* Wd1    = (const float*)d_in[22];
  const float* bd1    = (const float*)d_in[23];
  const float* Wd3    = (const float*)d_in[24];
  const float* bd3    = (const float*)d_in[25];
  float* out = (float*)d_out;

  char* wsb = (char*)d_ws;
  size_t off = 0;
  auto alloc = [&](size_t bytes) -> void* {
    void* p = wsb + off;
    off = (off + bytes + 255) & ~(size_t)255;
    return p;
  };
  float* regH    = (float*)alloc((size_t)BN * 128 * 4);   // h1 / agg2 (64MB)
  float* agg1    = (float*)alloc((size_t)BN * 4 * 4);
  float* score1  = (float*)alloc((size_t)BN * 4);
  int*   perm1   = (int*)  alloc((size_t)BB * K1C * 4);
  int*   map1    = (int*)  alloc((size_t)BN * 4);
  float* xp1     = (float*)alloc((size_t)BB * K1C * 128 * 4);
  float* h2      = (float*)alloc((size_t)BB * K1C * 128 * 4);
  float* score2  = (float*)alloc((size_t)BB * K1C * 4);
  int*   perm2   = (int*)  alloc((size_t)BB * K2C * 4);
  float* invp    = (float*)alloc(256);
  float* xs      = (float*)alloc((size_t)TSEQ * BB * 128 * 4);
  float* gi      = (float*)alloc((size_t)2 * TSEQ * BB * 360 * 4);
  float* xc      = (float*)alloc((size_t)BB * 4816 * 4);
  int*   starts2 = (int*)  alloc((size_t)BB * K1C * 4);
  int*   cnt2    = (int*)  alloc((size_t)BB * K1C * 4);
  int*   elist2  = (int*)  alloc((size_t)EDG * 4);
  float* pmax1   = (float*)alloc((size_t)BB * NCH1 * 128 * 4);
  float* psum1   = (float*)alloc((size_t)BB * NCH1 * 128 * 4);
  float* pmax2   = (float*)alloc((size_t)BB * NCH2 * 128 * 4);
  float* psum2   = (float*)alloc((size_t)BB * NCH2 * 128 * 4);
  float* part    = (float*)alloc((size_t)BB * D1CH * 102 * 4);
  float* h1   = regH;
  float* agg2 = regH;

  k_pnorm<<<1, 128, 0, stream>>>(p1, p2, invp);

  // --- layer 1 (CSR build + aggregate fused, CSR lives in LDS only) ---
  k_l1<<<BB, 1024, 0, stream>>>(esrc, edst, x, agg1);
  k_h1<<<BN * 32 / 256, 256, 0, stream>>>(x, agg1, W1rel, W1root, b1, p1, invp, h1, score1);
  k_sort<<<BB, 512, 0, stream>>>(score1, NN, K1C, perm1, map1);
  k_gatherread<<<BB * NCH1, 128, 0, stream>>>(h1, score1, perm1, xp1, pmax1, psum1, K1C, NCH1);

  // --- layer 2: filtered CSR + fully-LDS-staged aggregate ---
  k_csr2<<<BB, 1024, 0, stream>>>(esrc, edst, map1, starts2, cnt2, elist2);
  k_agg2s<<<BB * 4, 1024, 0, stream>>>(starts2, cnt2, elist2, xp1, agg2);
  k_h2<<<(BB * K1C) / 128, 256, 0, stream>>>(agg2, xp1, W2rel, W2root, b2, p2, invp, h2, score2);
  k_sort<<<BB, 512, 0, stream>>>(score2, K1C, K2C, perm2, nullptr);
  k_gatherread<<<BB * NCH2, 128, 0, stream>>>(h2, score2, perm2, nullptr, pmax2, psum2, K2C, NCH2);

  // --- target branch ---
  k_conv<<<BB * TSEQ, 128, 0, stream>>>(target, Wc, bc, xs);
  k_gi<<<2 * TSEQ * 8, 384, 0, stream>>>(xs, Wihf, bihf, Wihb, bihb, gi);
  k_gru<<<2 * 64, 384, 0, stream>>>(gi, Whhf, bhhf, Whhb, bhhb, xc);

  // --- head ---
  k_xg<<<BB, 128, 0, stream>>>(pmax1, psum1, pmax2, psum2, xc);
  k_d1<<<(BB / 8) * D1CH, 128, 0, stream>>>(xc, Wd1, part);
  k_final2<<<BB, 128, 0, stream>>>(part, bd1, Wd3, bd3, out);
}

// Round 14
// 408.734 us; speedup vs baseline: 1.3323x; 1.0454x over previous
//
#include <hip/hip_runtime.h>
#include <math.h>

#define BB   128
#define NN   1024
#define BN   (BB*NN)          // 131072
#define EDG  (BB*8192)        // 1048576
#define K1C  820
#define K2C  656
#define TSEQ 19
#define HID  120
#define D1K  4816
#define D1CH 38               // ceil(4816/128)
#define NCH2 11               // ceil(656/64)

// ---------------- reduction helper (128-thread block) ----------------
__device__ __forceinline__ float blockReduceSum128(float v, float* tmp2) {
#pragma unroll
  for (int o = 32; o > 0; o >>= 1) v += __shfl_down(v, o);
  int lane = threadIdx.x & 63, w = threadIdx.x >> 6;
  if (lane == 0) tmp2[w] = v;
  __syncthreads();
  float r = tmp2[0] + tmp2[1];
  __syncthreads();
  return r;
}

// ---------------- p-norm precompute ----------------
__global__ void k_pnorm(const float* __restrict__ p1, const float* __restrict__ p2,
                        float* __restrict__ invp) {
  __shared__ float tmp2[2];
  float a = p1[threadIdx.x], b = p2[threadIdx.x];
  float s1 = blockReduceSum128(a * a, tmp2);
  float s2 = blockReduceSum128(b * b, tmp2);
  if (threadIdx.x == 0) { invp[0] = 1.f / sqrtf(s1); invp[1] = 1.f / sqrtf(s2); }
}

// ---------------- fused layer-1 CSR build + aggregate (all in LDS) ----------------
__global__ __launch_bounds__(1024) void k_l1(const int* __restrict__ src,
                                             const int* __restrict__ dst,
                                             const float* __restrict__ x,
                                             float* __restrict__ agg1) {
  __shared__ int hcur[1024];
  __shared__ int sscan[1024];
  __shared__ int ccnt[1024];
  __shared__ int el[8192];
  __shared__ float4 xls4[1024];
  int b = blockIdx.x, tid = threadIdx.x;
  int base = b * 8192, nb = b * 1024;
  hcur[tid] = 0;
  __syncthreads();
#pragma unroll
  for (int it = 0; it < 8; ++it)
    atomicAdd(&hcur[dst[base + it * 1024 + tid] - nb], 1);
  __syncthreads();
  int v = hcur[tid];
  ccnt[tid] = v;
  sscan[tid] = v;
  __syncthreads();
  for (int o = 1; o < 1024; o <<= 1) {
    int t = (tid >= o) ? sscan[tid - o] : 0;
    __syncthreads();
    sscan[tid] += t;
    __syncthreads();
  }
  hcur[tid] = sscan[tid] - v;          // exclusive start (local cursor)
  __syncthreads();
#pragma unroll
  for (int it = 0; it < 8; ++it) {
    int e = base + it * 1024 + tid;
    int d = dst[e] - nb;
    int pos = atomicAdd(&hcur[d], 1);
    el[pos] = src[e] - nb;             // LOCAL src id
  }
  xls4[tid] = ((const float4*)x)[nb + tid];
  __syncthreads();
  const float* xls = (const float*)xls4;
  int rg = tid >> 2, lane = tid & 3;
#pragma unroll
  for (int it = 0; it < 4; ++it) {
    int r = rg + it * 256;
    int n = ccnt[r], s0 = sscan[r] - n;
    float a0 = 0.f, a1 = 0.f;
    int j = 0;
    for (; j + 1 < n; j += 2) {
      a0 += xls[el[s0 + j] * 4 + lane];
      a1 += xls[el[s0 + j + 1] * 4 + lane];
    }
    if (j < n) a0 += xls[el[s0 + j] * 4 + lane];
    agg1[(size_t)(nb + r) * 4 + lane] = a0 + a1;
  }
}

// ---------------- h1 = relu(agg1@W1rel + x@W1root + b1); score1 fused ----------------
__global__ void k_h1(const float* __restrict__ x, const float* __restrict__ agg1,
                     const float* __restrict__ W1rel, const float* __restrict__ W1root,
                     const float* __restrict__ b1, const float* __restrict__ p1,
                     const float* __restrict__ invp,
                     float* __restrict__ h1, float* __restrict__ score1) {
  int tid = blockIdx.x * 256 + threadIdx.x;
  int r = tid >> 5, lane = tid & 31, f4 = lane * 4;
  float4 a = ((const float4*)agg1)[r];
  float4 xv = ((const float4*)x)[r];
  float o[4], dot = 0.f;
#pragma unroll
  for (int j = 0; j < 4; ++j) {
    int f = f4 + j;
    float acc = b1[f]
      + a.x * W1rel[f] + a.y * W1rel[128 + f] + a.z * W1rel[256 + f] + a.w * W1rel[384 + f]
      + xv.x * W1root[f] + xv.y * W1root[128 + f] + xv.z * W1root[256 + f] + xv.w * W1root[384 + f];
    o[j] = fmaxf(acc, 0.f);
    dot += o[j] * p1[f];
  }
  *(float4*)&h1[(size_t)r * 128 + f4] = make_float4(o[0], o[1], o[2], o[3]);
#pragma unroll
  for (int off = 16; off > 0; off >>= 1) dot += __shfl_down(dot, off, 32);
  if (lane == 0) score1[r] = tanhf(dot * invp[0]);
}

// ---------------- per-graph top-k via LDS bitonic sort (1024 slots) ----------------
__global__ void k_sort(const float* __restrict__ score, int n_per, int K,
                       int* __restrict__ perm, int* __restrict__ mapping) {
  __shared__ float s[1024];
  __shared__ int   id[1024];
  int b = blockIdx.x;
  const float* sc = score + (size_t)b * n_per;
  for (int i = threadIdx.x; i < 1024; i += blockDim.x) {
    if (i < n_per) { s[i] = sc[i]; id[i] = i; }
    else           { s[i] = -INFINITY; id[i] = 0x7fffffff; }
  }
  __syncthreads();
  for (int k = 2; k <= 1024; k <<= 1) {
    for (int j = k >> 1; j > 0; j >>= 1) {
      for (int i = threadIdx.x; i < 1024; i += blockDim.x) {
        int l = i ^ j;
        if (l > i) {
          float si = s[i], sl = s[l];
          int ii = id[i], il = id[l];
          bool iBeforeL = (si > sl) || (si == sl && ii < il);
          bool up = ((i & k) == 0);
          if (up ? (!iBeforeL) : iBeforeL) {
            s[i] = sl; s[l] = si; id[i] = il; id[l] = ii;
          }
        }
      }
      __syncthreads();
    }
  }
  for (int r = threadIdx.x; r < K; r += blockDim.x)
    perm[(size_t)b * K + r] = b * n_per + id[r];
  if (mapping) {
    for (int i = threadIdx.x; i < n_per; i += blockDim.x)
      mapping[(size_t)b * n_per + i] = -1;
    __syncthreads();
    for (int r = threadIdx.x; r < K; r += blockDim.x)
      mapping[(size_t)b * n_per + id[r]] = b * K + r;
  }
}

// ---------------- fused gather(+scale) + partial readout (layer-2 only now) ----------------
#define RCH 64
__global__ void k_gatherread(const float* __restrict__ h, const float* __restrict__ score,
                             const int* __restrict__ perm, float* __restrict__ xp,
                             float* __restrict__ pmax, float* __restrict__ psum,
                             int K, int nch) {
  int b = blockIdx.x / nch, c = blockIdx.x % nch, f = threadIdx.x;  // 128 threads
  int r0 = c * RCH, r1 = min(r0 + RCH, K);
  float mx = -INFINITY, sm = 0.f;
  if (xp) {
    for (int r = r0; r < r1; ++r) {
      int g = perm[(size_t)b * K + r];
      float v = h[(size_t)g * 128 + f] * score[g];
      xp[((size_t)b * K + r) * 128 + f] = v;
      mx = fmaxf(mx, v); sm += v;
    }
  } else {
    for (int r = r0; r < r1; ++r) {
      int g = perm[(size_t)b * K + r];
      float v = h[(size_t)g * 128 + f] * score[g];
      mx = fmaxf(mx, v); sm += v;
    }
  }
  pmax[((size_t)b * nch + c) * 128 + f] = mx;
  psum[((size_t)b * nch + c) * 128 + f] = sm;
}

// ---------------- layer-2 filtered CSR (per-graph, LDS, no global atomics) ----------------
__global__ __launch_bounds__(1024) void k_csr2(const int* __restrict__ src,
                                               const int* __restrict__ dst,
                                               const int* __restrict__ map,
                                               int* __restrict__ starts2,
                                               int* __restrict__ cnt2,
                                               int* __restrict__ elist2) {
  __shared__ int mloc[8192];   // local kept dst per edge, -1 invalid
  __shared__ int msl[8192];    // local kept src per edge
  __shared__ int h[1024];
  __shared__ int s[1024];
  int g = blockIdx.x, tid = threadIdx.x;
  int base = g * 8192, nb2 = g * K1C;
  h[tid] = 0;
  __syncthreads();
#pragma unroll
  for (int it = 0; it < 8; ++it) {
    int e = base + it * 1024 + tid;
    int ms = map[src[e]], md = map[dst[e]];
    bool valid = (ms >= 0) && (md >= 0);
    int idx = it * 1024 + tid;
    int ml = valid ? (md - nb2) : -1;
    mloc[idx] = ml;
    msl[idx] = ms - nb2;
    if (valid) atomicAdd(&h[ml], 1);
  }
  __syncthreads();
  int v = (tid < K1C) ? h[tid] : 0;
  if (tid < K1C) cnt2[nb2 + tid] = v;
  s[tid] = v;
  __syncthreads();
  for (int o = 1; o < 1024; o <<= 1) {
    int t = (tid >= o) ? s[tid - o] : 0;
    __syncthreads();
    s[tid] += t;
    __syncthreads();
  }
  int st = s[tid] - v;
  if (tid < K1C) starts2[nb2 + tid] = base + st;
  h[tid] = st;                        // local cursor
  __syncthreads();
#pragma unroll
  for (int it = 0; it < 8; ++it) {
    int idx = it * 1024 + tid;
    int ml = mloc[idx];
    if (ml >= 0) {
      int pos = atomicAdd(&h[ml], 1);
      elist2[base + pos] = msl[idx];
    }
  }
}

// ---------------- layer-2 aggregate + layer-1 readout, xp1 computed inline ----------------
// Stages xls[r][lane32] = h1[perm1[r]]*score1 (scattered, L3-resident h1); edge walk in LDS;
// also reduces layer-1 readout (max/sum over all 820 rows) for this 32-feat chunk.
__global__ __launch_bounds__(1024) void k_agg2r(const int* __restrict__ starts2,
                                                const int* __restrict__ cnt2,
                                                const int* __restrict__ elist2,
                                                const int* __restrict__ perm1,
                                                const float* __restrict__ score1,
                                                const float* __restrict__ h1,
                                                float* __restrict__ agg2,
                                                float* __restrict__ xmax1,
                                                float* __restrict__ xsum1) {
  __shared__ float xls[K1C * 32];     // 104,960 B
  __shared__ int   el[8192];          // 32,768 B
  __shared__ int   sts[K1C];
  __shared__ int   ctn[K1C];
  __shared__ int   pid[K1C];
  __shared__ float scs[K1C];
  __shared__ float red[32 * 32];      // 4 KB (reused: max then sum)
  int g = blockIdx.x >> 2, q = blockIdx.x & 3;
  int tid = threadIdx.x;
  int nb2 = g * K1C, base = g * 8192;
  for (int i = tid; i < K1C; i += 1024) {
    int p = perm1[nb2 + i];
    pid[i] = p;
    scs[i] = score1[p];
    sts[i] = starts2[nb2 + i] - base;
    ctn[i] = cnt2[nb2 + i];
  }
  {
    const int4* e4 = (const int4*)(elist2 + base);
    for (int i = tid; i < 2048; i += 1024) ((int4*)el)[i] = e4[i];
  }
  __syncthreads();
  for (int i = tid; i < K1C * 8; i += 1024) {
    int row = i >> 3, f4 = (i & 7) * 4;
    float4 v = *(const float4*)&h1[(size_t)pid[row] * 128 + q * 32 + f4];
    float s = scs[row];
    v.x *= s; v.y *= s; v.z *= s; v.w *= s;
    *(float4*)&xls[row * 32 + f4] = v;
  }
  __syncthreads();
  int rg = tid >> 5, lane = tid & 31;  // 32 row-groups x 32 feats
  for (int r = rg; r < K1C; r += 32) {
    int s0 = sts[r], n = ctn[r];
    float a0 = 0.f, a1 = 0.f, a2 = 0.f, a3 = 0.f;
    int j = 0;
    for (; j + 3 < n; j += 4) {
      a0 += xls[el[s0 + j] * 32 + lane];
      a1 += xls[el[s0 + j + 1] * 32 + lane];
      a2 += xls[el[s0 + j + 2] * 32 + lane];
      a3 += xls[el[s0 + j + 3] * 32 + lane];
    }
    for (; j < n; ++j) a0 += xls[el[s0 + j] * 32 + lane];
    agg2[(size_t)(nb2 + r) * 128 + q * 32 + lane] = (a0 + a1) + (a2 + a3);
  }
  // layer-1 readout for this feature chunk
  float mx = -INFINITY, sm = 0.f;
  for (int r = rg; r < K1C; r += 32) {
    float v = xls[r * 32 + lane];
    mx = fmaxf(mx, v); sm += v;
  }
  red[rg * 32 + lane] = mx;
  __syncthreads();
  if (rg == 0) {
    float m = red[lane];
#pragma unroll
    for (int t2 = 1; t2 < 32; ++t2) m = fmaxf(m, red[t2 * 32 + lane]);
    xmax1[g * 128 + q * 32 + lane] = m;
  }
  __syncthreads();
  red[rg * 32 + lane] = sm;
  __syncthreads();
  if (rg == 0) {
    float s2 = red[lane];
#pragma unroll
    for (int t2 = 1; t2 < 32; ++t2) s2 += red[t2 * 32 + lane];
    xsum1[g * 128 + q * 32 + lane] = s2;
  }
}

// ---------------- h2 GEMM: 128x128 tile, 8x8/thread, BK=16; xp1-half gathered from h1 ----------------
#define ALDA 130
#define WLDA 132
__global__ __launch_bounds__(256, 4) void k_h2(
    const float* __restrict__ agg2, const int* __restrict__ perm1,
    const float* __restrict__ score1, const float* __restrict__ h1,
    const float* __restrict__ W2rel, const float* __restrict__ W2root,
    const float* __restrict__ b2, const float* __restrict__ p2,
    const float* __restrict__ invp, float* __restrict__ h2,
    float* __restrict__ score2) {
  __shared__ float As[16][ALDA];
  __shared__ float Ws[16][WLDA];
  __shared__ int   pid2[128];
  __shared__ float sc2[128];
  int tid = threadIdx.x;
  int r0 = blockIdx.x * 128;
  int tx = tid & 15, ty = tid >> 4;
  if (tid < 128) {
    int p = perm1[r0 + tid];
    pid2[tid] = p;
    sc2[tid] = score1[p];
  }
  __syncthreads();
  float acc[8][8] = {};
  for (int ks = 0; ks < 16; ++ks) {
    const float* Wsrc = (ks < 8) ? W2rel : W2root;
    int kof = (ks & 7) * 16;
    if (ks < 8) {
#pragma unroll
      for (int l = 0; l < 2; ++l) {
        int idx = l * 256 + tid;
        int row = idx >> 2, kq = (idx & 3) * 4;
        float4 v = *(const float4*)&agg2[(size_t)(r0 + row) * 128 + kof + kq];
        As[kq + 0][row] = v.x; As[kq + 1][row] = v.y;
        As[kq + 2][row] = v.z; As[kq + 3][row] = v.w;
      }
    } else {
#pragma unroll
      for (int l = 0; l < 2; ++l) {
        int idx = l * 256 + tid;
        int row = idx >> 2, kq = (idx & 3) * 4;
        float4 v = *(const float4*)&h1[(size_t)pid2[row] * 128 + kof + kq];
        float s = sc2[row];
        As[kq + 0][row] = v.x * s; As[kq + 1][row] = v.y * s;
        As[kq + 2][row] = v.z * s; As[kq + 3][row] = v.w * s;
      }
    }
#pragma unroll
    for (int l = 0; l < 2; ++l) {
      int idx = l * 256 + tid;
      int kr = idx >> 5, c4 = (idx & 31) * 4;
      *(float4*)&Ws[kr][c4] = *(const float4*)&Wsrc[(size_t)(kof + kr) * 128 + c4];
    }
    __syncthreads();
#pragma unroll 8
    for (int kk = 0; kk < 16; ++kk) {
      float4 a0 = *(const float4*)&As[kk][ty * 8];
      float4 a1 = *(const float4*)&As[kk][ty * 8 + 4];
      float4 w0 = *(const float4*)&Ws[kk][tx * 4];
      float4 w1 = *(const float4*)&Ws[kk][64 + tx * 4];
      float av[8] = {a0.x, a0.y, a0.z, a0.w, a1.x, a1.y, a1.z, a1.w};
      float wv[8] = {w0.x, w0.y, w0.z, w0.w, w1.x, w1.y, w1.z, w1.w};
#pragma unroll
      for (int i = 0; i < 8; ++i)
#pragma unroll
        for (int j = 0; j < 8; ++j) acc[i][j] += av[i] * wv[j];
    }
    __syncthreads();
  }
  float4 bb0 = *(const float4*)&b2[tx * 4];
  float4 bb1 = *(const float4*)&b2[64 + tx * 4];
  float4 pp0 = *(const float4*)&p2[tx * 4];
  float4 pp1 = *(const float4*)&p2[64 + tx * 4];
  float bbv[8] = {bb0.x, bb0.y, bb0.z, bb0.w, bb1.x, bb1.y, bb1.z, bb1.w};
  float pbv[8] = {pp0.x, pp0.y, pp0.z, pp0.w, pp1.x, pp1.y, pp1.z, pp1.w};
  float inv = invp[1];
#pragma unroll
  for (int i = 0; i < 8; ++i) {
    int row = r0 + ty * 8 + i;
    float o[8], dot = 0.f;
#pragma unroll
    for (int j = 0; j < 8; ++j) {
      o[j] = fmaxf(acc[i][j] + bbv[j], 0.f);
      dot += o[j] * pbv[j];
    }
    *(float4*)&h2[(size_t)row * 128 + tx * 4] = make_float4(o[0], o[1], o[2], o[3]);
    *(float4*)&h2[(size_t)row * 128 + 64 + tx * 4] = make_float4(o[4], o[5], o[6], o[7]);
#pragma unroll
    for (int off = 8; off > 0; off >>= 1) dot += __shfl_down(dot, off, 16);
    if (tx == 0) score2[row] = tanhf(dot * inv);
  }
}

// ---------------- target conv + relu + avgpool -> xs[t][b][o] ----------------
__global__ void k_conv(const float* __restrict__ target, const float* __restrict__ Wc,
                       const float* __restrict__ bc, float* __restrict__ xs) {
  int gb = blockIdx.x;               // B*19
  int b = gb / TSEQ, tt = gb % TSEQ;
  int o = threadIdx.x;               // 128
  __shared__ float tg[30][8];
  for (int i = threadIdx.x; i < 210; i += 128) {
    int ch = i / 7, u = i % 7;
    tg[ch][u] = target[((size_t)b * 30 + ch) * 101 + tt * 5 + u];
  }
  __syncthreads();
  const float* w = Wc + (size_t)o * 90;
  float acc5[5] = {0, 0, 0, 0, 0};
  for (int ch = 0; ch < 30; ++ch) {
    float w0 = w[ch * 3], w1 = w[ch * 3 + 1], w2 = w[ch * 3 + 2];
#pragma unroll
    for (int u = 0; u < 5; ++u)
      acc5[u] += tg[ch][u] * w0 + tg[ch][u + 1] * w1 + tg[ch][u + 2] * w2;
  }
  float bo = bc[o], s = 0.f;
#pragma unroll
  for (int u = 0; u < 5; ++u) s += fmaxf(acc5[u] + bo, 0.f);
  xs[((size_t)tt * BB + b) * 128 + o] = s * 0.2f;
}

// ---------------- gi = xs @ Wih^T + bih; 16 batches per block ----------------
#define GIB 16
__global__ __launch_bounds__(384) void k_gi(const float* __restrict__ xs,
                     const float* __restrict__ Wihf, const float* __restrict__ bihf,
                     const float* __restrict__ Wihb, const float* __restrict__ bihb,
                     float* __restrict__ gi) {
  int bg = blockIdx.x & 7;
  int t = (blockIdx.x >> 3) % TSEQ;
  int dir = blockIdx.x / (8 * TSEQ);
  int b0 = bg * GIB;
  __shared__ float xst[GIB][128];
  int tid = threadIdx.x;
  for (int i = tid; i < GIB * 128; i += 384) {
    int bb = i >> 7, k = i & 127;
    xst[bb][k] = xs[((size_t)t * BB + b0 + bb) * 128 + k];
  }
  __syncthreads();
  int j = tid;
  if (j < 360) {
    const float* W = (dir ? Wihb : Wihf) + (size_t)j * 128;
    float bias = (dir ? bihb : bihf)[j];
    float acc[GIB];
#pragma unroll
    for (int bb = 0; bb < GIB; ++bb) acc[bb] = bias;
#pragma unroll 4
    for (int k = 0; k < 128; ++k) {
      float w = W[k];
#pragma unroll
      for (int bb = 0; bb < GIB; ++bb) acc[bb] += xst[bb][k] * w;
    }
    size_t base = ((size_t)dir * TSEQ + t) * BB + b0;
#pragma unroll
    for (int bb = 0; bb < GIB; ++bb) gi[(base + bb) * 360 + j] = acc[bb];
  }
}

// ---------------- GRU recurrence: Whh rows held in REGISTERS, h via LDS broadcast ----------------
__global__ __launch_bounds__(384) void k_gru(const float* __restrict__ gi,
                      const float* __restrict__ Whhf, const float* __restrict__ bhhf,
                      const float* __restrict__ Whhb, const float* __restrict__ bhhb,
                      float* __restrict__ xc) {
  int pair = blockIdx.x & 63, dir = blockIdx.x >> 6;
  int b0 = pair * 2;
  const float* Whh = dir ? Whhb : Whhf;
  const float* bhh = dir ? bhhb : bhhf;
  __shared__ float h_sh[2][HID];
  __shared__ float g0[360], g1[360];
  int j = threadIdx.x;               // 384
  float wrow[HID];
  float bias = 0.f;
  if (j < 360) {
    const float4* W4 = (const float4*)(Whh + (size_t)j * HID);
#pragma unroll
    for (int k4 = 0; k4 < HID / 4; ++k4) {
      float4 w = W4[k4];
      wrow[k4 * 4 + 0] = w.x; wrow[k4 * 4 + 1] = w.y;
      wrow[k4 * 4 + 2] = w.z; wrow[k4 * 4 + 3] = w.w;
    }
    bias = bhh[j];
  }
  if (j < 2 * HID) h_sh[j / HID][j % HID] = 0.f;
  __syncthreads();
  for (int st = 0; st < TSEQ; ++st) {
    int tt = dir ? (TSEQ - 1 - st) : st;
    if (j < 360) {
      float a0 = bias, a1 = bias;
      const float4* h40 = (const float4*)h_sh[0];
      const float4* h41 = (const float4*)h_sh[1];
#pragma unroll
      for (int k4 = 0; k4 < HID / 4; ++k4) {
        float4 v0 = h40[k4];
        float4 v1 = h41[k4];
        a0 += wrow[k4*4+0]*v0.x + wrow[k4*4+1]*v0.y + wrow[k4*4+2]*v0.z + wrow[k4*4+3]*v0.w;
        a1 += wrow[k4*4+0]*v1.x + wrow[k4*4+1]*v1.y + wrow[k4*4+2]*v1.z + wrow[k4*4+3]*v1.w;
      }
      g0[j] = a0; g1[j] = a1;
    }
    __syncthreads();
    if (j < 2 * HID) {
      int bb = j / HID, th = j - bb * HID;
      const float* g = gi + (((size_t)dir * TSEQ + tt) * BB + (b0 + bb)) * 360;
      const float* gh = bb ? g1 : g0;
      float r  = 1.f / (1.f + expf(-(g[th]       + gh[th])));
      float z  = 1.f / (1.f + expf(-(g[120 + th] + gh[120 + th])));
      float ng = tanhf(g[240 + th] + r * gh[240 + th]);
      float hn = (1.f - z) * ng + z * h_sh[bb][th];
      h_sh[bb][th] = hn;
      xc[(size_t)(b0 + bb) * 4816 + 256 + (size_t)tt * 240 + dir * 120 + th] = hn;
    }
    __syncthreads();
  }
}

// ---------------- fused final readout: xc[:, :256] = x1 + x2 ----------------
__global__ void k_xg(const float* __restrict__ xmax1, const float* __restrict__ xsum1,
                     const float* __restrict__ pmax2, const float* __restrict__ psum2,
                     float* __restrict__ xc) {
  int b = blockIdx.x, f = threadIdx.x;  // 128 threads
  float mx2 = -INFINITY, sm2 = 0.f;
  for (int c = 0; c < NCH2; ++c) {
    mx2 = fmaxf(mx2, pmax2[((size_t)b * NCH2 + c) * 128 + f]);
    sm2 += psum2[((size_t)b * NCH2 + c) * 128 + f];
  }
  xc[(size_t)b * 4816 + f] = xmax1[b * 128 + f] + mx2;
  xc[(size_t)b * 4816 + 128 + f] = xsum1[b * 128 + f] / (float)K1C + sm2 / (float)K2C;
}

// ---------------- d1 partial GEMM ----------------
__global__ __launch_bounds__(128) void k_d1(const float* __restrict__ xc,
                                            const float* __restrict__ Wd1,
                                            float* __restrict__ part) {
  int c = blockIdx.x % D1CH;
  int rg = blockIdx.x / D1CH;
  int k0 = c * 128, kn = min(128, D1K - k0);
  __shared__ float xcs[8][128];
  int tid = threadIdx.x;
#pragma unroll
  for (int l = 0; l < 8; ++l) {
    int i = tid + l * 128;
    int r = i >> 7, k = i & 127;
    xcs[r][k] = (k < kn) ? xc[(size_t)(rg * 8 + r) * D1K + k0 + k] : 0.f;
  }
  __syncthreads();
  int j = tid;
  if (j < 102) {
    float acc[8] = {};
    for (int k = 0; k < kn; ++k) {
      float w = Wd1[(size_t)(k0 + k) * 102 + j];
#pragma unroll
      for (int r = 0; r < 8; ++r) acc[r] += xcs[r][k] * w;
    }
#pragma unroll
    for (int r = 0; r < 8; ++r)
      part[((size_t)(rg * 8 + r) * D1CH + c) * 102 + j] = acc[r];
  }
}

// ---------------- reduce partials + relu + d3 + log_softmax ----------------
__global__ void k_final2(const float* __restrict__ part, const float* __restrict__ bd1,
                         const float* __restrict__ Wd3, const float* __restrict__ bd3,
                         float* __restrict__ out) {
  __shared__ float tmp2[2];
  int b = blockIdx.x, j = threadIdx.x;
  float v = 0.f;
  if (j < 102) {
    float acc = bd1[j];
    for (int c = 0; c < D1CH; ++c) acc += part[((size_t)b * D1CH + c) * 102 + j];
    v = fmaxf(acc, 0.f);
  }
  float c0 = (j < 102) ? v * Wd3[j * 2] : 0.f;
  float c1 = (j < 102) ? v * Wd3[j * 2 + 1] : 0.f;
  float z0 = blockReduceSum128(c0, tmp2) + bd3[0];
  float z1 = blockReduceSum128(c1, tmp2) + bd3[1];
  if (j < 2) {
    float m = fmaxf(z0, z1);
    float lse = m + logf(expf(z0 - m) + expf(z1 - m));
    out[b * 2 + j] = (j == 0 ? z0 : z1) - lse;
  }
}

// ---------------- launch ----------------
extern "C" void kernel_launch(void* const* d_in, const int* in_sizes, int n_in,
                              void* d_out, int out_size, void* d_ws, size_t ws_size,
                              hipStream_t stream) {
  const float* x      = (const float*)d_in[0];
  const float* target = (const float*)d_in[1];
  const int*   esrc   = (const int*)d_in[2];
  const int*   edst   = (const int*)d_in[3];
  const float* W1rel  = (const float*)d_in[4];
  const float* W1root = (const float*)d_in[5];
  const float* b1     = (const float*)d_in[6];
  const float* p1     = (const float*)d_in[7];
  const float* W2rel  = (const float*)d_in[8];
  const float* W2root = (const float*)d_in[9];
  const float* b2     = (const float*)d_in[10];
  const float* p2     = (const float*)d_in[11];
  const float* Wc     = (const float*)d_in[12];
  const float* bc     = (const float*)d_in[13];
  const float* Wihf   = (const float*)d_in[14];
  const float* Whhf   = (const float*)d_in[15];
  const float* bihf   = (const float*)d_in[16];
  const float* bhhf   = (const float*)d_in[17];
  const float* Wihb   = (const float*)d_in[18];
  const float* Whhb   = (const float*)d_in[19];
  const float* bihb   = (const float*)d_in[20];
  const float* bhhb   = (const float*)d_in[21];
  const float* Wd1    = (const float*)d_in[22];
  const float* bd1    = (const float*)d_in[23];
  const float* Wd3    = (const float*)d_in[24];
  const float* bd3    = (const float*)d_in[25];
  float* out = (float*)d_out;

  char* wsb = (char*)d_ws;
  size_t off = 0;
  auto alloc = [&](size_t bytes) -> void* {
    void* p = wsb + off;
    off = (off + bytes + 255) & ~(size_t)255;
    return p;
  };
  float* h1      = (float*)alloc((size_t)BN * 128 * 4);       // 64MB, live until h2 done
  float* agg2    = (float*)alloc((size_t)BB * K1C * 128 * 4); // 53.7MB
  float* agg1    = (float*)alloc((size_t)BN * 4 * 4);
  float* score1  = (float*)alloc((size_t)BN * 4);
  int*   perm1   = (int*)  alloc((size_t)BB * K1C * 4);
  int*   map1    = (int*)  alloc((size_t)BN * 4);
  float* h2      = (float*)alloc((size_t)BB * K1C * 128 * 4);
  float* score2  = (float*)alloc((size_t)BB * K1C * 4);
  int*   perm2   = (int*)  alloc((size_t)BB * K2C * 4);
  float* invp    = (float*)alloc(256);
  float* xs      = (float*)alloc((size_t)TSEQ * BB * 128 * 4);
  float* gi      = (float*)alloc((size_t)2 * TSEQ * BB * 360 * 4);
  float* xc      = (float*)alloc((size_t)BB * 4816 * 4);
  int*   starts2 = (int*)  alloc((size_t)BB * K1C * 4);
  int*   cnt2    = (int*)  alloc((size_t)BB * K1C * 4);
  int*   elist2  = (int*)  alloc((size_t)EDG * 4);
  float* xmax1   = (float*)alloc((size_t)BB * 128 * 4);
  float* xsum1   = (float*)alloc((size_t)BB * 128 * 4);
  float* pmax2   = (float*)alloc((size_t)BB * NCH2 * 128 * 4);
  float* psum2   = (float*)alloc((size_t)BB * NCH2 * 128 * 4);
  float* part    = (float*)alloc((size_t)BB * D1CH * 102 * 4);

  k_pnorm<<<1, 128, 0, stream>>>(p1, p2, invp);

  // --- layer 1 (CSR build + aggregate fused, CSR lives in LDS only) ---
  k_l1<<<BB, 1024, 0, stream>>>(esrc, edst, x, agg1);
  k_h1<<<BN * 32 / 256, 256, 0, stream>>>(x, agg1, W1rel, W1root, b1, p1, invp, h1, score1);
  k_sort<<<BB, 512, 0, stream>>>(score1, NN, K1C, perm1, map1);

  // --- layer 2: filtered CSR + aggregate (xp1 inline) + GEMM (xp1 inline) ---
  k_csr2<<<BB, 1024, 0, stream>>>(esrc, edst, map1, starts2, cnt2, elist2);
  k_agg2r<<<BB * 4, 1024, 0, stream>>>(starts2, cnt2, elist2, perm1, score1, h1,
                                       agg2, xmax1, xsum1);
  k_h2<<<(BB * K1C) / 128, 256, 0, stream>>>(agg2, perm1, score1, h1,
                                             W2rel, W2root, b2, p2, invp, h2, score2);
  k_sort<<<BB, 512, 0, stream>>>(score2, K1C, K2C, perm2, nullptr);
  k_gatherread<<<BB * NCH2, 128, 0, stream>>>(h2, score2, perm2, nullptr, pmax2, psum2, K2C, NCH2);

  // --- target branch ---
  k_conv<<<BB * TSEQ, 128, 0, stream>>>(target, Wc, bc, xs);
  k_gi<<<2 * TSEQ * 8, 384, 0, stream>>>(xs, Wihf, bihf, Wihb, bihb, gi);
  k_gru<<<2 * 64, 384, 0, stream>>>(gi, Whhf, bhhf, Whhb, bhhb, xc);

  // --- head ---
  k_xg<<<BB, 128, 0, stream>>>(xmax1, xsum1, pmax2, psum2, xc);
  k_d1<<<(BB / 8) * D1CH, 128, 0, stream>>>(xc, Wd1, part);
  k_final2<<<BB, 128, 0, stream>>>(part, bd1, Wd3, bd3, out);
}

// Round 15
// 336.130 us; speedup vs baseline: 1.6201x; 1.2160x over previous
//
#include <hip/hip_runtime.h>
#include <math.h>

#define BB   128
#define NN   1024
#define BN   (BB*NN)          // 131072
#define EDG  (BB*8192)        // 1048576
#define K1C  820
#define K2C  656
#define TSEQ 19
#define HID  120
#define D1K  4816
#define D1CH 38               // ceil(4816/128)
#define NCH2 11               // ceil(656/64)

typedef unsigned short u16;
typedef __attribute__((ext_vector_type(8))) short bf16x8;
typedef __attribute__((ext_vector_type(4))) float f32x4;

__device__ __forceinline__ u16 f2b(float x) {   // fp32 -> bf16 RNE
  unsigned int u = __float_as_uint(x);
  u += 0x7FFFu + ((u >> 16) & 1u);
  return (u16)(u >> 16);
}

// ---------------- reduction helper (128-thread block) ----------------
__device__ __forceinline__ float blockReduceSum128(float v, float* tmp2) {
#pragma unroll
  for (int o = 32; o > 0; o >>= 1) v += __shfl_down(v, o);
  int lane = threadIdx.x & 63, w = threadIdx.x >> 6;
  if (lane == 0) tmp2[w] = v;
  __syncthreads();
  float r = tmp2[0] + tmp2[1];
  __syncthreads();
  return r;
}

// ---------------- p-norm precompute ----------------
__global__ void k_pnorm(const float* __restrict__ p1, const float* __restrict__ p2,
                        float* __restrict__ invp) {
  __shared__ float tmp2[2];
  float a = p1[threadIdx.x], b = p2[threadIdx.x];
  float s1 = blockReduceSum128(a * a, tmp2);
  float s2 = blockReduceSum128(b * b, tmp2);
  if (threadIdx.x == 0) { invp[0] = 1.f / sqrtf(s1); invp[1] = 1.f / sqrtf(s2); }
}

// ---------------- pack W2rel|W2root into MFMA fragment order (bf16) ----------------
// Wfrag[((ks*8+ct)*64+lane)*8+j] = W[ks*32+(lane>>4)*8+j][ct*16+(lane&15)]
__global__ void k_wb(const float* __restrict__ W2rel, const float* __restrict__ W2root,
                     u16* __restrict__ Wfrag) {
  int idx = blockIdx.x * 256 + threadIdx.x;   // 16 blocks -> 4096
  int lane = idx & 63, ct = (idx >> 6) & 7, ks = idx >> 9;
  int c = ct * 16 + (lane & 15);
  int kbase = ks * 32 + (lane >> 4) * 8;
#pragma unroll
  for (int j = 0; j < 8; ++j) {
    int k = kbase + j;
    float w = (k < 128) ? W2rel[(size_t)k * 128 + c] : W2root[(size_t)(k - 128) * 128 + c];
    Wfrag[(size_t)idx * 8 + j] = f2b(w);
  }
}

// ---------------- fused layer-1 CSR build + aggregate (all in LDS) ----------------
__global__ __launch_bounds__(1024) void k_l1(const int* __restrict__ src,
                                             const int* __restrict__ dst,
                                             const float* __restrict__ x,
                                             float* __restrict__ agg1) {
  __shared__ int hcur[1024];
  __shared__ int sscan[1024];
  __shared__ int ccnt[1024];
  __shared__ int el[8192];
  __shared__ float4 xls4[1024];
  int b = blockIdx.x, tid = threadIdx.x;
  int base = b * 8192, nb = b * 1024;
  hcur[tid] = 0;
  __syncthreads();
#pragma unroll
  for (int it = 0; it < 8; ++it)
    atomicAdd(&hcur[dst[base + it * 1024 + tid] - nb], 1);
  __syncthreads();
  int v = hcur[tid];
  ccnt[tid] = v;
  sscan[tid] = v;
  __syncthreads();
  for (int o = 1; o < 1024; o <<= 1) {
    int t = (tid >= o) ? sscan[tid - o] : 0;
    __syncthreads();
    sscan[tid] += t;
    __syncthreads();
  }
  hcur[tid] = sscan[tid] - v;          // exclusive start (local cursor)
  __syncthreads();
#pragma unroll
  for (int it = 0; it < 8; ++it) {
    int e = base + it * 1024 + tid;
    int d = dst[e] - nb;
    int pos = atomicAdd(&hcur[d], 1);
    el[pos] = src[e] - nb;             // LOCAL src id
  }
  xls4[tid] = ((const float4*)x)[nb + tid];
  __syncthreads();
  const float* xls = (const float*)xls4;
  int rg = tid >> 2, lane = tid & 3;
#pragma unroll
  for (int it = 0; it < 4; ++it) {
    int r = rg + it * 256;
    int n = ccnt[r], s0 = sscan[r] - n;
    float a0 = 0.f, a1 = 0.f;
    int j = 0;
    for (; j + 1 < n; j += 2) {
      a0 += xls[el[s0 + j] * 4 + lane];
      a1 += xls[el[s0 + j + 1] * 4 + lane];
    }
    if (j < n) a0 += xls[el[s0 + j] * 4 + lane];
    agg1[(size_t)(nb + r) * 4 + lane] = a0 + a1;
  }
}

// ---------------- h1 = relu(agg1@W1rel + x@W1root + b1); score1 fused ----------------
__global__ void k_h1(const float* __restrict__ x, const float* __restrict__ agg1,
                     const float* __restrict__ W1rel, const float* __restrict__ W1root,
                     const float* __restrict__ b1, const float* __restrict__ p1,
                     const float* __restrict__ invp,
                     float* __restrict__ h1, float* __restrict__ score1) {
  int tid = blockIdx.x * 256 + threadIdx.x;
  int r = tid >> 5, lane = tid & 31, f4 = lane * 4;
  float4 a = ((const float4*)agg1)[r];
  float4 xv = ((const float4*)x)[r];
  float o[4], dot = 0.f;
#pragma unroll
  for (int j = 0; j < 4; ++j) {
    int f = f4 + j;
    float acc = b1[f]
      + a.x * W1rel[f] + a.y * W1rel[128 + f] + a.z * W1rel[256 + f] + a.w * W1rel[384 + f]
      + xv.x * W1root[f] + xv.y * W1root[128 + f] + xv.z * W1root[256 + f] + xv.w * W1root[384 + f];
    o[j] = fmaxf(acc, 0.f);
    dot += o[j] * p1[f];
  }
  *(float4*)&h1[(size_t)r * 128 + f4] = make_float4(o[0], o[1], o[2], o[3]);
#pragma unroll
  for (int off = 16; off > 0; off >>= 1) dot += __shfl_down(dot, off, 32);
  if (lane == 0) score1[r] = tanhf(dot * invp[0]);
}

// ---------------- per-graph top-k via LDS bitonic sort (1024 slots) ----------------
__global__ void k_sort(const float* __restrict__ score, int n_per, int K,
                       int* __restrict__ perm, int* __restrict__ mapping) {
  __shared__ float s[1024];
  __shared__ int   id[1024];
  int b = blockIdx.x;
  const float* sc = score + (size_t)b * n_per;
  for (int i = threadIdx.x; i < 1024; i += blockDim.x) {
    if (i < n_per) { s[i] = sc[i]; id[i] = i; }
    else           { s[i] = -INFINITY; id[i] = 0x7fffffff; }
  }
  __syncthreads();
  for (int k = 2; k <= 1024; k <<= 1) {
    for (int j = k >> 1; j > 0; j >>= 1) {
      for (int i = threadIdx.x; i < 1024; i += blockDim.x) {
        int l = i ^ j;
        if (l > i) {
          float si = s[i], sl = s[l];
          int ii = id[i], il = id[l];
          bool iBeforeL = (si > sl) || (si == sl && ii < il);
          bool up = ((i & k) == 0);
          if (up ? (!iBeforeL) : iBeforeL) {
            s[i] = sl; s[l] = si; id[i] = il; id[l] = ii;
          }
        }
      }
      __syncthreads();
    }
  }
  for (int r = threadIdx.x; r < K; r += blockDim.x)
    perm[(size_t)b * K + r] = b * n_per + id[r];
  if (mapping) {
    for (int i = threadIdx.x; i < n_per; i += blockDim.x)
      mapping[(size_t)b * n_per + i] = -1;
    __syncthreads();
    for (int r = threadIdx.x; r < K; r += blockDim.x)
      mapping[(size_t)b * n_per + id[r]] = b * K + r;
  }
}

// ---------------- fused gather(+scale) + partial readout (layer-2) ----------------
#define RCH 64
__global__ void k_gatherread(const float* __restrict__ h, const float* __restrict__ score,
                             const int* __restrict__ perm, float* __restrict__ xp,
                             float* __restrict__ pmax, float* __restrict__ psum,
                             int K, int nch) {
  int b = blockIdx.x / nch, c = blockIdx.x % nch, f = threadIdx.x;  // 128 threads
  int r0 = c * RCH, r1 = min(r0 + RCH, K);
  float mx = -INFINITY, sm = 0.f;
  if (xp) {
    for (int r = r0; r < r1; ++r) {
      int g = perm[(size_t)b * K + r];
      float v = h[(size_t)g * 128 + f] * score[g];
      xp[((size_t)b * K + r) * 128 + f] = v;
      mx = fmaxf(mx, v); sm += v;
    }
  } else {
    for (int r = r0; r < r1; ++r) {
      int g = perm[(size_t)b * K + r];
      float v = h[(size_t)g * 128 + f] * score[g];
      mx = fmaxf(mx, v); sm += v;
    }
  }
  pmax[((size_t)b * nch + c) * 128 + f] = mx;
  psum[((size_t)b * nch + c) * 128 + f] = sm;
}

// ---------------- layer-2 filtered CSR (per-graph, LDS, no global atomics) ----------------
__global__ __launch_bounds__(1024) void k_csr2(const int* __restrict__ src,
                                               const int* __restrict__ dst,
                                               const int* __restrict__ map,
                                               int* __restrict__ starts2,
                                               int* __restrict__ cnt2,
                                               int* __restrict__ elist2) {
  __shared__ int mloc[8192];   // local kept dst per edge, -1 invalid
  __shared__ int msl[8192];    // local kept src per edge
  __shared__ int h[1024];
  __shared__ int s[1024];
  int g = blockIdx.x, tid = threadIdx.x;
  int base = g * 8192, nb2 = g * K1C;
  h[tid] = 0;
  __syncthreads();
#pragma unroll
  for (int it = 0; it < 8; ++it) {
    int e = base + it * 1024 + tid;
    int ms = map[src[e]], md = map[dst[e]];
    bool valid = (ms >= 0) && (md >= 0);
    int idx = it * 1024 + tid;
    int ml = valid ? (md - nb2) : -1;
    mloc[idx] = ml;
    msl[idx] = ms - nb2;
    if (valid) atomicAdd(&h[ml], 1);
  }
  __syncthreads();
  int v = (tid < K1C) ? h[tid] : 0;
  if (tid < K1C) cnt2[nb2 + tid] = v;
  s[tid] = v;
  __syncthreads();
  for (int o = 1; o < 1024; o <<= 1) {
    int t = (tid >= o) ? s[tid - o] : 0;
    __syncthreads();
    s[tid] += t;
    __syncthreads();
  }
  int st = s[tid] - v;
  if (tid < K1C) starts2[nb2 + tid] = base + st;
  h[tid] = st;                        // local cursor
  __syncthreads();
#pragma unroll
  for (int it = 0; it < 8; ++it) {
    int idx = it * 1024 + tid;
    int ml = mloc[idx];
    if (ml >= 0) {
      int pos = atomicAdd(&h[ml], 1);
      elist2[base + pos] = msl[idx];
    }
  }
}

// ---------------- layer-2 aggregate + layer-1 readout; emits bf16 A = [agg|xp] ----------------
__global__ __launch_bounds__(1024) void k_agg2r(const int* __restrict__ starts2,
                                                const int* __restrict__ cnt2,
                                                const int* __restrict__ elist2,
                                                const int* __restrict__ perm1,
                                                const float* __restrict__ score1,
                                                const float* __restrict__ h1,
                                                u16* __restrict__ Abf,
                                                float* __restrict__ xmax1,
                                                float* __restrict__ xsum1) {
  __shared__ float xls[K1C * 32];     // 104,960 B
  __shared__ int   el[8192];          // 32,768 B
  __shared__ int   sts[K1C];
  __shared__ int   ctn[K1C];
  __shared__ int   pid[K1C];
  __shared__ float scs[K1C];
  __shared__ float red[32 * 32];      // 4 KB (reused: max then sum)
  int g = blockIdx.x >> 2, q = blockIdx.x & 3;
  int tid = threadIdx.x;
  int nb2 = g * K1C, base = g * 8192;
  for (int i = tid; i < K1C; i += 1024) {
    int p = perm1[nb2 + i];
    pid[i] = p;
    scs[i] = score1[p];
    sts[i] = starts2[nb2 + i] - base;
    ctn[i] = cnt2[nb2 + i];
  }
  {
    const int4* e4 = (const int4*)(elist2 + base);
    for (int i = tid; i < 2048; i += 1024) ((int4*)el)[i] = e4[i];
  }
  __syncthreads();
  for (int i = tid; i < K1C * 8; i += 1024) {
    int row = i >> 3, f4 = (i & 7) * 4;
    float4 v = *(const float4*)&h1[(size_t)pid[row] * 128 + q * 32 + f4];
    float s = scs[row];
    v.x *= s; v.y *= s; v.z *= s; v.w *= s;
    *(float4*)&xls[row * 32 + f4] = v;
    ushort4 bv;
    bv.x = f2b(v.x); bv.y = f2b(v.y); bv.z = f2b(v.z); bv.w = f2b(v.w);
    *(ushort4*)&Abf[(size_t)(nb2 + row) * 256 + 128 + q * 32 + f4] = bv;  // xp half
  }
  __syncthreads();
  int rg = tid >> 5, lane = tid & 31;  // 32 row-groups x 32 feats
  for (int r = rg; r < K1C; r += 32) {
    int s0 = sts[r], n = ctn[r];
    float a0 = 0.f, a1 = 0.f, a2 = 0.f, a3 = 0.f;
    int j = 0;
    for (; j + 3 < n; j += 4) {
      a0 += xls[el[s0 + j] * 32 + lane];
      a1 += xls[el[s0 + j + 1] * 32 + lane];
      a2 += xls[el[s0 + j + 2] * 32 + lane];
      a3 += xls[el[s0 + j + 3] * 32 + lane];
    }
    for (; j < n; ++j) a0 += xls[el[s0 + j] * 32 + lane];
    Abf[(size_t)(nb2 + r) * 256 + q * 32 + lane] = f2b((a0 + a1) + (a2 + a3));  // agg half
  }
  // layer-1 readout for this feature chunk
  float mx = -INFINITY, sm = 0.f;
  for (int r = rg; r < K1C; r += 32) {
    float v = xls[r * 32 + lane];
    mx = fmaxf(mx, v); sm += v;
  }
  red[rg * 32 + lane] = mx;
  __syncthreads();
  if (rg == 0) {
    float m = red[lane];
#pragma unroll
    for (int t2 = 1; t2 < 32; ++t2) m = fmaxf(m, red[t2 * 32 + lane]);
    xmax1[g * 128 + q * 32 + lane] = m;
  }
  __syncthreads();
  red[rg * 32 + lane] = sm;
  __syncthreads();
  if (rg == 0) {
    float s2 = red[lane];
#pragma unroll
    for (int t2 = 1; t2 < 32; ++t2) s2 += red[t2 * 32 + lane];
    xsum1[g * 128 + q * 32 + lane] = s2;
  }
}

// ---------------- h2 via MFMA bf16: 64x128 block tile, 4 waves, K=256 ----------------
__global__ __launch_bounds__(256, 4) void k_h2m(
    const u16* __restrict__ Abf, const u16* __restrict__ Wfrag,
    const float* __restrict__ b2, const float* __restrict__ p2,
    const float* __restrict__ invp,
    float* __restrict__ h2, float* __restrict__ score2) {
  __shared__ u16 Als[64][40];        // padded: row stride 80B, 2-way max on stores
  int tid = threadIdx.x;
  int r0 = blockIdx.x * 64;
  int wv = tid >> 6, lane = tid & 63;
  int lr = lane & 15, kg = lane >> 4;
  f32x4 acc[8];
  f32x4 z = {0.f, 0.f, 0.f, 0.f};
#pragma unroll
  for (int ct = 0; ct < 8; ++ct) acc[ct] = z;
  for (int ks = 0; ks < 8; ++ks) {
    // stage A tile: 64 rows x 32 k bf16 (4 KB), coalesced
    {
      int row = tid >> 2, kq = (tid & 3) * 8;
      *(f32x4*)&Als[row][kq] =
          *(const f32x4*)&Abf[(size_t)(r0 + row) * 256 + ks * 32 + kq];
    }
    __syncthreads();
    bf16x8 a = *(const bf16x8*)&Als[wv * 16 + lr][kg * 8];   // k = ks*32+kg*8+j
    const u16* wf = Wfrag + (size_t)ks * 4096;               // same k mapping
#pragma unroll
    for (int ct = 0; ct < 8; ++ct) {
      bf16x8 b = *(const bf16x8*)&wf[(ct * 64 + lane) * 8];
      acc[ct] = __builtin_amdgcn_mfma_f32_16x16x32_bf16(a, b, acc[ct], 0, 0, 0);
    }
    __syncthreads();
  }
  // epilogue: bias + relu + h2 store + fused score2
  float inv = invp[1];
  float dots[4] = {0.f, 0.f, 0.f, 0.f};
#pragma unroll
  for (int ct = 0; ct < 8; ++ct) {
    int c = ct * 16 + lr;
    float bb = b2[c], pp = p2[c];
#pragma unroll
    for (int i = 0; i < 4; ++i) {
      float o = fmaxf(acc[ct][i] + bb, 0.f);
      h2[(size_t)(r0 + wv * 16 + kg * 4 + i) * 128 + c] = o;
      dots[i] += o * pp;
    }
  }
#pragma unroll
  for (int i = 0; i < 4; ++i) {
    float d = dots[i];
#pragma unroll
    for (int m = 8; m >= 1; m >>= 1) d += __shfl_xor(d, m);
    if (lr == 0) score2[r0 + wv * 16 + kg * 4 + i] = tanhf(d * inv);
  }
}

// ---------------- target conv + relu + avgpool -> xs[t][b][o] ----------------
__global__ void k_conv(const float* __restrict__ target, const float* __restrict__ Wc,
                       const float* __restrict__ bc, float* __restrict__ xs) {
  int gb = blockIdx.x;               // B*19
  int b = gb / TSEQ, tt = gb % TSEQ;
  int o = threadIdx.x;               // 128
  __shared__ float tg[30][8];
  for (int i = threadIdx.x; i < 210; i += 128) {
    int ch = i / 7, u = i % 7;
    tg[ch][u] = target[((size_t)b * 30 + ch) * 101 + tt * 5 + u];
  }
  __syncthreads();
  const float* w = Wc + (size_t)o * 90;
  float acc5[5] = {0, 0, 0, 0, 0};
  for (int ch = 0; ch < 30; ++ch) {
    float w0 = w[ch * 3], w1 = w[ch * 3 + 1], w2 = w[ch * 3 + 2];
#pragma unroll
    for (int u = 0; u < 5; ++u)
      acc5[u] += tg[ch][u] * w0 + tg[ch][u + 1] * w1 + tg[ch][u + 2] * w2;
  }
  float bo = bc[o], s = 0.f;
#pragma unroll
  for (int u = 0; u < 5; ++u) s += fmaxf(acc5[u] + bo, 0.f);
  xs[((size_t)tt * BB + b) * 128 + o] = s * 0.2f;
}

// ---------------- gi = xs @ Wih^T + bih; 16 batches per block ----------------
#define GIB 16
__global__ __launch_bounds__(384) void k_gi(const float* __restrict__ xs,
                     const float* __restrict__ Wihf, const float* __restrict__ bihf,
                     const float* __restrict__ Wihb, const float* __restrict__ bihb,
                     float* __restrict__ gi) {
  int bg = blockIdx.x & 7;
  int t = (blockIdx.x >> 3) % TSEQ;
  int dir = blockIdx.x / (8 * TSEQ);
  int b0 = bg * GIB;
  __shared__ float xst[GIB][128];
  int tid = threadIdx.x;
  for (int i = tid; i < GIB * 128; i += 384) {
    int bb = i >> 7, k = i & 127;
    xst[bb][k] = xs[((size_t)t * BB + b0 + bb) * 128 + k];
  }
  __syncthreads();
  int j = tid;
  if (j < 360) {
    const float* W = (dir ? Wihb : Wihf) + (size_t)j * 128;
    float bias = (dir ? bihb : bihf)[j];
    float acc[GIB];
#pragma unroll
    for (int bb = 0; bb < GIB; ++bb) acc[bb] = bias;
#pragma unroll 4
    for (int k = 0; k < 128; ++k) {
      float w = W[k];
#pragma unroll
      for (int bb = 0; bb < GIB; ++bb) acc[bb] += xst[bb][k] * w;
    }
    size_t base = ((size_t)dir * TSEQ + t) * BB + b0;
#pragma unroll
    for (int bb = 0; bb < GIB; ++bb) gi[(base + bb) * 360 + j] = acc[bb];
  }
}

// ---------------- GRU recurrence: Whh rows held in REGISTERS, h via LDS broadcast ----------------
__global__ __launch_bounds__(384) void k_gru(const float* __restrict__ gi,
                      const float* __restrict__ Whhf, const float* __restrict__ bhhf,
                      const float* __restrict__ Whhb, const float* __restrict__ bhhb,
                      float* __restrict__ xc) {
  int pair = blockIdx.x & 63, dir = blockIdx.x >> 6;
  int b0 = pair * 2;
  const float* Whh = dir ? Whhb : Whhf;
  const float* bhh = dir ? bhhb : bhhf;
  __shared__ float h_sh[2][HID];
  __shared__ float g0[360], g1[360];
  int j = threadIdx.x;               // 384
  float wrow[HID];
  float bias = 0.f;
  if (j < 360) {
    const float4* W4 = (const float4*)(Whh + (size_t)j * HID);
#pragma unroll
    for (int k4 = 0; k4 < HID / 4; ++k4) {
      float4 w = W4[k4];
      wrow[k4 * 4 + 0] = w.x; wrow[k4 * 4 + 1] = w.y;
      wrow[k4 * 4 + 2] = w.z; wrow[k4 * 4 + 3] = w.w;
    }
    bias = bhh[j];
  }
  if (j < 2 * HID) h_sh[j / HID][j % HID] = 0.f;
  __syncthreads();
  for (int st = 0; st < TSEQ; ++st) {
    int tt = dir ? (TSEQ - 1 - st) : st;
    if (j < 360) {
      float a0 = bias, a1 = bias;
      const float4* h40 = (const float4*)h_sh[0];
      const float4* h41 = (const float4*)h_sh[1];
#pragma unroll
      for (int k4 = 0; k4 < HID / 4; ++k4) {
        float4 v0 = h40[k4];
        float4 v1 = h41[k4];
        a0 += wrow[k4*4+0]*v0.x + wrow[k4*4+1]*v0.y + wrow[k4*4+2]*v0.z + wrow[k4*4+3]*v0.w;
        a1 += wrow[k4*4+0]*v1.x + wrow[k4*4+1]*v1.y + wrow[k4*4+2]*v1.z + wrow[k4*4+3]*v1.w;
      }
      g0[j] = a0; g1[j] = a1;
    }
    __syncthreads();
    if (j < 2 * HID) {
      int bb = j / HID, th = j - bb * HID;
      const float* g = gi + (((size_t)dir * TSEQ + tt) * BB + (b0 + bb)) * 360;
      const float* gh = bb ? g1 : g0;
      float r  = 1.f / (1.f + expf(-(g[th]       + gh[th])));
      float z  = 1.f / (1.f + expf(-(g[120 + th] + gh[120 + th])));
      float ng = tanhf(g[240 + th] + r * gh[240 + th]);
      float hn = (1.f - z) * ng + z * h_sh[bb][th];
      h_sh[bb][th] = hn;
      xc[(size_t)(b0 + bb) * 4816 + 256 + (size_t)tt * 240 + dir * 120 + th] = hn;
    }
    __syncthreads();
  }
}

// ---------------- fused final readout: xc[:, :256] = x1 + x2 ----------------
__global__ void k_xg(const float* __restrict__ xmax1, const float* __restrict__ xsum1,
                     const float* __restrict__ pmax2, const float* __restrict__ psum2,
                     float* __restrict__ xc) {
  int b = blockIdx.x, f = threadIdx.x;  // 128 threads
  float mx2 = -INFINITY, sm2 = 0.f;
  for (int c = 0; c < NCH2; ++c) {
    mx2 = fmaxf(mx2, pmax2[((size_t)b * NCH2 + c) * 128 + f]);
    sm2 += psum2[((size_t)b * NCH2 + c) * 128 + f];
  }
  xc[(size_t)b * 4816 + f] = xmax1[b * 128 + f] + mx2;
  xc[(size_t)b * 4816 + 128 + f] = xsum1[b * 128 + f] / (float)K1C + sm2 / (float)K2C;
}

// ---------------- d1 partial GEMM ----------------
__global__ __launch_bounds__(128) void k_d1(const float* __restrict__ xc,
                                            const float* __restrict__ Wd1,
                                            float* __restrict__ part) {
  int c = blockIdx.x % D1CH;
  int rg = blockIdx.x / D1CH;
  int k0 = c * 128, kn = min(128, D1K - k0);
  __shared__ float xcs[8][128];
  int tid = threadIdx.x;
#pragma unroll
  for (int l = 0; l < 8; ++l) {
    int i = tid + l * 128;
    int r = i >> 7, k = i & 127;
    xcs[r][k] = (k < kn) ? xc[(size_t)(rg * 8 + r) * D1K + k0 + k] : 0.f;
  }
  __syncthreads();
  int j = tid;
  if (j < 102) {
    float acc[8] = {};
    for (int k = 0; k < kn; ++k) {
      float w = Wd1[(size_t)(k0 + k) * 102 + j];
#pragma unroll
      for (int r = 0; r < 8; ++r) acc[r] += xcs[r][k] * w;
    }
#pragma unroll
    for (int r = 0; r < 8; ++r)
      part[((size_t)(rg * 8 + r) * D1CH + c) * 102 + j] = acc[r];
  }
}

// ---------------- reduce partials + relu + d3 + log_softmax ----------------
__global__ void k_final2(const float* __restrict__ part, const float* __restrict__ bd1,
                         const float* __restrict__ Wd3, const float* __restrict__ bd3,
                         float* __restrict__ out) {
  __shared__ float tmp2[2];
  int b = blockIdx.x, j = threadIdx.x;
  float v = 0.f;
  if (j < 102) {
    float acc = bd1[j];
    for (int c = 0; c < D1CH; ++c) acc += part[((size_t)b * D1CH + c) * 102 + j];
    v = fmaxf(acc, 0.f);
  }
  float c0 = (j < 102) ? v * Wd3[j * 2] : 0.f;
  float c1 = (j < 102) ? v * Wd3[j * 2 + 1] : 0.f;
  float z0 = blockReduceSum128(c0, tmp2) + bd3[0];
  float z1 = blockReduceSum128(c1, tmp2) + bd3[1];
  if (j < 2) {
    float m = fmaxf(z0, z1);
    float lse = m + logf(expf(z0 - m) + expf(z1 - m));
    out[b * 2 + j] = (j == 0 ? z0 : z1) - lse;
  }
}

// ---------------- launch ----------------
extern "C" void kernel_launch(void* const* d_in, const int* in_sizes, int n_in,
                              void* d_out, int out_size, void* d_ws, size_t ws_size,
                              hipStream_t stream) {
  const float* x      = (const float*)d_in[0];
  const float* target = (const float*)d_in[1];
  const int*   esrc   = (const int*)d_in[2];
  const int*   edst   = (const int*)d_in[3];
  const float* W1rel  = (const float*)d_in[4];
  const float* W1root = (const float*)d_in[5];
  const float* b1     = (const float*)d_in[6];
  const float* p1     = (const float*)d_in[7];
  const float* W2rel  = (const float*)d_in[8];
  const float* W2root = (const float*)d_in[9];
  const float* b2     = (const float*)d_in[10];
  const float* p2     = (const float*)d_in[11];
  const float* Wc     = (const float*)d_in[12];
  const float* bc     = (const float*)d_in[13];
  const float* Wihf   = (const float*)d_in[14];
  const float* Whhf   = (const float*)d_in[15];
  const float* bihf   = (const float*)d_in[16];
  const float* bhhf   = (const float*)d_in[17];
  const float* Wihb   = (const float*)d_in[18];
  const float* Whhb   = (const float*)d_in[19];
  const float* bihb   = (const float*)d_in[20];
  const float* bhhb   = (const float*)d_in[21];
  const float* Wd1    = (const float*)d_in[22];
  const float* bd1    = (const float*)d_in[23];
  const float* Wd3    = (const float*)d_in[24];
  const float* bd3    = (const float*)d_in[25];
  float* out = (float*)d_out;

  char* wsb = (char*)d_ws;
  size_t off = 0;
  auto alloc = [&](size_t bytes) -> void* {
    void* p = wsb + off;
    off = (off + bytes + 255) & ~(size_t)255;
    return p;
  };
  float* h1      = (float*)alloc((size_t)BN * 128 * 4);       // 64MB
  u16*   Abf     = (u16*)  alloc((size_t)BB * K1C * 256 * 2); // 53.7MB bf16 [agg|xp]
  u16*   Wfrag   = (u16*)  alloc((size_t)4096 * 8 * 2);       // 64KB fragment-ordered W
  float* agg1    = (float*)alloc((size_t)BN * 4 * 4);
  float* score1  = (float*)alloc((size_t)BN * 4);
  int*   perm1   = (int*)  alloc((size_t)BB * K1C * 4);
  int*   map1    = (int*)  alloc((size_t)BN * 4);
  float* h2      = (float*)alloc((size_t)BB * K1C * 128 * 4);
  float* score2  = (float*)alloc((size_t)BB * K1C * 4);
  int*   perm2   = (int*)  alloc((size_t)BB * K2C * 4);
  float* invp    = (float*)alloc(256);
  float* xs      = (float*)alloc((size_t)TSEQ * BB * 128 * 4);
  float* gi      = (float*)alloc((size_t)2 * TSEQ * BB * 360 * 4);
  float* xc      = (float*)alloc((size_t)BB * 4816 * 4);
  int*   starts2 = (int*)  alloc((size_t)BB * K1C * 4);
  int*   cnt2    = (int*)  alloc((size_t)BB * K1C * 4);
  int*   elist2  = (int*)  alloc((size_t)EDG * 4);
  float* xmax1   = (float*)alloc((size_t)BB * 128 * 4);
  float* xsum1   = (float*)alloc((size_t)BB * 128 * 4);
  float* pmax2   = (float*)alloc((size_t)BB * NCH2 * 128 * 4);
  float* psum2   = (float*)alloc((size_t)BB * NCH2 * 128 * 4);
  float* part    = (float*)alloc((size_t)BB * D1CH * 102 * 4);

  k_pnorm<<<1, 128, 0, stream>>>(p1, p2, invp);
  k_wb<<<16, 256, 0, stream>>>(W2rel, W2root, Wfrag);

  // --- layer 1 ---
  k_l1<<<BB, 1024, 0, stream>>>(esrc, edst, x, agg1);
  k_h1<<<BN * 32 / 256, 256, 0, stream>>>(x, agg1, W1rel, W1root, b1, p1, invp, h1, score1);
  k_sort<<<BB, 512, 0, stream>>>(score1, NN, K1C, perm1, map1);

  // --- layer 2: filtered CSR + aggregate (emits bf16 A) + MFMA GEMM ---
  k_csr2<<<BB, 1024, 0, stream>>>(esrc, edst, map1, starts2, cnt2, elist2);
  k_agg2r<<<BB * 4, 1024, 0, stream>>>(starts2, cnt2, elist2, perm1, score1, h1,
                                       Abf, xmax1, xsum1);
  k_h2m<<<(BB * K1C) / 64, 256, 0, stream>>>(Abf, Wfrag, b2, p2, invp, h2, score2);
  k_sort<<<BB, 512, 0, stream>>>(score2, K1C, K2C, perm2, nullptr);
  k_gatherread<<<BB * NCH2, 128, 0, stream>>>(h2, score2, perm2, nullptr, pmax2, psum2, K2C, NCH2);

  // --- target branch ---
  k_conv<<<BB * TSEQ, 128, 0, stream>>>(target, Wc, bc, xs);
  k_gi<<<2 * TSEQ * 8, 384, 0, stream>>>(xs, Wihf, bihf, Wihb, bihb, gi);
  k_gru<<<2 * 64, 384, 0, stream>>>(gi, Whhf, bhhf, Whhb, bhhb, xc);

  // --- head ---
  k_xg<<<BB, 128, 0, stream>>>(xmax1, xsum1, pmax2, psum2, xc);
  k_d1<<<(BB / 8) * D1CH, 128, 0, stream>>>(xc, Wd1, part);
  k_final2<<<BB, 128, 0, stream>>>(part, bd1, Wd3, bd3, out);
}

// Round 16
// 331.598 us; speedup vs baseline: 1.6422x; 1.0137x over previous
//
#include <hip/hip_runtime.h>
#include <math.h>

#define BB   128
#define NN   1024
#define BN   (BB*NN)          // 131072
#define EDG  (BB*8192)        // 1048576
#define K1C  820
#define K2C  656
#define TSEQ 19
#define HID  120
#define D1K  4816
#define D1CH 38               // ceil(4816/128)
#define NCH2 11               // ceil(656/64)

typedef unsigned short u16;
typedef __attribute__((ext_vector_type(8))) short bf16x8;
typedef __attribute__((ext_vector_type(4))) float f32x4;

__device__ __forceinline__ u16 f2b(float x) {   // fp32 -> bf16 RNE
  unsigned int u = __float_as_uint(x);
  u += 0x7FFFu + ((u >> 16) & 1u);
  return (u16)(u >> 16);
}
__device__ __forceinline__ float b2f(u16 v) {
  return __uint_as_float(((unsigned int)v) << 16);
}

// ---------------- reduction helper (128-thread block) ----------------
__device__ __forceinline__ float blockReduceSum128(float v, float* tmp2) {
#pragma unroll
  for (int o = 32; o > 0; o >>= 1) v += __shfl_down(v, o);
  int lane = threadIdx.x & 63, w = threadIdx.x >> 6;
  if (lane == 0) tmp2[w] = v;
  __syncthreads();
  float r = tmp2[0] + tmp2[1];
  __syncthreads();
  return r;
}

// ---------------- p-norm precompute ----------------
__global__ void k_pnorm(const float* __restrict__ p1, const float* __restrict__ p2,
                        float* __restrict__ invp) {
  __shared__ float tmp2[2];
  float a = p1[threadIdx.x], b = p2[threadIdx.x];
  float s1 = blockReduceSum128(a * a, tmp2);
  float s2 = blockReduceSum128(b * b, tmp2);
  if (threadIdx.x == 0) { invp[0] = 1.f / sqrtf(s1); invp[1] = 1.f / sqrtf(s2); }
}

// ---------------- pack W2rel|W2root into MFMA fragment order (bf16) ----------------
__global__ void k_wb(const float* __restrict__ W2rel, const float* __restrict__ W2root,
                     u16* __restrict__ Wfrag) {
  int idx = blockIdx.x * 256 + threadIdx.x;   // 16 blocks -> 4096
  int lane = idx & 63, ct = (idx >> 6) & 7, ks = idx >> 9;
  int c = ct * 16 + (lane & 15);
  int kbase = ks * 32 + (lane >> 4) * 8;
#pragma unroll
  for (int j = 0; j < 8; ++j) {
    int k = kbase + j;
    float w = (k < 128) ? W2rel[(size_t)k * 128 + c] : W2root[(size_t)(k - 128) * 128 + c];
    Wfrag[(size_t)idx * 8 + j] = f2b(w);
  }
}

// ---------------- fused layer-1 CSR build + aggregate (all in LDS) ----------------
__global__ __launch_bounds__(1024) void k_l1(const int* __restrict__ src,
                                             const int* __restrict__ dst,
                                             const float* __restrict__ x,
                                             float* __restrict__ agg1) {
  __shared__ int hcur[1024];
  __shared__ int sscan[1024];
  __shared__ int ccnt[1024];
  __shared__ int el[8192];
  __shared__ float4 xls4[1024];
  int b = blockIdx.x, tid = threadIdx.x;
  int base = b * 8192, nb = b * 1024;
  hcur[tid] = 0;
  __syncthreads();
#pragma unroll
  for (int it = 0; it < 8; ++it)
    atomicAdd(&hcur[dst[base + it * 1024 + tid] - nb], 1);
  __syncthreads();
  int v = hcur[tid];
  ccnt[tid] = v;
  sscan[tid] = v;
  __syncthreads();
  for (int o = 1; o < 1024; o <<= 1) {
    int t = (tid >= o) ? sscan[tid - o] : 0;
    __syncthreads();
    sscan[tid] += t;
    __syncthreads();
  }
  hcur[tid] = sscan[tid] - v;          // exclusive start (local cursor)
  __syncthreads();
#pragma unroll
  for (int it = 0; it < 8; ++it) {
    int e = base + it * 1024 + tid;
    int d = dst[e] - nb;
    int pos = atomicAdd(&hcur[d], 1);
    el[pos] = src[e] - nb;             // LOCAL src id
  }
  xls4[tid] = ((const float4*)x)[nb + tid];
  __syncthreads();
  const float* xls = (const float*)xls4;
  int rg = tid >> 2, lane = tid & 3;
#pragma unroll
  for (int it = 0; it < 4; ++it) {
    int r = rg + it * 256;
    int n = ccnt[r], s0 = sscan[r] - n;
    float a0 = 0.f, a1 = 0.f;
    int j = 0;
    for (; j + 1 < n; j += 2) {
      a0 += xls[el[s0 + j] * 4 + lane];
      a1 += xls[el[s0 + j + 1] * 4 + lane];
    }
    if (j < n) a0 += xls[el[s0 + j] * 4 + lane];
    agg1[(size_t)(nb + r) * 4 + lane] = a0 + a1;
  }
}

// ---------------- h1 = relu(agg1@W1rel + x@W1root + b1); score1 fused ----------------
__global__ void k_h1(const float* __restrict__ x, const float* __restrict__ agg1,
                     const float* __restrict__ W1rel, const float* __restrict__ W1root,
                     const float* __restrict__ b1, const float* __restrict__ p1,
                     const float* __restrict__ invp,
                     float* __restrict__ h1, float* __restrict__ score1) {
  int tid = blockIdx.x * 256 + threadIdx.x;
  int r = tid >> 5, lane = tid & 31, f4 = lane * 4;
  float4 a = ((const float4*)agg1)[r];
  float4 xv = ((const float4*)x)[r];
  float o[4], dot = 0.f;
#pragma unroll
  for (int j = 0; j < 4; ++j) {
    int f = f4 + j;
    float acc = b1[f]
      + a.x * W1rel[f] + a.y * W1rel[128 + f] + a.z * W1rel[256 + f] + a.w * W1rel[384 + f]
      + xv.x * W1root[f] + xv.y * W1root[128 + f] + xv.z * W1root[256 + f] + xv.w * W1root[384 + f];
    o[j] = fmaxf(acc, 0.f);
    dot += o[j] * p1[f];
  }
  *(float4*)&h1[(size_t)r * 128 + f4] = make_float4(o[0], o[1], o[2], o[3]);
#pragma unroll
  for (int off = 16; off > 0; off >>= 1) dot += __shfl_down(dot, off, 32);
  if (lane == 0) score1[r] = tanhf(dot * invp[0]);
}

// ---------------- per-graph top-k via LDS bitonic sort (1024 slots) ----------------
__global__ void k_sort(const float* __restrict__ score, int n_per, int K,
                       int* __restrict__ perm, int* __restrict__ mapping) {
  __shared__ float s[1024];
  __shared__ int   id[1024];
  int b = blockIdx.x;
  const float* sc = score + (size_t)b * n_per;
  for (int i = threadIdx.x; i < 1024; i += blockDim.x) {
    if (i < n_per) { s[i] = sc[i]; id[i] = i; }
    else           { s[i] = -INFINITY; id[i] = 0x7fffffff; }
  }
  __syncthreads();
  for (int k = 2; k <= 1024; k <<= 1) {
    for (int j = k >> 1; j > 0; j >>= 1) {
      for (int i = threadIdx.x; i < 1024; i += blockDim.x) {
        int l = i ^ j;
        if (l > i) {
          float si = s[i], sl = s[l];
          int ii = id[i], il = id[l];
          bool iBeforeL = (si > sl) || (si == sl && ii < il);
          bool up = ((i & k) == 0);
          if (up ? (!iBeforeL) : iBeforeL) {
            s[i] = sl; s[l] = si; id[i] = il; id[l] = ii;
          }
        }
      }
      __syncthreads();
    }
  }
  for (int r = threadIdx.x; r < K; r += blockDim.x)
    perm[(size_t)b * K + r] = b * n_per + id[r];
  if (mapping) {
    for (int i = threadIdx.x; i < n_per; i += blockDim.x)
      mapping[(size_t)b * n_per + i] = -1;
    __syncthreads();
    for (int r = threadIdx.x; r < K; r += blockDim.x)
      mapping[(size_t)b * n_per + id[r]] = b * K + r;
  }
}

// ---------------- layer-2 gather + partial readout from bf16 h2 ----------------
#define RCH 64
__global__ void k_gatherread(const u16* __restrict__ h2b, const float* __restrict__ score,
                             const int* __restrict__ perm,
                             float* __restrict__ pmax, float* __restrict__ psum,
                             int K, int nch) {
  int b = blockIdx.x / nch, c = blockIdx.x % nch, f = threadIdx.x;  // 128 threads
  int r0 = c * RCH, r1 = min(r0 + RCH, K);
  float mx = -INFINITY, sm = 0.f;
  for (int r = r0; r < r1; ++r) {
    int g = perm[(size_t)b * K + r];
    float v = b2f(h2b[(size_t)g * 128 + f]) * score[g];
    mx = fmaxf(mx, v); sm += v;
  }
  pmax[((size_t)b * nch + c) * 128 + f] = mx;
  psum[((size_t)b * nch + c) * 128 + f] = sm;
}

// ---------------- layer-2 filtered CSR (per-graph, LDS, no global atomics) ----------------
__global__ __launch_bounds__(1024) void k_csr2(const int* __restrict__ src,
                                               const int* __restrict__ dst,
                                               const int* __restrict__ map,
                                               int* __restrict__ starts2,
                                               int* __restrict__ cnt2,
                                               int* __restrict__ elist2) {
  __shared__ int mloc[8192];   // local kept dst per edge, -1 invalid
  __shared__ int msl[8192];    // local kept src per edge
  __shared__ int h[1024];
  __shared__ int s[1024];
  int g = blockIdx.x, tid = threadIdx.x;
  int base = g * 8192, nb2 = g * K1C;
  h[tid] = 0;
  __syncthreads();
#pragma unroll
  for (int it = 0; it < 8; ++it) {
    int e = base + it * 1024 + tid;
    int ms = map[src[e]], md = map[dst[e]];
    bool valid = (ms >= 0) && (md >= 0);
    int idx = it * 1024 + tid;
    int ml = valid ? (md - nb2) : -1;
    mloc[idx] = ml;
    msl[idx] = ms - nb2;
    if (valid) atomicAdd(&h[ml], 1);
  }
  __syncthreads();
  int v = (tid < K1C) ? h[tid] : 0;
  if (tid < K1C) cnt2[nb2 + tid] = v;
  s[tid] = v;
  __syncthreads();
  for (int o = 1; o < 1024; o <<= 1) {
    int t = (tid >= o) ? s[tid - o] : 0;
    __syncthreads();
    s[tid] += t;
    __syncthreads();
  }
  int st = s[tid] - v;
  if (tid < K1C) starts2[nb2 + tid] = base + st;
  h[tid] = st;                        // local cursor
  __syncthreads();
#pragma unroll
  for (int it = 0; it < 8; ++it) {
    int idx = it * 1024 + tid;
    int ml = mloc[idx];
    if (ml >= 0) {
      int pos = atomicAdd(&h[ml], 1);
      elist2[base + pos] = msl[idx];
    }
  }
}

// ---------------- layer-2 aggregate + layer-1 readout; float2/lane; emits bf16 A ----------------
__global__ __launch_bounds__(1024) void k_agg2r(const int* __restrict__ starts2,
                                                const int* __restrict__ cnt2,
                                                const int* __restrict__ elist2,
                                                const int* __restrict__ perm1,
                                                const float* __restrict__ score1,
                                                const float* __restrict__ h1,
                                                u16* __restrict__ Abf,
                                                float* __restrict__ xmax1,
                                                float* __restrict__ xsum1) {
  __shared__ float xls[K1C * 32];     // 104,960 B
  __shared__ int   el[8192];          // 32,768 B
  __shared__ int   sts[K1C];
  __shared__ int   ctn[K1C];
  __shared__ int   pid[K1C];
  __shared__ float scs[K1C];
  __shared__ float red[64][33];       // 8,448 B (reused: max then sum)
  int g = blockIdx.x >> 2, q = blockIdx.x & 3;
  int tid = threadIdx.x;
  int nb2 = g * K1C, base = g * 8192;
  for (int i = tid; i < K1C; i += 1024) {
    int p = perm1[nb2 + i];
    pid[i] = p;
    scs[i] = score1[p];
    sts[i] = starts2[nb2 + i] - base;
    ctn[i] = cnt2[nb2 + i];
  }
  {
    const int4* e4 = (const int4*)(elist2 + base);
    for (int i = tid; i < 2048; i += 1024) ((int4*)el)[i] = e4[i];
  }
  __syncthreads();
  for (int i = tid; i < K1C * 8; i += 1024) {
    int row = i >> 3, f4 = (i & 7) * 4;
    float4 v = *(const float4*)&h1[(size_t)pid[row] * 128 + q * 32 + f4];
    float s = scs[row];
    v.x *= s; v.y *= s; v.z *= s; v.w *= s;
    *(float4*)&xls[row * 32 + f4] = v;
    ushort4 bv;
    bv.x = f2b(v.x); bv.y = f2b(v.y); bv.z = f2b(v.z); bv.w = f2b(v.w);
    *(ushort4*)&Abf[(size_t)(nb2 + row) * 256 + 128 + q * 32 + f4] = bv;  // xp half
  }
  __syncthreads();
  int rg = tid >> 4, f2 = (tid & 15) * 2;   // 64 row-groups x 16 lanes (2 feats each)
  float mx0 = -INFINITY, mx1 = -INFINITY, sm0 = 0.f, sm1 = 0.f;
  for (int r = rg; r < K1C; r += 64) {
    int s0 = sts[r], n = ctn[r];
    float a0 = 0.f, a1 = 0.f, c0 = 0.f, c1 = 0.f;
    int j = 0;
    for (; j + 1 < n; j += 2) {
      float2 v0 = *(const float2*)&xls[el[s0 + j] * 32 + f2];
      float2 v1 = *(const float2*)&xls[el[s0 + j + 1] * 32 + f2];
      a0 += v0.x; a1 += v0.y; c0 += v1.x; c1 += v1.y;
    }
    if (j < n) {
      float2 v = *(const float2*)&xls[el[s0 + j] * 32 + f2];
      a0 += v.x; a1 += v.y;
    }
    ushort2 ov;
    ov.x = f2b(a0 + c0); ov.y = f2b(a1 + c1);
    *(ushort2*)&Abf[(size_t)(nb2 + r) * 256 + q * 32 + f2] = ov;          // agg half
    float2 w = *(const float2*)&xls[r * 32 + f2];                          // layer-1 readout
    mx0 = fmaxf(mx0, w.x); mx1 = fmaxf(mx1, w.y);
    sm0 += w.x; sm1 += w.y;
  }
  red[rg][f2] = mx0; red[rg][f2 + 1] = mx1;
  __syncthreads();
  if (tid < 32) {
    float m = red[0][tid];
#pragma unroll 8
    for (int t2 = 1; t2 < 64; ++t2) m = fmaxf(m, red[t2][tid]);
    xmax1[g * 128 + q * 32 + tid] = m;
  }
  __syncthreads();
  red[rg][f2] = sm0; red[rg][f2 + 1] = sm1;
  __syncthreads();
  if (tid < 32) {
    float s2 = red[0][tid];
#pragma unroll 8
    for (int t2 = 1; t2 < 64; ++t2) s2 += red[t2][tid];
    xsum1[g * 128 + q * 32 + tid] = s2;
  }
}

// ---------------- h2 via MFMA bf16: 64x128 block tile, 4 waves, K=256; bf16 h2 out ----------------
__global__ __launch_bounds__(256, 4) void k_h2m(
    const u16* __restrict__ Abf, const u16* __restrict__ Wfrag,
    const float* __restrict__ b2, const float* __restrict__ p2,
    const float* __restrict__ invp,
    u16* __restrict__ h2b, float* __restrict__ score2) {
  __shared__ u16 Als[64][40];        // padded
  int tid = threadIdx.x;
  int r0 = blockIdx.x * 64;
  int wv = tid >> 6, lane = tid & 63;
  int lr = lane & 15, kg = lane >> 4;
  f32x4 acc[8];
  f32x4 z = {0.f, 0.f, 0.f, 0.f};
#pragma unroll
  for (int ct = 0; ct < 8; ++ct) acc[ct] = z;
  for (int ks = 0; ks < 8; ++ks) {
    {
      int row = tid >> 2, kq = (tid & 3) * 8;
      *(f32x4*)&Als[row][kq] =
          *(const f32x4*)&Abf[(size_t)(r0 + row) * 256 + ks * 32 + kq];
    }
    __syncthreads();
    bf16x8 a = *(const bf16x8*)&Als[wv * 16 + lr][kg * 8];
    const u16* wf = Wfrag + (size_t)ks * 4096;
#pragma unroll
    for (int ct = 0; ct < 8; ++ct) {
      bf16x8 b = *(const bf16x8*)&wf[(ct * 64 + lane) * 8];
      acc[ct] = __builtin_amdgcn_mfma_f32_16x16x32_bf16(a, b, acc[ct], 0, 0, 0);
    }
    __syncthreads();
  }
  float inv = invp[1];
  float dots[4] = {0.f, 0.f, 0.f, 0.f};
#pragma unroll
  for (int ct = 0; ct < 8; ++ct) {
    int c = ct * 16 + lr;
    float bb = b2[c], pp = p2[c];
#pragma unroll
    for (int i = 0; i < 4; ++i) {
      float o = fmaxf(acc[ct][i] + bb, 0.f);
      h2b[(size_t)(r0 + wv * 16 + kg * 4 + i) * 128 + c] = f2b(o);
      dots[i] += o * pp;
    }
  }
#pragma unroll
  for (int i = 0; i < 4; ++i) {
    float d = dots[i];
#pragma unroll
    for (int m = 8; m >= 1; m >>= 1) d += __shfl_xor(d, m);
    if (lr == 0) score2[r0 + wv * 16 + kg * 4 + i] = tanhf(d * inv);
  }
}

// ---------------- target conv + relu + avgpool -> xs[t][b][o] ----------------
__global__ void k_conv(const float* __restrict__ target, const float* __restrict__ Wc,
                       const float* __restrict__ bc, float* __restrict__ xs) {
  int gb = blockIdx.x;               // B*19
  int b = gb / TSEQ, tt = gb % TSEQ;
  int o = threadIdx.x;               // 128
  __shared__ float tg[30][8];
  for (int i = threadIdx.x; i < 210; i += 128) {
    int ch = i / 7, u = i % 7;
    tg[ch][u] = target[((size_t)b * 30 + ch) * 101 + tt * 5 + u];
  }
  __syncthreads();
  const float* w = Wc + (size_t)o * 90;
  float acc5[5] = {0, 0, 0, 0, 0};
  for (int ch = 0; ch < 30; ++ch) {
    float w0 = w[ch * 3], w1 = w[ch * 3 + 1], w2 = w[ch * 3 + 2];
#pragma unroll
    for (int u = 0; u < 5; ++u)
      acc5[u] += tg[ch][u] * w0 + tg[ch][u + 1] * w1 + tg[ch][u + 2] * w2;
  }
  float bo = bc[o], s = 0.f;
#pragma unroll
  for (int u = 0; u < 5; ++u) s += fmaxf(acc5[u] + bo, 0.f);
  xs[((size_t)tt * BB + b) * 128 + o] = s * 0.2f;
}

// ---------------- gi = xs @ Wih^T + bih; 16 batches per block ----------------
#define GIB 16
__global__ __launch_bounds__(384) void k_gi(const float* __restrict__ xs,
                     const float* __restrict__ Wihf, const float* __restrict__ bihf,
                     const float* __restrict__ Wihb, const float* __restrict__ bihb,
                     float* __restrict__ gi) {
  int bg = blockIdx.x & 7;
  int t = (blockIdx.x >> 3) % TSEQ;
  int dir = blockIdx.x / (8 * TSEQ);
  int b0 = bg * GIB;
  __shared__ float xst[GIB][128];
  int tid = threadIdx.x;
  for (int i = tid; i < GIB * 128; i += 384) {
    int bb = i >> 7, k = i & 127;
    xst[bb][k] = xs[((size_t)t * BB + b0 + bb) * 128 + k];
  }
  __syncthreads();
  int j = tid;
  if (j < 360) {
    const float* W = (dir ? Wihb : Wihf) + (size_t)j * 128;
    float bias = (dir ? bihb : bihf)[j];
    float acc[GIB];
#pragma unroll
    for (int bb = 0; bb < GIB; ++bb) acc[bb] = bias;
#pragma unroll 4
    for (int k = 0; k < 128; ++k) {
      float w = W[k];
#pragma unroll
      for (int bb = 0; bb < GIB; ++bb) acc[bb] += xst[bb][k] * w;
    }
    size_t base = ((size_t)dir * TSEQ + t) * BB + b0;
#pragma unroll
    for (int bb = 0; bb < GIB; ++bb) gi[(base + bb) * 360 + j] = acc[bb];
  }
}

// ---------------- GRU recurrence: Whh rows held in REGISTERS, h via LDS broadcast ----------------
__global__ __launch_bounds__(384) void k_gru(const float* __restrict__ gi,
                      const float* __restrict__ Whhf, const float* __restrict__ bhhf,
                      const float* __restrict__ Whhb, const float* __restrict__ bhhb,
                      float* __restrict__ xc) {
  int pair = blockIdx.x & 63, dir = blockIdx.x >> 6;
  int b0 = pair * 2;
  const float* Whh = dir ? Whhb : Whhf;
  const float* bhh = dir ? bhhb : bhhf;
  __shared__ float h_sh[2][HID];
  __shared__ float g0[360], g1[360];
  int j = threadIdx.x;               // 384
  float wrow[HID];
  float bias = 0.f;
  if (j < 360) {
    const float4* W4 = (const float4*)(Whh + (size_t)j * HID);
#pragma unroll
    for (int k4 = 0; k4 < HID / 4; ++k4) {
      float4 w = W4[k4];
      wrow[k4 * 4 + 0] = w.x; wrow[k4 * 4 + 1] = w.y;
      wrow[k4 * 4 + 2] = w.z; wrow[k4 * 4 + 3] = w.w;
    }
    bias = bhh[j];
  }
  if (j < 2 * HID) h_sh[j / HID][j % HID] = 0.f;
  __syncthreads();
  for (int st = 0; st < TSEQ; ++st) {
    int tt = dir ? (TSEQ - 1 - st) : st;
    if (j < 360) {
      float a0 = bias, a1 = bias;
      const float4* h40 = (const float4*)h_sh[0];
      const float4* h41 = (const float4*)h_sh[1];
#pragma unroll
      for (int k4 = 0; k4 < HID / 4; ++k4) {
        float4 v0 = h40[k4];
        float4 v1 = h41[k4];
        a0 += wrow[k4*4+0]*v0.x + wrow[k4*4+1]*v0.y + wrow[k4*4+2]*v0.z + wrow[k4*4+3]*v0.w;
        a1 += wrow[k4*4+0]*v1.x + wrow[k4*4+1]*v1.y + wrow[k4*4+2]*v1.z + wrow[k4*4+3]*v1.w;
      }
      g0[j] = a0; g1[j] = a1;
    }
    __syncthreads();
    if (j < 2 * HID) {
      int bb = j / HID, th = j - bb * HID;
      const float* g = gi + (((size_t)dir * TSEQ + tt) * BB + (b0 + bb)) * 360;
      const float* gh = bb ? g1 : g0;
      float r  = 1.f / (1.f + expf(-(g[th]       + gh[th])));
      float z  = 1.f / (1.f + expf(-(g[120 + th] + gh[120 + th])));
      float ng = tanhf(g[240 + th] + r * gh[240 + th]);
      float hn = (1.f - z) * ng + z * h_sh[bb][th];
      h_sh[bb][th] = hn;
      xc[(size_t)(b0 + bb) * 4816 + 256 + (size_t)tt * 240 + dir * 120 + th] = hn;
    }
    __syncthreads();
  }
}

// ---------------- fused final readout: xc[:, :256] = x1 + x2 ----------------
__global__ void k_xg(const float* __restrict__ xmax1, const float* __restrict__ xsum1,
                     const float* __restrict__ pmax2, const float* __restrict__ psum2,
                     float* __restrict__ xc) {
  int b = blockIdx.x, f = threadIdx.x;  // 128 threads
  float mx2 = -INFINITY, sm2 = 0.f;
  for (int c = 0; c < NCH2; ++c) {
    mx2 = fmaxf(mx2, pmax2[((size_t)b * NCH2 + c) * 128 + f]);
    sm2 += psum2[((size_t)b * NCH2 + c) * 128 + f];
  }
  xc[(size_t)b * 4816 + f] = xmax1[b * 128 + f] + mx2;
  xc[(size_t)b * 4816 + 128 + f] = xsum1[b * 128 + f] / (float)K1C + sm2 / (float)K2C;
}

// ---------------- d1 partial GEMM ----------------
__global__ __launch_bounds__(128) void k_d1(const float* __restrict__ xc,
                                            const float* __restrict__ Wd1,
                                            float* __restrict__ part) {
  int c = blockIdx.x % D1CH;
  int rg = blockIdx.x / D1CH;
  int k0 = c * 128, kn = min(128, D1K - k0);
  __shared__ float xcs[8][128];
  int tid = threadIdx.x;
#pragma unroll
  for (int l = 0; l < 8; ++l) {
    int i = tid + l * 128;
    int r = i >> 7, k = i & 127;
    xcs[r][k] = (k < kn) ? xc[(size_t)(rg * 8 + r) * D1K + k0 + k] : 0.f;
  }
  __syncthreads();
  int j = tid;
  if (j < 102) {
    float acc[8] = {};
    for (int k = 0; k < kn; ++k) {
      float w = Wd1[(size_t)(k0 + k) * 102 + j];
#pragma unroll
      for (int r = 0; r < 8; ++r) acc[r] += xcs[r][k] * w;
    }
#pragma unroll
    for (int r = 0; r < 8; ++r)
      part[((size_t)(rg * 8 + r) * D1CH + c) * 102 + j] = acc[r];
  }
}

// ---------------- reduce partials + relu + d3 + log_softmax ----------------
__global__ void k_final2(const float* __restrict__ part, const float* __restrict__ bd1,
                         const float* __restrict__ Wd3, const float* __restrict__ bd3,
                         float* __restrict__ out) {
  __shared__ float tmp2[2];
  int b = blockIdx.x, j = threadIdx.x;
  float v = 0.f;
  if (j < 102) {
    float acc = bd1[j];
    for (int c = 0; c < D1CH; ++c) acc += part[((size_t)b * D1CH + c) * 102 + j];
    v = fmaxf(acc, 0.f);
  }
  float c0 = (j < 102) ? v * Wd3[j * 2] : 0.f;
  float c1 = (j < 102) ? v * Wd3[j * 2 + 1] : 0.f;
  float z0 = blockReduceSum128(c0, tmp2) + bd3[0];
  float z1 = blockReduceSum128(c1, tmp2) + bd3[1];
  if (j < 2) {
    float m = fmaxf(z0, z1);
    float lse = m + logf(expf(z0 - m) + expf(z1 - m));
    out[b * 2 + j] = (j == 0 ? z0 : z1) - lse;
  }
}

// ---------------- launch ----------------
extern "C" void kernel_launch(void* const* d_in, const int* in_sizes, int n_in,
                              void* d_out, int out_size, void* d_ws, size_t ws_size,
                              hipStream_t stream) {
  const float* x      = (const float*)d_in[0];
  const float* target = (const float*)d_in[1];
  const int*   esrc   = (const int*)d_in[2];
  const int*   edst   = (const int*)d_in[3];
  const float* W1rel  = (const float*)d_in[4];
  const float* W1root = (const float*)d_in[5];
  const float* b1     = (const float*)d_in[6];
  const float* p1     = (const float*)d_in[7];
  const float* W2rel  = (const float*)d_in[8];
  const float* W2root = (const float*)d_in[9];
  const float* b2     = (const float*)d_in[10];
  const float* p2     = (const float*)d_in[11];
  const float* Wc     = (const float*)d_in[12];
  const float* bc     = (const float*)d_in[13];
  const float* Wihf   = (const float*)d_in[14];
  const float* Whhf   = (const float*)d_in[15];
  const float* bihf   = (const float*)d_in[16];
  const float* bhhf   = (const float*)d_in[17];
  const float* Wihb   = (const float*)d_in[18];
  const float* Whhb   = (const float*)d_in[19];
  const float* bihb   = (const float*)d_in[20];
  const float* bhhb   = (const float*)d_in[21];
  const float* Wd1    = (const float*)d_in[22];
  const float* bd1    = (const float*)d_in[23];
  const float* Wd3    = (const float*)d_in[24];
  const float* bd3    = (const float*)d_in[25];
  float* out = (float*)d_out;

  char* wsb = (char*)d_ws;
  size_t off = 0;
  auto alloc = [&](size_t bytes) -> void* {
    void* p = wsb + off;
    off = (off + bytes + 255) & ~(size_t)255;
    return p;
  };
  float* h1      = (float*)alloc((size_t)BN * 128 * 4);       // 64MB
  u16*   Abf     = (u16*)  alloc((size_t)BB * K1C * 256 * 2); // 53.7MB bf16 [agg|xp]
  u16*   Wfrag   = (u16*)  alloc((size_t)4096 * 8 * 2);       // 64KB fragment-ordered W
  float* agg1    = (float*)alloc((size_t)BN * 4 * 4);
  float* score1  = (float*)alloc((size_t)BN * 4);
  int*   perm1   = (int*)  alloc((size_t)BB * K1C * 4);
  int*   map1    = (int*)  alloc((size_t)BN * 4);
  u16*   h2b     = (u16*)  alloc((size_t)BB * K1C * 128 * 2); // 26.9MB bf16
  float* score2  = (float*)alloc((size_t)BB * K1C * 4);
  int*   perm2   = (int*)  alloc((size_t)BB * K2C * 4);
  float* invp    = (float*)alloc(256);
  float* xs      = (float*)alloc((size_t)TSEQ * BB * 128 * 4);
  float* gi      = (float*)alloc((size_t)2 * TSEQ * BB * 360 * 4);
  float* xc      = (float*)alloc((size_t)BB * 4816 * 4);
  int*   starts2 = (int*)  alloc((size_t)BB * K1C * 4);
  int*   cnt2    = (int*)  alloc((size_t)BB * K1C * 4);
  int*   elist2  = (int*)  alloc((size_t)EDG * 4);
  float* xmax1   = (float*)alloc((size_t)BB * 128 * 4);
  float* xsum1   = (float*)alloc((size_t)BB * 128 * 4);
  float* pmax2   = (float*)alloc((size_t)BB * NCH2 * 128 * 4);
  float* psum2   = (float*)alloc((size_t)BB * NCH2 * 128 * 4);
  float* part    = (float*)alloc((size_t)BB * D1CH * 102 * 4);

  k_pnorm<<<1, 128, 0, stream>>>(p1, p2, invp);
  k_wb<<<16, 256, 0, stream>>>(W2rel, W2root, Wfrag);

  // --- layer 1 ---
  k_l1<<<BB, 1024, 0, stream>>>(esrc, edst, x, agg1);
  k_h1<<<BN * 32 / 256, 256, 0, stream>>>(x, agg1, W1rel, W1root, b1, p1, invp, h1, score1);
  k_sort<<<BB, 512, 0, stream>>>(score1, NN, K1C, perm1, map1);

  // --- layer 2: filtered CSR + aggregate (emits bf16 A) + MFMA GEMM ---
  k_csr2<<<BB, 1024, 0, stream>>>(esrc, edst, map1, starts2, cnt2, elist2);
  k_agg2r<<<BB * 4, 1024, 0, stream>>>(starts2, cnt2, elist2, perm1, score1, h1,
                                       Abf, xmax1, xsum1);
  k_h2m<<<(BB * K1C) / 64, 256, 0, stream>>>(Abf, Wfrag, b2, p2, invp, h2b, score2);
  k_sort<<<BB, 512, 0, stream>>>(score2, K1C, K2C, perm2, nullptr);
  k_gatherread<<<BB * NCH2, 128, 0, stream>>>(h2b, score2, perm2, pmax2, psum2, K2C, NCH2);

  // --- target branch ---
  k_conv<<<BB * TSEQ, 128, 0, stream>>>(target, Wc, bc, xs);
  k_gi<<<2 * TSEQ * 8, 384, 0, stream>>>(xs, Wihf, bihf, Wihb, bihb, gi);
  k_gru<<<2 * 64, 384, 0, stream>>>(gi, Whhf, bhhf, Whhb, bhhb, xc);

  // --- head ---
  k_xg<<<BB, 128, 0, stream>>>(xmax1, xsum1, pmax2, psum2, xc);
  k_d1<<<(BB / 8) * D1CH, 128, 0, stream>>>(xc, Wd1, part);
  k_final2<<<BB, 128, 0, stream>>>(part, bd1, Wd3, bd3, out);
}

// Round 17
// 308.018 us; speedup vs baseline: 1.7679x; 1.0766x over previous
//
#include <hip/hip_runtime.h>
#include <math.h>

#define BB   128
#define NN   1024
#define BN   (BB*NN)          // 131072
#define EDG  (BB*8192)        // 1048576
#define K1C  820
#define K2C  656
#define TSEQ 19
#define HID  120
#define D1K  4816
#define D1CH 76               // ceil(4816/64)
#define NCH2 11               // ceil(656/64)

typedef unsigned short u16;
typedef __attribute__((ext_vector_type(8))) short bf16x8;
typedef __attribute__((ext_vector_type(4))) float f32x4;

__device__ __forceinline__ u16 f2b(float x) {   // fp32 -> bf16 RNE
  unsigned int u = __float_as_uint(x);
  u += 0x7FFFu + ((u >> 16) & 1u);
  return (u16)(u >> 16);
}
__device__ __forceinline__ float b2f(u16 v) {
  return __uint_as_float(((unsigned int)v) << 16);
}

// ---------------- reduction helper (128-thread block) ----------------
__device__ __forceinline__ float blockReduceSum128(float v, float* tmp2) {
#pragma unroll
  for (int o = 32; o > 0; o >>= 1) v += __shfl_down(v, o);
  int lane = threadIdx.x & 63, w = threadIdx.x >> 6;
  if (lane == 0) tmp2[w] = v;
  __syncthreads();
  float r = tmp2[0] + tmp2[1];
  __syncthreads();
  return r;
}

// ---------------- p-norm precompute ----------------
__global__ void k_pnorm(const float* __restrict__ p1, const float* __restrict__ p2,
                        float* __restrict__ invp) {
  __shared__ float tmp2[2];
  float a = p1[threadIdx.x], b = p2[threadIdx.x];
  float s1 = blockReduceSum128(a * a, tmp2);
  float s2 = blockReduceSum128(b * b, tmp2);
  if (threadIdx.x == 0) { invp[0] = 1.f / sqrtf(s1); invp[1] = 1.f / sqrtf(s2); }
}

// ---------------- pack W2rel|W2root into MFMA fragment order (bf16) ----------------
__global__ void k_wb(const float* __restrict__ W2rel, const float* __restrict__ W2root,
                     u16* __restrict__ Wfrag) {
  int idx = blockIdx.x * 256 + threadIdx.x;   // 16 blocks -> 4096
  int lane = idx & 63, ct = (idx >> 6) & 7, ks = idx >> 9;
  int c = ct * 16 + (lane & 15);
  int kbase = ks * 32 + (lane >> 4) * 8;
#pragma unroll
  for (int j = 0; j < 8; ++j) {
    int k = kbase + j;
    float w = (k < 128) ? W2rel[(size_t)k * 128 + c] : W2root[(size_t)(k - 128) * 128 + c];
    Wfrag[(size_t)idx * 8 + j] = f2b(w);
  }
}

// ---------------- fused layer-1 CSR build + aggregate (all in LDS) ----------------
__global__ __launch_bounds__(1024) void k_l1(const int* __restrict__ src,
                                             const int* __restrict__ dst,
                                             const float* __restrict__ x,
                                             float* __restrict__ agg1) {
  __shared__ int hcur[1024];
  __shared__ int sscan[1024];
  __shared__ int ccnt[1024];
  __shared__ int el[8192];
  __shared__ float4 xls4[1024];
  int b = blockIdx.x, tid = threadIdx.x;
  int base = b * 8192, nb = b * 1024;
  hcur[tid] = 0;
  __syncthreads();
#pragma unroll
  for (int it = 0; it < 8; ++it)
    atomicAdd(&hcur[dst[base + it * 1024 + tid] - nb], 1);
  __syncthreads();
  int v = hcur[tid];
  ccnt[tid] = v;
  sscan[tid] = v;
  __syncthreads();
  for (int o = 1; o < 1024; o <<= 1) {
    int t = (tid >= o) ? sscan[tid - o] : 0;
    __syncthreads();
    sscan[tid] += t;
    __syncthreads();
  }
  hcur[tid] = sscan[tid] - v;          // exclusive start (local cursor)
  __syncthreads();
#pragma unroll
  for (int it = 0; it < 8; ++it) {
    int e = base + it * 1024 + tid;
    int d = dst[e] - nb;
    int pos = atomicAdd(&hcur[d], 1);
    el[pos] = src[e] - nb;             // LOCAL src id
  }
  xls4[tid] = ((const float4*)x)[nb + tid];
  __syncthreads();
  const float* xls = (const float*)xls4;
  int rg = tid >> 2, lane = tid & 3;
#pragma unroll
  for (int it = 0; it < 4; ++it) {
    int r = rg + it * 256;
    int n = ccnt[r], s0 = sscan[r] - n;
    float a0 = 0.f, a1 = 0.f;
    int j = 0;
    for (; j + 1 < n; j += 2) {
      a0 += xls[el[s0 + j] * 4 + lane];
      a1 += xls[el[s0 + j + 1] * 4 + lane];
    }
    if (j < n) a0 += xls[el[s0 + j] * 4 + lane];
    agg1[(size_t)(nb + r) * 4 + lane] = a0 + a1;
  }
}

// ---------------- h1 = relu(agg1@W1rel + x@W1root + b1); score1 fused ----------------
__global__ void k_h1(const float* __restrict__ x, const float* __restrict__ agg1,
                     const float* __restrict__ W1rel, const float* __restrict__ W1root,
                     const float* __restrict__ b1, const float* __restrict__ p1,
                     const float* __restrict__ invp,
                     float* __restrict__ h1, float* __restrict__ score1) {
  int tid = blockIdx.x * 256 + threadIdx.x;
  int r = tid >> 5, lane = tid & 31, f4 = lane * 4;
  float4 a = ((const float4*)agg1)[r];
  float4 xv = ((const float4*)x)[r];
  float o[4], dot = 0.f;
#pragma unroll
  for (int j = 0; j < 4; ++j) {
    int f = f4 + j;
    float acc = b1[f]
      + a.x * W1rel[f] + a.y * W1rel[128 + f] + a.z * W1rel[256 + f] + a.w * W1rel[384 + f]
      + xv.x * W1root[f] + xv.y * W1root[128 + f] + xv.z * W1root[256 + f] + xv.w * W1root[384 + f];
    o[j] = fmaxf(acc, 0.f);
    dot += o[j] * p1[f];
  }
  *(float4*)&h1[(size_t)r * 128 + f4] = make_float4(o[0], o[1], o[2], o[3]);
#pragma unroll
  for (int off = 16; off > 0; off >>= 1) dot += __shfl_down(dot, off, 32);
  if (lane == 0) score1[r] = tanhf(dot * invp[0]);
}

// ---------------- per-graph top-k via LDS bitonic sort (1024 slots) ----------------
__global__ void k_sort(const float* __restrict__ score, int n_per, int K,
                       int* __restrict__ perm, int* __restrict__ mapping) {
  __shared__ float s[1024];
  __shared__ int   id[1024];
  int b = blockIdx.x;
  const float* sc = score + (size_t)b * n_per;
  for (int i = threadIdx.x; i < 1024; i += blockDim.x) {
    if (i < n_per) { s[i] = sc[i]; id[i] = i; }
    else           { s[i] = -INFINITY; id[i] = 0x7fffffff; }
  }
  __syncthreads();
  for (int k = 2; k <= 1024; k <<= 1) {
    for (int j = k >> 1; j > 0; j >>= 1) {
      for (int i = threadIdx.x; i < 1024; i += blockDim.x) {
        int l = i ^ j;
        if (l > i) {
          float si = s[i], sl = s[l];
          int ii = id[i], il = id[l];
          bool iBeforeL = (si > sl) || (si == sl && ii < il);
          bool up = ((i & k) == 0);
          if (up ? (!iBeforeL) : iBeforeL) {
            s[i] = sl; s[l] = si; id[i] = il; id[l] = ii;
          }
        }
      }
      __syncthreads();
    }
  }
  for (int r = threadIdx.x; r < K; r += blockDim.x)
    perm[(size_t)b * K + r] = b * n_per + id[r];
  if (mapping) {
    for (int i = threadIdx.x; i < n_per; i += blockDim.x)
      mapping[(size_t)b * n_per + i] = -1;
    __syncthreads();
    for (int r = threadIdx.x; r < K; r += blockDim.x)
      mapping[(size_t)b * n_per + id[r]] = b * K + r;
  }
}

// ---------------- layer-2 gather + partial readout from bf16 h2 ----------------
#define RCH 64
__global__ void k_gatherread(const u16* __restrict__ h2b, const float* __restrict__ score,
                             const int* __restrict__ perm,
                             float* __restrict__ pmax, float* __restrict__ psum,
                             int K, int nch) {
  int b = blockIdx.x / nch, c = blockIdx.x % nch, f = threadIdx.x;  // 128 threads
  int r0 = c * RCH, r1 = min(r0 + RCH, K);
  float mx = -INFINITY, sm = 0.f;
  for (int r = r0; r < r1; ++r) {
    int g = perm[(size_t)b * K + r];
    float v = b2f(h2b[(size_t)g * 128 + f]) * score[g];
    mx = fmaxf(mx, v); sm += v;
  }
  pmax[((size_t)b * nch + c) * 128 + f] = mx;
  psum[((size_t)b * nch + c) * 128 + f] = sm;
}

// ---------------- layer-2 filtered CSR (per-graph, LDS, no global atomics) ----------------
__global__ __launch_bounds__(1024) void k_csr2(const int* __restrict__ src,
                                               const int* __restrict__ dst,
                                               const int* __restrict__ map,
                                               int* __restrict__ starts2,
                                               int* __restrict__ cnt2,
                                               int* __restrict__ elist2) {
  __shared__ int mloc[8192];   // local kept dst per edge, -1 invalid
  __shared__ int msl[8192];    // local kept src per edge
  __shared__ int h[1024];
  __shared__ int s[1024];
  int g = blockIdx.x, tid = threadIdx.x;
  int base = g * 8192, nb2 = g * K1C;
  h[tid] = 0;
  __syncthreads();
#pragma unroll
  for (int it = 0; it < 8; ++it) {
    int e = base + it * 1024 + tid;
    int ms = map[src[e]], md = map[dst[e]];
    bool valid = (ms >= 0) && (md >= 0);
    int idx = it * 1024 + tid;
    int ml = valid ? (md - nb2) : -1;
    mloc[idx] = ml;
    msl[idx] = ms - nb2;
    if (valid) atomicAdd(&h[ml], 1);
  }
  __syncthreads();
  int v = (tid < K1C) ? h[tid] : 0;
  if (tid < K1C) cnt2[nb2 + tid] = v;
  s[tid] = v;
  __syncthreads();
  for (int o = 1; o < 1024; o <<= 1) {
    int t = (tid >= o) ? s[tid - o] : 0;
    __syncthreads();
    s[tid] += t;
    __syncthreads();
  }
  int st = s[tid] - v;
  if (tid < K1C) starts2[nb2 + tid] = base + st;
  h[tid] = st;                        // local cursor
  __syncthreads();
#pragma unroll
  for (int it = 0; it < 8; ++it) {
    int idx = it * 1024 + tid;
    int ml = mloc[idx];
    if (ml >= 0) {
      int pos = atomicAdd(&h[ml], 1);
      elist2[base + pos] = msl[idx];
    }
  }
}

// ---------------- layer-2 aggregate + layer-1 readout; float2/lane; emits bf16 A ----------------
__global__ __launch_bounds__(1024) void k_agg2r(const int* __restrict__ starts2,
                                                const int* __restrict__ cnt2,
                                                const int* __restrict__ elist2,
                                                const int* __restrict__ perm1,
                                                const float* __restrict__ score1,
                                                const float* __restrict__ h1,
                                                u16* __restrict__ Abf,
                                                float* __restrict__ xmax1,
                                                float* __restrict__ xsum1) {
  __shared__ float xls[K1C * 32];     // 104,960 B
  __shared__ int   el[8192];          // 32,768 B
  __shared__ int   sts[K1C];
  __shared__ int   ctn[K1C];
  __shared__ int   pid[K1C];
  __shared__ float scs[K1C];
  __shared__ float red[64][33];       // 8,448 B (reused: max then sum)
  int g = blockIdx.x >> 2, q = blockIdx.x & 3;
  int tid = threadIdx.x;
  int nb2 = g * K1C, base = g * 8192;
  for (int i = tid; i < K1C; i += 1024) {
    int p = perm1[nb2 + i];
    pid[i] = p;
    scs[i] = score1[p];
    sts[i] = starts2[nb2 + i] - base;
    ctn[i] = cnt2[nb2 + i];
  }
  {
    const int4* e4 = (const int4*)(elist2 + base);
    for (int i = tid; i < 2048; i += 1024) ((int4*)el)[i] = e4[i];
  }
  __syncthreads();
  for (int i = tid; i < K1C * 8; i += 1024) {
    int row = i >> 3, f4 = (i & 7) * 4;
    float4 v = *(const float4*)&h1[(size_t)pid[row] * 128 + q * 32 + f4];
    float s = scs[row];
    v.x *= s; v.y *= s; v.z *= s; v.w *= s;
    *(float4*)&xls[row * 32 + f4] = v;
    ushort4 bv;
    bv.x = f2b(v.x); bv.y = f2b(v.y); bv.z = f2b(v.z); bv.w = f2b(v.w);
    *(ushort4*)&Abf[(size_t)(nb2 + row) * 256 + 128 + q * 32 + f4] = bv;  // xp half
  }
  __syncthreads();
  int rg = tid >> 4, f2 = (tid & 15) * 2;   // 64 row-groups x 16 lanes (2 feats each)
  float mx0 = -INFINITY, mx1 = -INFINITY, sm0 = 0.f, sm1 = 0.f;
  for (int r = rg; r < K1C; r += 64) {
    int s0 = sts[r], n = ctn[r];
    float a0 = 0.f, a1 = 0.f, c0 = 0.f, c1 = 0.f;
    int j = 0;
    for (; j + 1 < n; j += 2) {
      float2 v0 = *(const float2*)&xls[el[s0 + j] * 32 + f2];
      float2 v1 = *(const float2*)&xls[el[s0 + j + 1] * 32 + f2];
      a0 += v0.x; a1 += v0.y; c0 += v1.x; c1 += v1.y;
    }
    if (j < n) {
      float2 v = *(const float2*)&xls[el[s0 + j] * 32 + f2];
      a0 += v.x; a1 += v.y;
    }
    ushort2 ov;
    ov.x = f2b(a0 + c0); ov.y = f2b(a1 + c1);
    *(ushort2*)&Abf[(size_t)(nb2 + r) * 256 + q * 32 + f2] = ov;          // agg half
    float2 w = *(const float2*)&xls[r * 32 + f2];                          // layer-1 readout
    mx0 = fmaxf(mx0, w.x); mx1 = fmaxf(mx1, w.y);
    sm0 += w.x; sm1 += w.y;
  }
  red[rg][f2] = mx0; red[rg][f2 + 1] = mx1;
  __syncthreads();
  if (tid < 32) {
    float m = red[0][tid];
#pragma unroll 8
    for (int t2 = 1; t2 < 64; ++t2) m = fmaxf(m, red[t2][tid]);
    xmax1[g * 128 + q * 32 + tid] = m;
  }
  __syncthreads();
  red[rg][f2] = sm0; red[rg][f2 + 1] = sm1;
  __syncthreads();
  if (tid < 32) {
    float s2 = red[0][tid];
#pragma unroll 8
    for (int t2 = 1; t2 < 64; ++t2) s2 += red[t2][tid];
    xsum1[g * 128 + q * 32 + tid] = s2;
  }
}

// ---------------- h2 via MFMA bf16: 64x128 block tile, 4 waves, K=256; bf16 h2 out ----------------
__global__ __launch_bounds__(256, 4) void k_h2m(
    const u16* __restrict__ Abf, const u16* __restrict__ Wfrag,
    const float* __restrict__ b2, const float* __restrict__ p2,
    const float* __restrict__ invp,
    u16* __restrict__ h2b, float* __restrict__ score2) {
  __shared__ u16 Als[64][40];        // padded
  int tid = threadIdx.x;
  int r0 = blockIdx.x * 64;
  int wv = tid >> 6, lane = tid & 63;
  int lr = lane & 15, kg = lane >> 4;
  f32x4 acc[8];
  f32x4 z = {0.f, 0.f, 0.f, 0.f};
#pragma unroll
  for (int ct = 0; ct < 8; ++ct) acc[ct] = z;
  for (int ks = 0; ks < 8; ++ks) {
    {
      int row = tid >> 2, kq = (tid & 3) * 8;
      *(f32x4*)&Als[row][kq] =
          *(const f32x4*)&Abf[(size_t)(r0 + row) * 256 + ks * 32 + kq];
    }
    __syncthreads();
    bf16x8 a = *(const bf16x8*)&Als[wv * 16 + lr][kg * 8];
    const u16* wf = Wfrag + (size_t)ks * 4096;
#pragma unroll
    for (int ct = 0; ct < 8; ++ct) {
      bf16x8 b = *(const bf16x8*)&wf[(ct * 64 + lane) * 8];
      acc[ct] = __builtin_amdgcn_mfma_f32_16x16x32_bf16(a, b, acc[ct], 0, 0, 0);
    }
    __syncthreads();
  }
  float inv = invp[1];
  float dots[4] = {0.f, 0.f, 0.f, 0.f};
#pragma unroll
  for (int ct = 0; ct < 8; ++ct) {
    int c = ct * 16 + lr;
    float bb = b2[c], pp = p2[c];
#pragma unroll
    for (int i = 0; i < 4; ++i) {
      float o = fmaxf(acc[ct][i] + bb, 0.f);
      h2b[(size_t)(r0 + wv * 16 + kg * 4 + i) * 128 + c] = f2b(o);
      dots[i] += o * pp;
    }
  }
#pragma unroll
  for (int i = 0; i < 4; ++i) {
    float d = dots[i];
#pragma unroll
    for (int m = 8; m >= 1; m >>= 1) d += __shfl_xor(d, m);
    if (lr == 0) score2[r0 + wv * 16 + kg * 4 + i] = tanhf(d * inv);
  }
}

// ---------------- target conv + relu + avgpool -> xs[t][b][o] ----------------
__global__ void k_conv(const float* __restrict__ target, const float* __restrict__ Wc,
                       const float* __restrict__ bc, float* __restrict__ xs) {
  int gb = blockIdx.x;               // B*19
  int b = gb / TSEQ, tt = gb % TSEQ;
  int o = threadIdx.x;               // 128
  __shared__ float tg[30][8];
  for (int i = threadIdx.x; i < 210; i += 128) {
    int ch = i / 7, u = i % 7;
    tg[ch][u] = target[((size_t)b * 30 + ch) * 101 + tt * 5 + u];
  }
  __syncthreads();
  const float* w = Wc + (size_t)o * 90;
  float acc5[5] = {0, 0, 0, 0, 0};
  for (int ch = 0; ch < 30; ++ch) {
    float w0 = w[ch * 3], w1 = w[ch * 3 + 1], w2 = w[ch * 3 + 2];
#pragma unroll
    for (int u = 0; u < 5; ++u)
      acc5[u] += tg[ch][u] * w0 + tg[ch][u + 1] * w1 + tg[ch][u + 2] * w2;
  }
  float bo = bc[o], s = 0.f;
#pragma unroll
  for (int u = 0; u < 5; ++u) s += fmaxf(acc5[u] + bo, 0.f);
  xs[((size_t)tt * BB + b) * 128 + o] = s * 0.2f;
}

// ---------------- gi = xs @ Wih^T + bih; 16 batches per block ----------------
#define GIB 16
__global__ __launch_bounds__(384) void k_gi(const float* __restrict__ xs,
                     const float* __restrict__ Wihf, const float* __restrict__ bihf,
                     const float* __restrict__ Wihb, const float* __restrict__ bihb,
                     float* __restrict__ gi) {
  int bg = blockIdx.x & 7;
  int t = (blockIdx.x >> 3) % TSEQ;
  int dir = blockIdx.x / (8 * TSEQ);
  int b0 = bg * GIB;
  __shared__ float xst[GIB][128];
  int tid = threadIdx.x;
  for (int i = tid; i < GIB * 128; i += 384) {
    int bb = i >> 7, k = i & 127;
    xst[bb][k] = xs[((size_t)t * BB + b0 + bb) * 128 + k];
  }
  __syncthreads();
  int j = tid;
  if (j < 360) {
    const float* W = (dir ? Wihb : Wihf) + (size_t)j * 128;
    float bias = (dir ? bihb : bihf)[j];
    float acc[GIB];
#pragma unroll
    for (int bb = 0; bb < GIB; ++bb) acc[bb] = bias;
#pragma unroll 4
    for (int k = 0; k < 128; ++k) {
      float w = W[k];
#pragma unroll
      for (int bb = 0; bb < GIB; ++bb) acc[bb] += xst[bb][k] * w;
    }
    size_t base = ((size_t)dir * TSEQ + t) * BB + b0;
#pragma unroll
    for (int bb = 0; bb < GIB; ++bb) gi[(base + bb) * 360 + j] = acc[bb];
  }
}

// ---------------- GRU recurrence: Whh rows held in REGISTERS, h via LDS broadcast ----------------
__global__ __launch_bounds__(384) void k_gru(const float* __restrict__ gi,
                      const float* __restrict__ Whhf, const float* __restrict__ bhhf,
                      const float* __restrict__ Whhb, const float* __restrict__ bhhb,
                      float* __restrict__ xc) {
  int pair = blockIdx.x & 63, dir = blockIdx.x >> 6;
  int b0 = pair * 2;
  const float* Whh = dir ? Whhb : Whhf;
  const float* bhh = dir ? bhhb : bhhf;
  __shared__ float h_sh[2][HID];
  __shared__ float g0[360], g1[360];
  int j = threadIdx.x;               // 384
  float wrow[HID];
  float bias = 0.f;
  if (j < 360) {
    const float4* W4 = (const float4*)(Whh + (size_t)j * HID);
#pragma unroll
    for (int k4 = 0; k4 < HID / 4; ++k4) {
      float4 w = W4[k4];
      wrow[k4 * 4 + 0] = w.x; wrow[k4 * 4 + 1] = w.y;
      wrow[k4 * 4 + 2] = w.z; wrow[k4 * 4 + 3] = w.w;
    }
    bias = bhh[j];
  }
  if (j < 2 * HID) h_sh[j / HID][j % HID] = 0.f;
  __syncthreads();
  for (int st = 0; st < TSEQ; ++st) {
    int tt = dir ? (TSEQ - 1 - st) : st;
    if (j < 360) {
      float a0 = bias, a1 = bias;
      const float4* h40 = (const float4*)h_sh[0];
      const float4* h41 = (const float4*)h_sh[1];
#pragma unroll
      for (int k4 = 0; k4 < HID / 4; ++k4) {
        float4 v0 = h40[k4];
        float4 v1 = h41[k4];
        a0 += wrow[k4*4+0]*v0.x + wrow[k4*4+1]*v0.y + wrow[k4*4+2]*v0.z + wrow[k4*4+3]*v0.w;
        a1 += wrow[k4*4+0]*v1.x + wrow[k4*4+1]*v1.y + wrow[k4*4+2]*v1.z + wrow[k4*4+3]*v1.w;
      }
      g0[j] = a0; g1[j] = a1;
    }
    __syncthreads();
    if (j < 2 * HID) {
      int bb = j / HID, th = j - bb * HID;
      const float* g = gi + (((size_t)dir * TSEQ + tt) * BB + (b0 + bb)) * 360;
      const float* gh = bb ? g1 : g0;
      float r  = 1.f / (1.f + expf(-(g[th]       + gh[th])));
      float z  = 1.f / (1.f + expf(-(g[120 + th] + gh[120 + th])));
      float ng = tanhf(g[240 + th] + r * gh[240 + th]);
      float hn = (1.f - z) * ng + z * h_sh[bb][th];
      h_sh[bb][th] = hn;
      xc[(size_t)(b0 + bb) * 4816 + 256 + (size_t)tt * 240 + dir * 120 + th] = hn;
    }
    __syncthreads();
  }
}

// ---------------- fused final readout: xc[:, :256] = x1 + x2 ----------------
__global__ void k_xg(const float* __restrict__ xmax1, const float* __restrict__ xsum1,
                     const float* __restrict__ pmax2, const float* __restrict__ psum2,
                     float* __restrict__ xc) {
  int b = blockIdx.x, f = threadIdx.x;  // 128 threads
  float mx2 = -INFINITY, sm2 = 0.f;
  for (int c = 0; c < NCH2; ++c) {
    mx2 = fmaxf(mx2, pmax2[((size_t)b * NCH2 + c) * 128 + f]);
    sm2 += psum2[((size_t)b * NCH2 + c) * 128 + f];
  }
  xc[(size_t)b * 4816 + f] = xmax1[b * 128 + f] + mx2;
  xc[(size_t)b * 4816 + 128 + f] = xsum1[b * 128 + f] / (float)K1C + sm2 / (float)K2C;
}

// ---------------- d1 partial GEMM: K-chunk 64 staged in LDS, 4 rows/block, grid 2432 ----------------
__global__ __launch_bounds__(128) void k_d1(const float* __restrict__ xc,
                                            const float* __restrict__ Wd1,
                                            float* __restrict__ part) {
  int c = blockIdx.x % D1CH;          // k-chunk of 64
  int rg = blockIdx.x / D1CH;         // row group of 4 (0..31)
  int k0 = c * 64, kn = min(64, D1K - k0);
  __shared__ float wls[64 * 102];     // 26.1 KB, [k][j] contiguous
  __shared__ float xcs[4][64];
  int tid = threadIdx.x;
  for (int i = tid; i < 4 * 64; i += 128) {
    int r = i >> 6, k = i & 63;
    xcs[r][k] = (k < kn) ? xc[(size_t)(rg * 4 + r) * D1K + k0 + k] : 0.f;
  }
  {
    // Wd1[(k0+k)*102+j] over k,j is contiguous: Wd1 + k0*102, kn*102 floats
    const float2* s2 = (const float2*)(Wd1 + (size_t)k0 * 102);
    float2* d2 = (float2*)wls;
    int n2 = (kn * 102) >> 1;
    for (int i = tid; i < n2; i += 128) d2[i] = s2[i];
  }
  __syncthreads();
  int j = tid;
  if (j < 102) {
    float a0 = 0.f, a1 = 0.f, a2 = 0.f, a3 = 0.f;
#pragma unroll 4
    for (int k = 0; k < kn; ++k) {
      float w = wls[k * 102 + j];
      a0 += xcs[0][k] * w; a1 += xcs[1][k] * w;
      a2 += xcs[2][k] * w; a3 += xcs[3][k] * w;
    }
    part[((size_t)(rg * 4 + 0) * D1CH + c) * 102 + j] = a0;
    part[((size_t)(rg * 4 + 1) * D1CH + c) * 102 + j] = a1;
    part[((size_t)(rg * 4 + 2) * D1CH + c) * 102 + j] = a2;
    part[((size_t)(rg * 4 + 3) * D1CH + c) * 102 + j] = a3;
  }
}

// ---------------- reduce partials + relu + d3 + log_softmax ----------------
__global__ void k_final2(const float* __restrict__ part, const float* __restrict__ bd1,
                         const float* __restrict__ Wd3, const float* __restrict__ bd3,
                         float* __restrict__ out) {
  __shared__ float tmp2[2];
  int b = blockIdx.x, j = threadIdx.x;
  float v = 0.f;
  if (j < 102) {
    const float* pb = part + (size_t)b * D1CH * 102 + j;
    float s0 = 0.f, s1 = 0.f, s2 = 0.f, s3 = 0.f;
    for (int c = 0; c < D1CH; c += 4) {       // D1CH = 76 = 4*19
      s0 += pb[(c + 0) * 102];
      s1 += pb[(c + 1) * 102];
      s2 += pb[(c + 2) * 102];
      s3 += pb[(c + 3) * 102];
    }
    v = fmaxf((s0 + s1) + (s2 + s3) + bd1[j], 0.f);
  }
  float c0 = (j < 102) ? v * Wd3[j * 2] : 0.f;
  float c1 = (j < 102) ? v * Wd3[j * 2 + 1] : 0.f;
  float z0 = blockReduceSum128(c0, tmp2) + bd3[0];
  float z1 = blockReduceSum128(c1, tmp2) + bd3[1];
  if (j < 2) {
    float m = fmaxf(z0, z1);
    float lse = m + logf(expf(z0 - m) + expf(z1 - m));
    out[b * 2 + j] = (j == 0 ? z0 : z1) - lse;
  }
}

// ---------------- launch ----------------
extern "C" void kernel_launch(void* const* d_in, const int* in_sizes, int n_in,
                              void* d_out, int out_size, void* d_ws, size_t ws_size,
                              hipStream_t stream) {
  const float* x      = (const float*)d_in[0];
  const float* target = (const float*)d_in[1];
  const int*   esrc   = (const int*)d_in[2];
  const int*   edst   = (const int*)d_in[3];
  const float* W1rel  = (const float*)d_in[4];
  const float* W1root = (const float*)d_in[5];
  const float* b1     = (const float*)d_in[6];
  const float* p1     = (const float*)d_in[7];
  const float* W2rel  = (const float*)d_in[8];
  const float* W2root = (const float*)d_in[9];
  const float* b2     = (const float*)d_in[10];
  const float* p2     = (const float*)d_in[11];
  const float* Wc     = (const float*)d_in[12];
  const float* bc     = (const float*)d_in[13];
  const float* Wihf   = (const float*)d_in[14];
  const float* Whhf   = (const float*)d_in[15];
  const float* bihf   = (const float*)d_in[16];
  const float* bhhf   = (const float*)d_in[17];
  const float* Wihb   = (const float*)d_in[18];
  const float* Whhb   = (const float*)d_in[19];
  const float* bihb   = (const float*)d_in[20];
  const float* bhhb   = (const float*)d_in[21];
  const float* Wd1    = (const float*)d_in[22];
  const float* bd1    = (const float*)d_in[23];
  const float* Wd3    = (const float*)d_in[24];
  const float* bd3    = (const float*)d_in[25];
  float* out = (float*)d_out;

  char* wsb = (char*)d_ws;
  size_t off = 0;
  auto alloc = [&](size_t bytes) -> void* {
    void* p = wsb + off;
    off = (off + bytes + 255) & ~(size_t)255;
    return p;
  };
  float* h1      = (float*)alloc((size_t)BN * 128 * 4);       // 64MB
  u16*   Abf     = (u16*)  alloc((size_t)BB * K1C * 256 * 2); // 53.7MB bf16 [agg|xp]
  u16*   Wfrag   = (u16*)  alloc((size_t)4096 * 8 * 2);       // 64KB fragment-ordered W
  float* agg1    = (float*)alloc((size_t)BN * 4 * 4);
  float* score1  = (float*)alloc((size_t)BN * 4);
  int*   perm1   = (int*)  alloc((size_t)BB * K1C * 4);
  int*   map1    = (int*)  alloc((size_t)BN * 4);
  u16*   h2b     = (u16*)  alloc((size_t)BB * K1C * 128 * 2); // 26.9MB bf16
  float* score2  = (float*)alloc((size_t)BB * K1C * 4);
  int*   perm2   = (int*)  alloc((size_t)BB * K2C * 4);
  float* invp    = (float*)alloc(256);
  float* xs      = (float*)alloc((size_t)TSEQ * BB * 128 * 4);
  float* gi      = (float*)alloc((size_t)2 * TSEQ * BB * 360 * 4);
  float* xc      = (float*)alloc((size_t)BB * 4816 * 4);
  int*   starts2 = (int*)  alloc((size_t)BB * K1C * 4);
  int*   cnt2    = (int*)  alloc((size_t)BB * K1C * 4);
  int*   elist2  = (int*)  alloc((size_t)EDG * 4);
  float* xmax1   = (float*)alloc((size_t)BB * 128 * 4);
  float* xsum1   = (float*)alloc((size_t)BB * 128 * 4);
  float* pmax2   = (float*)alloc((size_t)BB * NCH2 * 128 * 4);
  float* psum2   = (float*)alloc((size_t)BB * NCH2 * 128 * 4);
  float* part    = (float*)alloc((size_t)BB * D1CH * 102 * 4);

  k_pnorm<<<1, 128, 0, stream>>>(p1, p2, invp);
  k_wb<<<16, 256, 0, stream>>>(W2rel, W2root, Wfrag);

  // --- layer 1 ---
  k_l1<<<BB, 1024, 0, stream>>>(esrc, edst, x, agg1);
  k_h1<<<BN * 32 / 256, 256, 0, stream>>>(x, agg1, W1rel, W1root, b1, p1, invp, h1, score1);
  k_sort<<<BB, 512, 0, stream>>>(score1, NN, K1C, perm1, map1);

  // --- layer 2: filtered CSR + aggregate (emits bf16 A) + MFMA GEMM ---
  k_csr2<<<BB, 1024, 0, stream>>>(esrc, edst, map1, starts2, cnt2, elist2);
  k_agg2r<<<BB * 4, 1024, 0, stream>>>(starts2, cnt2, elist2, perm1, score1, h1,
                                       Abf, xmax1, xsum1);
  k_h2m<<<(BB * K1C) / 64, 256, 0, stream>>>(Abf, Wfrag, b2, p2, invp, h2b, score2);
  k_sort<<<BB, 512, 0, stream>>>(score2, K1C, K2C, perm2, nullptr);
  k_gatherread<<<BB * NCH2, 128, 0, stream>>>(h2b, score2, perm2, pmax2, psum2, K2C, NCH2);

  // --- target branch ---
  k_conv<<<BB * TSEQ, 128, 0, stream>>>(target, Wc, bc, xs);
  k_gi<<<2 * TSEQ * 8, 384, 0, stream>>>(xs, Wihf, bihf, Wihb, bihb, gi);
  k_gru<<<2 * 64, 384, 0, stream>>>(gi, Whhf, bhhf, Whhb, bhhb, xc);

  // --- head ---
  k_xg<<<BB, 128, 0, stream>>>(xmax1, xsum1, pmax2, psum2, xc);
  k_d1<<<(BB / 4) * D1CH, 128, 0, stream>>>(xc, Wd1, part);
  k_final2<<<BB, 128, 0, stream>>>(part, bd1, Wd3, bd3, out);
}

// Round 18
// 273.680 us; speedup vs baseline: 1.9897x; 1.1255x over previous
//
#include <hip/hip_runtime.h>
#include <math.h>

#define BB   128
#define NN   1024
#define BN   (BB*NN)          // 131072
#define EDG  (BB*8192)        // 1048576
#define K1C  820
#define K2C  656
#define TSEQ 19
#define HID  120
#define D1K  4816
#define D1CH 76               // ceil(4816/64)
#define NCH2 11               // ceil(656/64)

typedef unsigned short u16;
typedef __attribute__((ext_vector_type(8))) short bf16x8;
typedef __attribute__((ext_vector_type(4))) float f32x4;

__device__ __forceinline__ u16 f2b(float x) {   // fp32 -> bf16 RNE
  unsigned int u = __float_as_uint(x);
  u += 0x7FFFu + ((u >> 16) & 1u);
  return (u16)(u >> 16);
}
__device__ __forceinline__ float b2f(u16 v) {
  return __uint_as_float(((unsigned int)v) << 16);
}

// ---------------- reduction helper (128-thread block) ----------------
__device__ __forceinline__ float blockReduceSum128(float v, float* tmp2) {
#pragma unroll
  for (int o = 32; o > 0; o >>= 1) v += __shfl_down(v, o);
  int lane = threadIdx.x & 63, w = threadIdx.x >> 6;
  if (lane == 0) tmp2[w] = v;
  __syncthreads();
  float r = tmp2[0] + tmp2[1];
  __syncthreads();
  return r;
}

// ---------------- p-norm precompute ----------------
__global__ void k_pnorm(const float* __restrict__ p1, const float* __restrict__ p2,
                        float* __restrict__ invp) {
  __shared__ float tmp2[2];
  float a = p1[threadIdx.x], b = p2[threadIdx.x];
  float s1 = blockReduceSum128(a * a, tmp2);
  float s2 = blockReduceSum128(b * b, tmp2);
  if (threadIdx.x == 0) { invp[0] = 1.f / sqrtf(s1); invp[1] = 1.f / sqrtf(s2); }
}

// ---------------- pack W2rel|W2root into MFMA fragment order (bf16) ----------------
__global__ void k_wb(const float* __restrict__ W2rel, const float* __restrict__ W2root,
                     u16* __restrict__ Wfrag) {
  int idx = blockIdx.x * 256 + threadIdx.x;   // 16 blocks -> 4096
  int lane = idx & 63, ct = (idx >> 6) & 7, ks = idx >> 9;
  int c = ct * 16 + (lane & 15);
  int kbase = ks * 32 + (lane >> 4) * 8;
#pragma unroll
  for (int j = 0; j < 8; ++j) {
    int k = kbase + j;
    float w = (k < 128) ? W2rel[(size_t)k * 128 + c] : W2root[(size_t)(k - 128) * 128 + c];
    Wfrag[(size_t)idx * 8 + j] = f2b(w);
  }
}

// ---------------- fused layer-1 CSR build + aggregate (all in LDS) ----------------
__global__ __launch_bounds__(1024) void k_l1(const int* __restrict__ src,
                                             const int* __restrict__ dst,
                                             const float* __restrict__ x,
                                             float* __restrict__ agg1) {
  __shared__ int hcur[1024];
  __shared__ int sscan[1024];
  __shared__ int ccnt[1024];
  __shared__ int el[8192];
  __shared__ float4 xls4[1024];
  int b = blockIdx.x, tid = threadIdx.x;
  int base = b * 8192, nb = b * 1024;
  hcur[tid] = 0;
  __syncthreads();
#pragma unroll
  for (int it = 0; it < 8; ++it)
    atomicAdd(&hcur[dst[base + it * 1024 + tid] - nb], 1);
  __syncthreads();
  int v = hcur[tid];
  ccnt[tid] = v;
  sscan[tid] = v;
  __syncthreads();
  for (int o = 1; o < 1024; o <<= 1) {
    int t = (tid >= o) ? sscan[tid - o] : 0;
    __syncthreads();
    sscan[tid] += t;
    __syncthreads();
  }
  hcur[tid] = sscan[tid] - v;          // exclusive start (local cursor)
  __syncthreads();
#pragma unroll
  for (int it = 0; it < 8; ++it) {
    int e = base + it * 1024 + tid;
    int d = dst[e] - nb;
    int pos = atomicAdd(&hcur[d], 1);
    el[pos] = src[e] - nb;             // LOCAL src id
  }
  xls4[tid] = ((const float4*)x)[nb + tid];
  __syncthreads();
  const float* xls = (const float*)xls4;
  int rg = tid >> 2, lane = tid & 3;
#pragma unroll
  for (int it = 0; it < 4; ++it) {
    int r = rg + it * 256;
    int n = ccnt[r], s0 = sscan[r] - n;
    float a0 = 0.f, a1 = 0.f;
    int j = 0;
    for (; j + 1 < n; j += 2) {
      a0 += xls[el[s0 + j] * 4 + lane];
      a1 += xls[el[s0 + j + 1] * 4 + lane];
    }
    if (j < n) a0 += xls[el[s0 + j] * 4 + lane];
    agg1[(size_t)(nb + r) * 4 + lane] = a0 + a1;
  }
}

// ---------------- h1 = relu(agg1@W1rel + x@W1root + b1); score1 fused ----------------
__global__ void k_h1(const float* __restrict__ x, const float* __restrict__ agg1,
                     const float* __restrict__ W1rel, const float* __restrict__ W1root,
                     const float* __restrict__ b1, const float* __restrict__ p1,
                     const float* __restrict__ invp,
                     float* __restrict__ h1, float* __restrict__ score1) {
  int tid = blockIdx.x * 256 + threadIdx.x;
  int r = tid >> 5, lane = tid & 31, f4 = lane * 4;
  float4 a = ((const float4*)agg1)[r];
  float4 xv = ((const float4*)x)[r];
  float o[4], dot = 0.f;
#pragma unroll
  for (int j = 0; j < 4; ++j) {
    int f = f4 + j;
    float acc = b1[f]
      + a.x * W1rel[f] + a.y * W1rel[128 + f] + a.z * W1rel[256 + f] + a.w * W1rel[384 + f]
      + xv.x * W1root[f] + xv.y * W1root[128 + f] + xv.z * W1root[256 + f] + xv.w * W1root[384 + f];
    o[j] = fmaxf(acc, 0.f);
    dot += o[j] * p1[f];
  }
  *(float4*)&h1[(size_t)r * 128 + f4] = make_float4(o[0], o[1], o[2], o[3]);
#pragma unroll
  for (int off = 16; off > 0; off >>= 1) dot += __shfl_down(dot, off, 32);
  if (lane == 0) score1[r] = tanhf(dot * invp[0]);
}

// ---------------- per-graph top-k via LDS bitonic sort (1024 threads) ----------------
__global__ __launch_bounds__(1024) void k_sort(const float* __restrict__ score, int n_per, int K,
                       int* __restrict__ perm, int* __restrict__ mapping) {
  __shared__ float s[1024];
  __shared__ int   id[1024];
  int b = blockIdx.x;
  const float* sc = score + (size_t)b * n_per;
  for (int i = threadIdx.x; i < 1024; i += blockDim.x) {
    if (i < n_per) { s[i] = sc[i]; id[i] = i; }
    else           { s[i] = -INFINITY; id[i] = 0x7fffffff; }
  }
  __syncthreads();
  for (int k = 2; k <= 1024; k <<= 1) {
    for (int j = k >> 1; j > 0; j >>= 1) {
      for (int i = threadIdx.x; i < 1024; i += blockDim.x) {
        int l = i ^ j;
        if (l > i) {
          float si = s[i], sl = s[l];
          int ii = id[i], il = id[l];
          bool iBeforeL = (si > sl) || (si == sl && ii < il);
          bool up = ((i & k) == 0);
          if (up ? (!iBeforeL) : iBeforeL) {
            s[i] = sl; s[l] = si; id[i] = il; id[l] = ii;
          }
        }
      }
      __syncthreads();
    }
  }
  for (int r = threadIdx.x; r < K; r += blockDim.x)
    perm[(size_t)b * K + r] = b * n_per + id[r];
  if (mapping) {
    for (int i = threadIdx.x; i < n_per; i += blockDim.x)
      mapping[(size_t)b * n_per + i] = -1;
    __syncthreads();
    for (int r = threadIdx.x; r < K; r += blockDim.x)
      mapping[(size_t)b * n_per + id[r]] = b * K + r;
  }
}

// ---------------- layer-2 gather + partial readout from bf16 h2 ----------------
#define RCH 64
__global__ void k_gatherread(const u16* __restrict__ h2b, const float* __restrict__ score,
                             const int* __restrict__ perm,
                             float* __restrict__ pmax, float* __restrict__ psum,
                             int K, int nch) {
  int b = blockIdx.x / nch, c = blockIdx.x % nch, f = threadIdx.x;  // 128 threads
  int r0 = c * RCH, r1 = min(r0 + RCH, K);
  float mx = -INFINITY, sm = 0.f;
  for (int r = r0; r < r1; ++r) {
    int g = perm[(size_t)b * K + r];
    float v = b2f(h2b[(size_t)g * 128 + f]) * score[g];
    mx = fmaxf(mx, v); sm += v;
  }
  pmax[((size_t)b * nch + c) * 128 + f] = mx;
  psum[((size_t)b * nch + c) * 128 + f] = sm;
}

// ---------------- layer-2 filtered CSR (per-graph, LDS, no global atomics) ----------------
__global__ __launch_bounds__(1024) void k_csr2(const int* __restrict__ src,
                                               const int* __restrict__ dst,
                                               const int* __restrict__ map,
                                               int* __restrict__ starts2,
                                               int* __restrict__ cnt2,
                                               int* __restrict__ elist2) {
  __shared__ int mloc[8192];   // local kept dst per edge, -1 invalid
  __shared__ int msl[8192];    // local kept src per edge
  __shared__ int h[1024];
  __shared__ int s[1024];
  int g = blockIdx.x, tid = threadIdx.x;
  int base = g * 8192, nb2 = g * K1C;
  h[tid] = 0;
  __syncthreads();
#pragma unroll
  for (int it = 0; it < 8; ++it) {
    int e = base + it * 1024 + tid;
    int ms = map[src[e]], md = map[dst[e]];
    bool valid = (ms >= 0) && (md >= 0);
    int idx = it * 1024 + tid;
    int ml = valid ? (md - nb2) : -1;
    mloc[idx] = ml;
    msl[idx] = ms - nb2;
    if (valid) atomicAdd(&h[ml], 1);
  }
  __syncthreads();
  int v = (tid < K1C) ? h[tid] : 0;
  if (tid < K1C) cnt2[nb2 + tid] = v;
  s[tid] = v;
  __syncthreads();
  for (int o = 1; o < 1024; o <<= 1) {
    int t = (tid >= o) ? s[tid - o] : 0;
    __syncthreads();
    s[tid] += t;
    __syncthreads();
  }
  int st = s[tid] - v;
  if (tid < K1C) starts2[nb2 + tid] = base + st;
  h[tid] = st;                        // local cursor
  __syncthreads();
#pragma unroll
  for (int it = 0; it < 8; ++it) {
    int idx = it * 1024 + tid;
    int ml = mloc[idx];
    if (ml >= 0) {
      int pos = atomicAdd(&h[ml], 1);
      elist2[base + pos] = msl[idx];
    }
  }
}

// ---------------- layer-2 aggregate + layer-1 readout; float4/lane walk; emits bf16 A ----------------
__global__ __launch_bounds__(1024) void k_agg2r(const int* __restrict__ starts2,
                                                const int* __restrict__ cnt2,
                                                const int* __restrict__ elist2,
                                                const int* __restrict__ perm1,
                                                const float* __restrict__ score1,
                                                const float* __restrict__ h1,
                                                u16* __restrict__ Abf,
                                                float* __restrict__ xmax1,
                                                float* __restrict__ xsum1) {
  __shared__ float xls[K1C * 32];     // 104,960 B
  __shared__ int   el[8192];          // 32,768 B
  __shared__ int   sts[K1C];
  __shared__ int   ctn[K1C];
  __shared__ int   pid[K1C];
  __shared__ float scs[K1C];
  __shared__ float redm[16][36];      // per-wave partial max
  __shared__ float reds[16][36];      // per-wave partial sum
  int g = blockIdx.x >> 2, q = blockIdx.x & 3;
  int tid = threadIdx.x;
  int nb2 = g * K1C, base = g * 8192;
  for (int i = tid; i < K1C; i += 1024) {
    int p = perm1[nb2 + i];
    pid[i] = p;
    scs[i] = score1[p];
    sts[i] = starts2[nb2 + i] - base;
    ctn[i] = cnt2[nb2 + i];
  }
  {
    const int4* e4 = (const int4*)(elist2 + base);
    for (int i = tid; i < 2048; i += 1024) ((int4*)el)[i] = e4[i];
  }
  __syncthreads();
  for (int i = tid; i < K1C * 8; i += 1024) {
    int row = i >> 3, f4 = (i & 7) * 4;
    float4 v = *(const float4*)&h1[(size_t)pid[row] * 128 + q * 32 + f4];
    float s = scs[row];
    v.x *= s; v.y *= s; v.z *= s; v.w *= s;
    *(float4*)&xls[row * 32 + f4] = v;
    ushort4 bv;
    bv.x = f2b(v.x); bv.y = f2b(v.y); bv.z = f2b(v.z); bv.w = f2b(v.w);
    *(ushort4*)&Abf[(size_t)(nb2 + row) * 256 + 128 + q * 32 + f4] = bv;  // xp half
  }
  __syncthreads();
  int rg = tid >> 3, f4l = (tid & 7) * 4;   // 128 row-groups x 8 lanes (4 feats each)
  float4 mx = make_float4(-INFINITY, -INFINITY, -INFINITY, -INFINITY);
  float4 sm = make_float4(0.f, 0.f, 0.f, 0.f);
  for (int r = rg; r < K1C; r += 128) {
    int s0 = sts[r], n = ctn[r];
    float4 a = make_float4(0.f, 0.f, 0.f, 0.f);
    float4 c = make_float4(0.f, 0.f, 0.f, 0.f);
    int j = 0;
    for (; j + 1 < n; j += 2) {
      float4 v0 = *(const float4*)&xls[el[s0 + j] * 32 + f4l];
      float4 v1 = *(const float4*)&xls[el[s0 + j + 1] * 32 + f4l];
      a.x += v0.x; a.y += v0.y; a.z += v0.z; a.w += v0.w;
      c.x += v1.x; c.y += v1.y; c.z += v1.z; c.w += v1.w;
    }
    if (j < n) {
      float4 v = *(const float4*)&xls[el[s0 + j] * 32 + f4l];
      a.x += v.x; a.y += v.y; a.z += v.z; a.w += v.w;
    }
    ushort4 ov;
    ov.x = f2b(a.x + c.x); ov.y = f2b(a.y + c.y);
    ov.z = f2b(a.z + c.z); ov.w = f2b(a.w + c.w);
    *(ushort4*)&Abf[(size_t)(nb2 + r) * 256 + q * 32 + f4l] = ov;          // agg half
    float4 w = *(const float4*)&xls[r * 32 + f4l];                          // layer-1 readout
    mx.x = fmaxf(mx.x, w.x); mx.y = fmaxf(mx.y, w.y);
    mx.z = fmaxf(mx.z, w.z); mx.w = fmaxf(mx.w, w.w);
    sm.x += w.x; sm.y += w.y; sm.z += w.z; sm.w += w.w;
  }
  // reduce over the 8 row-groups within each wave (lanes 8,16,32 apart share f4l)
#pragma unroll
  for (int m = 8; m <= 32; m <<= 1) {
    mx.x = fmaxf(mx.x, __shfl_xor(mx.x, m)); mx.y = fmaxf(mx.y, __shfl_xor(mx.y, m));
    mx.z = fmaxf(mx.z, __shfl_xor(mx.z, m)); mx.w = fmaxf(mx.w, __shfl_xor(mx.w, m));
    sm.x += __shfl_xor(sm.x, m); sm.y += __shfl_xor(sm.y, m);
    sm.z += __shfl_xor(sm.z, m); sm.w += __shfl_xor(sm.w, m);
  }
  int wv = tid >> 6;
  if ((tid & 63) < 8) {
    *(float4*)&redm[wv][f4l] = mx;
    *(float4*)&reds[wv][f4l] = sm;
  }
  __syncthreads();
  if (tid < 32) {
    float m = redm[0][tid], s2 = reds[0][tid];
#pragma unroll
    for (int w2 = 1; w2 < 16; ++w2) {
      m = fmaxf(m, redm[w2][tid]);
      s2 += reds[w2][tid];
    }
    xmax1[g * 128 + q * 32 + tid] = m;
    xsum1[g * 128 + q * 32 + tid] = s2;
  }
}

// ---------------- h2 via MFMA bf16: 64x128 block tile, 4 waves, K=256; bf16 h2 out ----------------
__global__ __launch_bounds__(256, 4) void k_h2m(
    const u16* __restrict__ Abf, const u16* __restrict__ Wfrag,
    const float* __restrict__ b2, const float* __restrict__ p2,
    const float* __restrict__ invp,
    u16* __restrict__ h2b, float* __restrict__ score2) {
  __shared__ u16 Als[64][40];        // padded
  int tid = threadIdx.x;
  int r0 = blockIdx.x * 64;
  int wv = tid >> 6, lane = tid & 63;
  int lr = lane & 15, kg = lane >> 4;
  f32x4 acc[8];
  f32x4 z = {0.f, 0.f, 0.f, 0.f};
#pragma unroll
  for (int ct = 0; ct < 8; ++ct) acc[ct] = z;
  for (int ks = 0; ks < 8; ++ks) {
    {
      int row = tid >> 2, kq = (tid & 3) * 8;
      *(f32x4*)&Als[row][kq] =
          *(const f32x4*)&Abf[(size_t)(r0 + row) * 256 + ks * 32 + kq];
    }
    __syncthreads();
    bf16x8 a = *(const bf16x8*)&Als[wv * 16 + lr][kg * 8];
    const u16* wf = Wfrag + (size_t)ks * 4096;
#pragma unroll
    for (int ct = 0; ct < 8; ++ct) {
      bf16x8 b = *(const bf16x8*)&wf[(ct * 64 + lane) * 8];
      acc[ct] = __builtin_amdgcn_mfma_f32_16x16x32_bf16(a, b, acc[ct], 0, 0, 0);
    }
    __syncthreads();
  }
  float inv = invp[1];
  float dots[4] = {0.f, 0.f, 0.f, 0.f};
#pragma unroll
  for (int ct = 0; ct < 8; ++ct) {
    int c = ct * 16 + lr;
    float bb = b2[c], pp = p2[c];
#pragma unroll
    for (int i = 0; i < 4; ++i) {
      float o = fmaxf(acc[ct][i] + bb, 0.f);
      h2b[(size_t)(r0 + wv * 16 + kg * 4 + i) * 128 + c] = f2b(o);
      dots[i] += o * pp;
    }
  }
#pragma unroll
  for (int i = 0; i < 4; ++i) {
    float d = dots[i];
#pragma unroll
    for (int m = 8; m >= 1; m >>= 1) d += __shfl_xor(d, m);
    if (lr == 0) score2[r0 + wv * 16 + kg * 4 + i] = tanhf(d * inv);
  }
}

// ---------------- target conv + relu + avgpool -> xs[t][b][o] ----------------
__global__ void k_conv(const float* __restrict__ target, const float* __restrict__ Wc,
                       const float* __restrict__ bc, float* __restrict__ xs) {
  int gb = blockIdx.x;               // B*19
  int b = gb / TSEQ, tt = gb % TSEQ;
  int o = threadIdx.x;               // 128
  __shared__ float tg[30][8];
  for (int i = threadIdx.x; i < 210; i += 128) {
    int ch = i / 7, u = i % 7;
    tg[ch][u] = target[((size_t)b * 30 + ch) * 101 + tt * 5 + u];
  }
  __syncthreads();
  const float* w = Wc + (size_t)o * 90;
  float acc5[5] = {0, 0, 0, 0, 0};
  for (int ch = 0; ch < 30; ++ch) {
    float w0 = w[ch * 3], w1 = w[ch * 3 + 1], w2 = w[ch * 3 + 2];
#pragma unroll
    for (int u = 0; u < 5; ++u)
      acc5[u] += tg[ch][u] * w0 + tg[ch][u + 1] * w1 + tg[ch][u + 2] * w2;
  }
  float bo = bc[o], s = 0.f;
#pragma unroll
  for (int u = 0; u < 5; ++u) s += fmaxf(acc5[u] + bo, 0.f);
  xs[((size_t)tt * BB + b) * 128 + o] = s * 0.2f;
}

// ---------------- gi = xs @ Wih^T + bih; 16 batches per block ----------------
#define GIB 16
__global__ __launch_bounds__(384) void k_gi(const float* __restrict__ xs,
                     const float* __restrict__ Wihf, const float* __restrict__ bihf,
                     const float* __restrict__ Wihb, const float* __restrict__ bihb,
                     float* __restrict__ gi) {
  int bg = blockIdx.x & 7;
  int t = (blockIdx.x >> 3) % TSEQ;
  int dir = blockIdx.x / (8 * TSEQ);
  int b0 = bg * GIB;
  __shared__ float xst[GIB][128];
  int tid = threadIdx.x;
  for (int i = tid; i < GIB * 128; i += 384) {
    int bb = i >> 7, k = i & 127;
    xst[bb][k] = xs[((size_t)t * BB + b0 + bb) * 128 + k];
  }
  __syncthreads();
  int j = tid;
  if (j < 360) {
    const float* W = (dir ? Wihb : Wihf) + (size_t)j * 128;
    float bias = (dir ? bihb : bihf)[j];
    float acc[GIB];
#pragma unroll
    for (int bb = 0; bb < GIB; ++bb) acc[bb] = bias;
#pragma unroll 4
    for (int k = 0; k < 128; ++k) {
      float w = W[k];
#pragma unroll
      for (int bb = 0; bb < GIB; ++bb) acc[bb] += xst[bb][k] * w;
    }
    size_t base = ((size_t)dir * TSEQ + t) * BB + b0;
#pragma unroll
    for (int bb = 0; bb < GIB; ++bb) gi[(base + bb) * 360 + j] = acc[bb];
  }
}

// ---------------- GRU recurrence: 1 batch/block (256 blocks), Whh in registers ----------------
__global__ __launch_bounds__(384) void k_gru(const float* __restrict__ gi,
                      const float* __restrict__ Whhf, const float* __restrict__ bhhf,
                      const float* __restrict__ Whhb, const float* __restrict__ bhhb,
                      float* __restrict__ xc) {
  int b = blockIdx.x & 127, dir = blockIdx.x >> 7;
  const float* Whh = dir ? Whhb : Whhf;
  const float* bhh = dir ? bhhb : bhhf;
  __shared__ float h_sh[HID];
  __shared__ float g_sh[360];
  int j = threadIdx.x;               // 384
  float wrow[HID];
  float bias = 0.f;
  if (j < 360) {
    const float4* W4 = (const float4*)(Whh + (size_t)j * HID);
#pragma unroll
    for (int k4 = 0; k4 < HID / 4; ++k4) {
      float4 w = W4[k4];
      wrow[k4 * 4 + 0] = w.x; wrow[k4 * 4 + 1] = w.y;
      wrow[k4 * 4 + 2] = w.z; wrow[k4 * 4 + 3] = w.w;
    }
    bias = bhh[j];
  }
  if (j < HID) h_sh[j] = 0.f;
  __syncthreads();
  for (int st = 0; st < TSEQ; ++st) {
    int tt = dir ? (TSEQ - 1 - st) : st;
    if (j < 360) {
      float a0 = bias;
      const float4* h4 = (const float4*)h_sh;
#pragma unroll
      for (int k4 = 0; k4 < HID / 4; ++k4) {
        float4 v0 = h4[k4];
        a0 += wrow[k4*4+0]*v0.x + wrow[k4*4+1]*v0.y + wrow[k4*4+2]*v0.z + wrow[k4*4+3]*v0.w;
      }
      g_sh[j] = a0;
    }
    __syncthreads();
    if (j < HID) {
      const float* g = gi + (((size_t)dir * TSEQ + tt) * BB + b) * 360;
      float r  = 1.f / (1.f + expf(-(g[j]       + g_sh[j])));
      float z  = 1.f / (1.f + expf(-(g[120 + j] + g_sh[120 + j])));
      float ng = tanhf(g[240 + j] + r * g_sh[240 + j]);
      float hn = (1.f - z) * ng + z * h_sh[j];
      h_sh[j] = hn;
      xc[(size_t)b * 4816 + 256 + (size_t)tt * 240 + dir * 120 + j] = hn;
    }
    __syncthreads();
  }
}

// ---------------- fused final readout: xc[:, :256] = x1 + x2 ----------------
__global__ void k_xg(const float* __restrict__ xmax1, const float* __restrict__ xsum1,
                     const float* __restrict__ pmax2, const float* __restrict__ psum2,
                     float* __restrict__ xc) {
  int b = blockIdx.x, f = threadIdx.x;  // 128 threads
  float mx2 = -INFINITY, sm2 = 0.f;
  for (int c = 0; c < NCH2; ++c) {
    mx2 = fmaxf(mx2, pmax2[((size_t)b * NCH2 + c) * 128 + f]);
    sm2 += psum2[((size_t)b * NCH2 + c) * 128 + f];
  }
  xc[(size_t)b * 4816 + f] = xmax1[b * 128 + f] + mx2;
  xc[(size_t)b * 4816 + 128 + f] = xsum1[b * 128 + f] / (float)K1C + sm2 / (float)K2C;
}

// ---------------- d1 partial GEMM: K-chunk 64 staged in LDS, 4 rows/block ----------------
__global__ __launch_bounds__(128) void k_d1(const float* __restrict__ xc,
                                            const float* __restrict__ Wd1,
                                            float* __restrict__ part) {
  int c = blockIdx.x % D1CH;          // k-chunk of 64
  int rg = blockIdx.x / D1CH;         // row group of 4 (0..31)
  int k0 = c * 64, kn = min(64, D1K - k0);
  __shared__ float wls[64 * 102];     // 26.1 KB, [k][j] contiguous
  __shared__ float xcs[4][64];
  int tid = threadIdx.x;
  for (int i = tid; i < 4 * 64; i += 128) {
    int r = i >> 6, k = i & 63;
    xcs[r][k] = (k < kn) ? xc[(size_t)(rg * 4 + r) * D1K + k0 + k] : 0.f;
  }
  {
    const float2* s2 = (const float2*)(Wd1 + (size_t)k0 * 102);
    float2* d2 = (float2*)wls;
    int n2 = (kn * 102) >> 1;
    for (int i = tid; i < n2; i += 128) d2[i] = s2[i];
  }
  __syncthreads();
  int j = tid;
  if (j < 102) {
    float a0 = 0.f, a1 = 0.f, a2 = 0.f, a3 = 0.f;
#pragma unroll 4
    for (int k = 0; k < kn; ++k) {
      float w = wls[k * 102 + j];
      a0 += xcs[0][k] * w; a1 += xcs[1][k] * w;
      a2 += xcs[2][k] * w; a3 += xcs[3][k] * w;
    }
    part[((size_t)(rg * 4 + 0) * D1CH + c) * 102 + j] = a0;
    part[((size_t)(rg * 4 + 1) * D1CH + c) * 102 + j] = a1;
    part[((size_t)(rg * 4 + 2) * D1CH + c) * 102 + j] = a2;
    part[((size_t)(rg * 4 + 3) * D1CH + c) * 102 + j] = a3;
  }
}

// ---------------- reduce partials + relu + d3 + log_softmax ----------------
__global__ void k_final2(const float* __restrict__ part, const float* __restrict__ bd1,
                         const float* __restrict__ Wd3, const float* __restrict__ bd3,
                         float* __restrict__ out) {
  __shared__ float tmp2[2];
  int b = blockIdx.x, j = threadIdx.x;
  float v = 0.f;
  if (j < 102) {
    const float* pb = part + (size_t)b * D1CH * 102 + j;
    float s0 = 0.f, s1 = 0.f, s2 = 0.f, s3 = 0.f;
    for (int c = 0; c < D1CH; c += 4) {       // D1CH = 76 = 4*19
      s0 += pb[(c + 0) * 102];
      s1 += pb[(c + 1) * 102];
      s2 += pb[(c + 2) * 102];
      s3 += pb[(c + 3) * 102];
    }
    v = fmaxf((s0 + s1) + (s2 + s3) + bd1[j], 0.f);
  }
  float c0 = (j < 102) ? v * Wd3[j * 2] : 0.f;
  float c1 = (j < 102) ? v * Wd3[j * 2 + 1] : 0.f;
  float z0 = blockReduceSum128(c0, tmp2) + bd3[0];
  float z1 = blockReduceSum128(c1, tmp2) + bd3[1];
  if (j < 2) {
    float m = fmaxf(z0, z1);
    float lse = m + logf(expf(z0 - m) + expf(z1 - m));
    out[b * 2 + j] = (j == 0 ? z0 : z1) - lse;
  }
}

// ---------------- launch ----------------
extern "C" void kernel_launch(void* const* d_in, const int* in_sizes, int n_in,
                              void* d_out, int out_size, void* d_ws, size_t ws_size,
                              hipStream_t stream) {
  const float* x      = (const float*)d_in[0];
  const float* target = (const float*)d_in[1];
  const int*   esrc   = (const int*)d_in[2];
  const int*   edst   = (const int*)d_in[3];
  const float* W1rel  = (const float*)d_in[4];
  const float* W1root = (const float*)d_in[5];
  const float* b1     = (const float*)d_in[6];
  const float* p1     = (const float*)d_in[7];
  const float* W2rel  = (const float*)d_in[8];
  const float* W2root = (const float*)d_in[9];
  const float* b2     = (const float*)d_in[10];
  const float* p2     = (const float*)d_in[11];
  const float* Wc     = (const float*)d_in[12];
  const float* bc     = (const float*)d_in[13];
  const float* Wihf   = (const float*)d_in[14];
  const float* Whhf   = (const float*)d_in[15];
  const float* bihf   = (const float*)d_in[16];
  const float* bhhf   = (const float*)d_in[17];
  const float* Wihb   = (const float*)d_in[18];
  const float* Whhb   = (const float*)d_in[19];
  const float* bihb   = (const float*)d_in[20];
  const float* bhhb   = (const float*)d_in[21];
  const float* Wd1    = (const float*)d_in[22];
  const float* bd1    = (const float*)d_in[23];
  const float* Wd3    = (const float*)d_in[24];
  const float* bd3    = (const float*)d_in[25];
  float* out = (float*)d_out;

  char* wsb = (char*)d_ws;
  size_t off = 0;
  auto alloc = [&](size_t bytes) -> void* {
    void* p = wsb + off;
    off = (off + bytes + 255) & ~(size_t)255;
    return p;
  };
  float* h1      = (float*)alloc((size_t)BN * 128 * 4);       // 64MB
  u16*   Abf     = (u16*)  alloc((size_t)BB * K1C * 256 * 2); // 53.7MB bf16 [agg|xp]
  u16*   Wfrag   = (u16*)  alloc((size_t)4096 * 8 * 2);       // 64KB fragment-ordered W
  float* agg1    = (float*)alloc((size_t)BN * 4 * 4);
  float* score1  = (float*)alloc((size_t)BN * 4);
  int*   perm1   = (int*)  alloc((size_t)BB * K1C * 4);
  int*   map1    = (int*)  alloc((size_t)BN * 4);
  u16*   h2b     = (u16*)  alloc((size_t)BB * K1C * 128 * 2); // 26.9MB bf16
  float* score2  = (float*)alloc((size_t)BB * K1C * 4);
  int*   perm2   = (int*)  alloc((size_t)BB * K2C * 4);
  float* invp    = (float*)alloc(256);
  float* xs      = (float*)alloc((size_t)TSEQ * BB * 128 * 4);
  float* gi      = (float*)alloc((size_t)2 * TSEQ * BB * 360 * 4);
  float* xc      = (float*)alloc((size_t)BB * 4816 * 4);
  int*   starts2 = (int*)  alloc((size_t)BB * K1C * 4);
  int*   cnt2    = (int*)  alloc((size_t)BB * K1C * 4);
  int*   elist2  = (int*)  alloc((size_t)EDG * 4);
  float* xmax1   = (float*)alloc((size_t)BB * 128 * 4);
  float* xsum1   = (float*)alloc((size_t)BB * 128 * 4);
  float* pmax2   = (float*)alloc((size_t)BB * NCH2 * 128 * 4);
  float* psum2   = (float*)alloc((size_t)BB * NCH2 * 128 * 4);
  float* part    = (float*)alloc((size_t)BB * D1CH * 102 * 4);

  k_pnorm<<<1, 128, 0, stream>>>(p1, p2, invp);
  k_wb<<<16, 256, 0, stream>>>(W2rel, W2root, Wfrag);

  // --- layer 1 ---
  k_l1<<<BB, 1024, 0, stream>>>(esrc, edst, x, agg1);
  k_h1<<<BN * 32 / 256, 256, 0, stream>>>(x, agg1, W1rel, W1root, b1, p1, invp, h1, score1);
  k_sort<<<BB, 1024, 0, stream>>>(score1, NN, K1C, perm1, map1);

  // --- layer 2: filtered CSR + aggregate (emits bf16 A) + MFMA GEMM ---
  k_csr2<<<BB, 1024, 0, stream>>>(esrc, edst, map1, starts2, cnt2, elist2);
  k_agg2r<<<BB * 4, 1024, 0, stream>>>(starts2, cnt2, elist2, perm1, score1, h1,
                                       Abf, xmax1, xsum1);
  k_h2m<<<(BB * K1C) / 64, 256, 0, stream>>>(Abf, Wfrag, b2, p2, invp, h2b, score2);
  k_sort<<<BB, 1024, 0, stream>>>(score2, K1C, K2C, perm2, nullptr);
  k_gatherread<<<BB * NCH2, 128, 0, stream>>>(h2b, score2, perm2, pmax2, psum2, K2C, NCH2);

  // --- target branch ---
  k_conv<<<BB * TSEQ, 128, 0, stream>>>(target, Wc, bc, xs);
  k_gi<<<2 * TSEQ * 8, 384, 0, stream>>>(xs, Wihf, bihf, Wihb, bihb, gi);
  k_gru<<<2 * 128, 384, 0, stream>>>(gi, Whhf, bhhf, Whhb, bhhb, xc);

  // --- head ---
  k_xg<<<BB, 128, 0, stream>>>(xmax1, xsum1, pmax2, psum2, xc);
  k_d1<<<(BB / 4) * D1CH, 128, 0, stream>>>(xc, Wd1, part);
  k_final2<<<BB, 128, 0, stream>>>(part, bd1, Wd3, bd3, out);
}